// Round 15
// baseline (757.655 us; speedup 1.0000x reference)
//
#include <hip/hip_runtime.h>
#include <hip/hip_bf16.h>

// ---------------------------------------------------------------------------
// CapsuleNetwork: embedding -> 2-layer BiLSTM -> attn pooling -> routing
// Round 14: scan chain shortened. Wave-local gates: B-fragment cols chosen as
// (gate, dim) interleave so each wave computes all 4 gates of its 4 dims;
// gate collection via 3x shfl_xor + select (no zbuf LDS, no extra barrier).
// All-thread flag polling (no tid0 poll + broadcast barrier). 2 barriers/step.
// B=128 T=64 E=300 H=256 DA=128 R=8 SC=32 AT=16
// ---------------------------------------------------------------------------

typedef __attribute__((ext_vector_type(8))) short bf16x8;
typedef __attribute__((ext_vector_type(4))) float f32x4;

__device__ __forceinline__ float sigf(float x) { return 1.0f / (1.0f + __expf(-x)); }
__device__ __forceinline__ float tanhf_fast(float x) { return 1.0f - 2.0f / (__expf(2.0f * x) + 1.0f); }

// ---------------- transpose w_hh [1024][256] -> Wt [256][1024] -------------
__global__ void k_transpose(const float* __restrict__ w0, const float* __restrict__ w1,
                            const float* __restrict__ w2, const float* __restrict__ w3,
                            float* __restrict__ wt)
{
    __shared__ float tile[32][33];
    const float* W = (blockIdx.z == 0) ? w0 : (blockIdx.z == 1) ? w1 : (blockIdx.z == 2) ? w2 : w3;
    float* Wt = wt + (size_t)blockIdx.z * 256 * 1024;
    const int j0 = blockIdx.x * 32, k0 = blockIdx.y * 32;
    const int tx = threadIdx.x, ty = threadIdx.y;  // (32,8)
    #pragma unroll
    for (int i = 0; i < 32; i += 8)
        tile[ty + i][tx] = W[(size_t)(j0 + ty + i) * 256 + (k0 + tx)];
    __syncthreads();
    #pragma unroll
    for (int i = 0; i < 32; i += 8)
        Wt[(size_t)(k0 + ty + i) * 1024 + (j0 + tx)] = tile[tx][ty + i];
}

// ---------------- zero words -----------------------------------------------
__global__ void k_zero(int* __restrict__ p, int n)
{
    const int i = blockIdx.x * blockDim.x + threadIdx.x;
    if (i < n) p[i] = 0;
}

// ---------------- bf16x3 MFMA GEMM with INLINE fp32->hi/lo split -----------
__global__ __launch_bounds__(256) void k_mgemm(
    const float* __restrict__ A, int lda, const int* __restrict__ tokens,
    const float* __restrict__ W0, const float* __restrict__ W1, int ldw,
    const float* __restrict__ bias0, const float* __restrict__ bias1,
    float* __restrict__ C, int ldc, int Kin, int Kp, int act_tanh)
{
    __shared__ unsigned short lAh[128 * 40];
    __shared__ unsigned short lAl[128 * 40];
    __shared__ unsigned short lBh[128 * 40];
    __shared__ unsigned short lBl[128 * 40];

    const int tid = threadIdx.x;
    const int m0 = blockIdx.x * 128;
    const int n0 = blockIdx.y * 128;
    const int w  = tid >> 6, l = tid & 63;
    const int wm = (w >> 1) * 64, wn = (w & 1) * 64;
    const int lr = l & 15, lk = (l >> 4) * 8;

    int srow[2], sk8[2];
    const float* arow[2];
    const float* wrow[2];
    #pragma unroll
    for (int p = 0; p < 2; ++p) {
        const int chunk = tid + p * 256;
        srow[p] = chunk >> 2;
        sk8[p]  = (chunk & 3) * 8;
        const int am = m0 + srow[p];
        if (tokens) {
            const int t = am >> 7, b = am & 127;
            arow[p] = A + (size_t)tokens[b * 64 + t] * lda;
        } else {
            arow[p] = A + (size_t)am * lda;
        }
        const int wnr = n0 + srow[p];
        wrow[p] = (wnr < 1024) ? (W0 + (size_t)wnr * ldw)
                               : (W1 + (size_t)(wnr - 1024) * ldw);
    }

    f32x4 acc[4][4];
    #pragma unroll
    for (int i = 0; i < 4; ++i)
        #pragma unroll
        for (int j = 0; j < 4; ++j)
            acc[i][j] = (f32x4){0.f, 0.f, 0.f, 0.f};

    float fa[2][8], fw[2][8];
    #pragma unroll
    for (int p = 0; p < 2; ++p) {
        const int k0 = sk8[p];
        if (k0 + 7 < Kin) {
            const float4 a0 = *(const float4*)(arow[p] + k0);
            const float4 a1 = *(const float4*)(arow[p] + k0 + 4);
            fa[p][0]=a0.x; fa[p][1]=a0.y; fa[p][2]=a0.z; fa[p][3]=a0.w;
            fa[p][4]=a1.x; fa[p][5]=a1.y; fa[p][6]=a1.z; fa[p][7]=a1.w;
            const float4 b0 = *(const float4*)(wrow[p] + k0);
            const float4 b1 = *(const float4*)(wrow[p] + k0 + 4);
            fw[p][0]=b0.x; fw[p][1]=b0.y; fw[p][2]=b0.z; fw[p][3]=b0.w;
            fw[p][4]=b1.x; fw[p][5]=b1.y; fw[p][6]=b1.z; fw[p][7]=b1.w;
        } else {
            #pragma unroll
            for (int j = 0; j < 8; ++j) {
                fa[p][j] = (k0 + j < Kin) ? arow[p][k0 + j] : 0.0f;
                fw[p][j] = (k0 + j < Kin) ? wrow[p][k0 + j] : 0.0f;
            }
        }
    }

    for (int kt = 0; kt < Kp; kt += 32) {
        #pragma unroll
        for (int p = 0; p < 2; ++p) {
            const int la = srow[p] * 40 + sk8[p];
            ushort hA[8], lA[8], hW[8], lW[8];
            #pragma unroll
            for (int j = 0; j < 8; ++j) {
                __hip_bfloat16 bh = __float2bfloat16(fa[p][j]);
                const float fh = __bfloat162float(bh);
                __hip_bfloat16 bl = __float2bfloat16(fa[p][j] - fh);
                hA[j] = *(ushort*)&bh; lA[j] = *(ushort*)&bl;
                __hip_bfloat16 wh = __float2bfloat16(fw[p][j]);
                const float fwh = __bfloat162float(wh);
                __hip_bfloat16 wl = __float2bfloat16(fw[p][j] - fwh);
                hW[j] = *(ushort*)&wh; lW[j] = *(ushort*)&wl;
            }
            *(bf16x8*)&lAh[la] = *(bf16x8*)hA;
            *(bf16x8*)&lAl[la] = *(bf16x8*)lA;
            *(bf16x8*)&lBh[la] = *(bf16x8*)hW;
            *(bf16x8*)&lBl[la] = *(bf16x8*)lW;
        }
        __syncthreads();
        if (kt + 32 < Kp) {
            #pragma unroll
            for (int p = 0; p < 2; ++p) {
                const int k0 = kt + 32 + sk8[p];
                if (k0 + 7 < Kin) {
                    const float4 a0 = *(const float4*)(arow[p] + k0);
                    const float4 a1 = *(const float4*)(arow[p] + k0 + 4);
                    fa[p][0]=a0.x; fa[p][1]=a0.y; fa[p][2]=a0.z; fa[p][3]=a0.w;
                    fa[p][4]=a1.x; fa[p][5]=a1.y; fa[p][6]=a1.z; fa[p][7]=a1.w;
                    const float4 b0 = *(const float4*)(wrow[p] + k0);
                    const float4 b1 = *(const float4*)(wrow[p] + k0 + 4);
                    fw[p][0]=b0.x; fw[p][1]=b0.y; fw[p][2]=b0.z; fw[p][3]=b0.w;
                    fw[p][4]=b1.x; fw[p][5]=b1.y; fw[p][6]=b1.z; fw[p][7]=b1.w;
                } else {
                    #pragma unroll
                    for (int j = 0; j < 8; ++j) {
                        fa[p][j] = (k0 + j < Kin) ? arow[p][k0 + j] : 0.0f;
                        fw[p][j] = (k0 + j < Kin) ? wrow[p][k0 + j] : 0.0f;
                    }
                }
            }
        }
        bf16x8 ah[4], al[4], bh[4], bl[4];
        #pragma unroll
        for (int f = 0; f < 4; ++f) {
            const int ra = (wm + f * 16 + lr) * 40 + lk;
            const int rb = (wn + f * 16 + lr) * 40 + lk;
            ah[f] = *(const bf16x8*)&lAh[ra];
            al[f] = *(const bf16x8*)&lAl[ra];
            bh[f] = *(const bf16x8*)&lBh[rb];
            bl[f] = *(const bf16x8*)&lBl[rb];
        }
        #pragma unroll
        for (int fm = 0; fm < 4; ++fm)
            #pragma unroll
            for (int fn = 0; fn < 4; ++fn) {
                acc[fm][fn] = __builtin_amdgcn_mfma_f32_16x16x32_bf16(ah[fm], bh[fn], acc[fm][fn], 0, 0, 0);
                acc[fm][fn] = __builtin_amdgcn_mfma_f32_16x16x32_bf16(ah[fm], bl[fn], acc[fm][fn], 0, 0, 0);
                acc[fm][fn] = __builtin_amdgcn_mfma_f32_16x16x32_bf16(al[fm], bh[fn], acc[fm][fn], 0, 0, 0);
            }
        __syncthreads();
    }
    #pragma unroll
    for (int fm = 0; fm < 4; ++fm)
        #pragma unroll
        for (int fn = 0; fn < 4; ++fn) {
            const int col = n0 + wn + fn * 16 + lr;
            const float bv = (col < 1024) ? (bias0 ? bias0[col] : 0.f)
                                          : (bias1 ? bias1[col - 1024] : 0.f);
            #pragma unroll
            for (int j = 0; j < 4; ++j) {
                const int row = m0 + wm + fm * 16 + (l >> 4) * 4 + j;
                float x = acc[fm][fn][j] + bv;
                if (act_tanh) x = tanhf_fast(x);
                C[(size_t)row * ldc + col] = x;
            }
        }
}

// ---------------- fp32 GEMM (R6) — votes only ------------------------------
__global__ __launch_bounds__(256) void k_gemm(
    const float* __restrict__ A, int lda, const int* __restrict__ tokens,
    const float* __restrict__ W0, const float* __restrict__ W1, int nsplit, int ldw,
    const float* __restrict__ bias0, const float* __restrict__ bias1,
    float* __restrict__ C, int ldc, int K, int transb, int act_tanh,
    long long sA, long long sW, long long sC)
{
    __shared__ float As[32][128];
    __shared__ float Ws[32][128];
    A  += (size_t)blockIdx.z * (size_t)sA;
    W0 += (size_t)blockIdx.z * (size_t)sW;
    C  += (size_t)blockIdx.z * (size_t)sC;
    const int tid = threadIdx.x;
    const int m0 = blockIdx.x * 128;
    const int n0 = blockIdx.y * 128;

    const int srow = tid >> 1;
    const int kh   = (tid & 1) * 16;
    const int am = m0 + srow;
    const float* arow;
    if (tokens) {
        const int t = am >> 7, b = am & 127;
        arow = A + (size_t)tokens[b * 64 + t] * lda;
    } else {
        arow = A + (size_t)am * lda;
    }
    const int wn = n0 + srow;
    const float* wrow = (wn < nsplit) ? (W0 + (size_t)wn * ldw)
                                      : (W1 + (size_t)(wn - nsplit) * ldw);
    const int kw = tid >> 3;
    const int n8 = (tid & 7) * 16;

    const int tm4 = (tid & 15) * 4;
    const int tn4 = (tid >> 4) * 4;
    float acc[8][8] = {};
    float4 ra[4], rw[4];

    const int nt = (K + 31) / 32;

    #pragma unroll
    for (int j = 0; j < 4; ++j) {
        const int k = kh + j * 4;
        if (k + 3 < K) ra[j] = *(const float4*)(arow + k);
        else {
            float t0 = (k + 0 < K) ? arow[k + 0] : 0.f;
            float t1 = (k + 1 < K) ? arow[k + 1] : 0.f;
            float t2 = (k + 2 < K) ? arow[k + 2] : 0.f;
            float t3 = (k + 3 < K) ? arow[k + 3] : 0.f;
            ra[j] = make_float4(t0, t1, t2, t3);
        }
    }
    if (transb) {
        #pragma unroll
        for (int j = 0; j < 4; ++j) {
            const int k = kh + j * 4;
            if (k + 3 < K) rw[j] = *(const float4*)(wrow + k);
            else {
                float t0 = (k + 0 < K) ? wrow[k + 0] : 0.f;
                float t1 = (k + 1 < K) ? wrow[k + 1] : 0.f;
                float t2 = (k + 2 < K) ? wrow[k + 2] : 0.f;
                float t3 = (k + 3 < K) ? wrow[k + 3] : 0.f;
                rw[j] = make_float4(t0, t1, t2, t3);
            }
        }
    } else {
        const float* src = (kw < K) ? (W0 + (size_t)kw * ldw + n0 + n8) : W0;
        #pragma unroll
        for (int j = 0; j < 4; ++j)
            rw[j] = (kw < K) ? *(const float4*)(src + j * 4) : make_float4(0, 0, 0, 0);
    }

    for (int tile = 0; tile < nt; ++tile) {
        #pragma unroll
        for (int j = 0; j < 4; ++j) {
            As[kh + j * 4 + 0][srow] = ra[j].x;
            As[kh + j * 4 + 1][srow] = ra[j].y;
            As[kh + j * 4 + 2][srow] = ra[j].z;
            As[kh + j * 4 + 3][srow] = ra[j].w;
        }
        if (transb) {
            #pragma unroll
            for (int j = 0; j < 4; ++j) {
                Ws[kh + j * 4 + 0][srow] = rw[j].x;
                Ws[kh + j * 4 + 1][srow] = rw[j].y;
                Ws[kh + j * 4 + 2][srow] = rw[j].z;
                Ws[kh + j * 4 + 3][srow] = rw[j].w;
            }
        } else {
            #pragma unroll
            for (int j = 0; j < 4; ++j)
                *(float4*)&Ws[kw][n8 + j * 4] = rw[j];
        }
        __syncthreads();
        if (tile + 1 < nt) {
            const int kb = (tile + 1) * 32;
            #pragma unroll
            for (int j = 0; j < 4; ++j) {
                const int k = kb + kh + j * 4;
                if (k + 3 < K) ra[j] = *(const float4*)(arow + k);
                else {
                    float t0 = (k + 0 < K) ? arow[k + 0] : 0.f;
                    float t1 = (k + 1 < K) ? arow[k + 1] : 0.f;
                    float t2 = (k + 2 < K) ? arow[k + 2] : 0.f;
                    float t3 = (k + 3 < K) ? arow[k + 3] : 0.f;
                    ra[j] = make_float4(t0, t1, t2, t3);
                }
            }
            if (transb) {
                #pragma unroll
                for (int j = 0; j < 4; ++j) {
                    const int k = kb + kh + j * 4;
                    if (k + 3 < K) rw[j] = *(const float4*)(wrow + k);
                    else {
                        float t0 = (k + 0 < K) ? wrow[k + 0] : 0.f;
                        float t1 = (k + 1 < K) ? wrow[k + 1] : 0.f;
                        float t2 = (k + 2 < K) ? wrow[k + 2] : 0.f;
                        float t3 = (k + 3 < K) ? wrow[k + 3] : 0.f;
                        rw[j] = make_float4(t0, t1, t2, t3);
                    }
                }
            } else {
                const int k = kb + kw;
                const float* src = (k < K) ? (W0 + (size_t)k * ldw + n0 + n8) : W0;
                #pragma unroll
                for (int j = 0; j < 4; ++j)
                    rw[j] = (k < K) ? *(const float4*)(src + j * 4) : make_float4(0, 0, 0, 0);
            }
        }
        #pragma unroll 8
        for (int kk = 0; kk < 32; ++kk) {
            const float4 a0 = *(const float4*)&As[kk][tm4];
            const float4 a1 = *(const float4*)&As[kk][tm4 + 64];
            const float4 b0 = *(const float4*)&Ws[kk][tn4];
            const float4 b1 = *(const float4*)&Ws[kk][tn4 + 64];
            const float av[8] = {a0.x, a0.y, a0.z, a0.w, a1.x, a1.y, a1.z, a1.w};
            const float bv[8] = {b0.x, b0.y, b0.z, b0.w, b1.x, b1.y, b1.z, b1.w};
            #pragma unroll
            for (int i = 0; i < 8; ++i)
                #pragma unroll
                for (int j = 0; j < 8; ++j)
                    acc[i][j] += av[i] * bv[j];
        }
        __syncthreads();
    }
    const int half = (n0 >= nsplit) ? 1 : 0;
    const float* bp = half ? bias1 : bias0;
    const int nl = n0 - (half ? nsplit : 0);
    #pragma unroll
    for (int i = 0; i < 8; ++i) {
        const int row = m0 + tm4 + (i >> 2) * 64 + (i & 3);
        #pragma unroll
        for (int jh = 0; jh < 2; ++jh) {
            float v[4];
            #pragma unroll
            for (int j = 0; j < 4; ++j) {
                float x = acc[i][jh * 4 + j];
                if (bp) x += bp[nl + tn4 + jh * 64 + j];
                if (act_tanh) x = tanhf_fast(x);
                v[j] = x;
            }
            *(float4*)(C + (size_t)row * ldc + n0 + tn4 + jh * 64) =
                make_float4(v[0], v[1], v[2], v[3]);
        }
    }
}

// ---------------- BiLSTM scan: MFMA + wave-local gates ---------------------
// 128 blocks x 512 thr. bx = s*16 + gid; gid = dir*8+qg (16 batch rows),
// s = 0..7 (32 h-dims). Wave w covers dims [s*32+w*4, +4) x ALL 4 gates:
// B-fragment col c -> W col (c>>2)*256 + s*32 + w*4 + (c&3). After MFMA,
// gates of a (batch,dim) live in lanes l, l^4, l^8, l^12 -> 3 shfl_xor +
// select; c_state in-lane (4 batch rows, x4 redundant across gate lanes).
// No zbuf, 2 barriers/step, all-thread flag poll. R8 flag protocol.
__global__ __launch_bounds__(512, 2) void k_scan10(
    const float* __restrict__ Zin, const float* __restrict__ WtF,
    const float* __restrict__ WtB, float* __restrict__ outbuf,
    int bt_layout, unsigned int* __restrict__ hx32, int* __restrict__ flags,
    int bx_base)
{
    __shared__ __align__(16) unsigned short hbh[16 * 264];
    __shared__ __align__(16) unsigned short hbl[16 * 264];
    __shared__ __align__(16) float zlds[16 * 132];

    const int bx  = blockIdx.x + bx_base;
    const int gid = bx & 15;           // dir*8 + qg
    const int s   = bx >> 4;           // 0..7 dim slice
    const int dir = gid >> 3;
    const int qg  = gid & 7;
    const int tid = threadIdx.x;
    const int w   = tid >> 6;          // wave 0..7 -> dims w*4..w*4+3
    const int l   = tid & 63;
    const int lr  = l & 15;            // fragment col c
    const int rg  = l >> 4;            // row group (4 batch rows)
    const int lk8 = rg * 8;
    const int gt  = lr >> 2;           // my gate
    const int d   = lr & 3;            // my dim offset
    const float* __restrict__ Wt = dir ? WtB : WtF;

    // ---- W preload: col(c) = (c>>2)*256 + s*32 + w*4 + (c&3) ----
    const int colg = gt * 256 + s * 32 + w * 4 + d;
    bf16x8 wbh[8], wbl[8];
    #pragma unroll
    for (int kf = 0; kf < 8; ++kf) {
        ushort ph[8], pl[8];
        #pragma unroll
        for (int j = 0; j < 8; ++j) {
            const int k = kf * 32 + lk8 + j;
            const float v = Wt[(size_t)k * 1024 + colg];
            __hip_bfloat16 bh = __float2bfloat16(v);
            __hip_bfloat16 bl = __float2bfloat16(v - __bfloat162float(bh));
            ph[j] = *(ushort*)&bh; pl[j] = *(ushort*)&bl;
        }
        wbh[kf] = *(bf16x8*)ph;
        wbl[kf] = *(bf16x8*)pl;
    }

    // h staging map (u64 pairs): row = tid>>5 (batch 0..15), 8 dims each
    const int st_base = (tid >> 5) * 256 + (tid & 31) * 8;
    const int st_lds  = (tid >> 5) * 264 + (tid & 31) * 8;
    // Z staging map: row = tid>>5, gate seg = (tid>>3)&3, 4 cols
    const int zrow = tid >> 5;
    const int zseg = (tid >> 3) & 3;
    const int zf4  = (tid & 7) * 4;
    const int fbase = gid * 64;

    float c_state[4] = {0.f, 0.f, 0.f, 0.f};

    for (int tt = 0; tt < 64; ++tt) {
        const int t = dir ? (63 - tt) : tt;
        // ---- Z prefetch (independent of h; overlaps poll) ----
        const float4 zv = *(const float4*)(Zin +
            (size_t)(t * 128 + qg * 16 + zrow) * 2048 + dir * 1024 + zseg * 256 + s * 32 + zf4);
        if (tt > 0) {
            // ---- all-thread poll ----
            while (__hip_atomic_load(&flags[fbase + tt - 1], __ATOMIC_RELAXED,
                                     __HIP_MEMORY_SCOPE_AGENT) < 8)
                __builtin_amdgcn_s_sleep(1);
            // ---- stage h (4 u64 loads -> unpack hi/lo) ----
            const unsigned long long* hs64 = (const unsigned long long*)
                (hx32 + ((size_t)(((tt - 1) & 1) * 16 + gid)) * 4096 + st_base);
            unsigned int hp[4], lp[4];
            #pragma unroll
            for (int j = 0; j < 4; ++j) {
                const unsigned long long q = __hip_atomic_load(&hs64[j], __ATOMIC_RELAXED,
                                                               __HIP_MEMORY_SCOPE_AGENT);
                const unsigned int w0 = (unsigned int)q;
                const unsigned int w1 = (unsigned int)(q >> 32);
                hp[j] = (w0 >> 16) | (w1 & 0xFFFF0000u);
                lp[j] = (w0 & 0xFFFFu) | (w1 << 16);
            }
            *(uint4*)&hbh[st_lds] = make_uint4(hp[0], hp[1], hp[2], hp[3]);
            *(uint4*)&hbl[st_lds] = make_uint4(lp[0], lp[1], lp[2], lp[3]);
        }
        // ---- stage Z ----
        *(float4*)&zlds[zrow * 132 + zseg * 32 + zf4] = zv;
        __syncthreads();
        // ---- MFMA (skip at tt=0: h=0) ----
        f32x4 acc = (f32x4){0.f, 0.f, 0.f, 0.f};
        if (tt > 0) {
            #pragma unroll
            for (int kf = 0; kf < 8; ++kf) {
                const int ao = lr * 264 + kf * 32 + lk8;
                const bf16x8 ah = *(const bf16x8*)&hbh[ao];
                const bf16x8 al = *(const bf16x8*)&hbl[ao];
                acc = __builtin_amdgcn_mfma_f32_16x16x32_bf16(ah, wbh[kf], acc, 0, 0, 0);
                acc = __builtin_amdgcn_mfma_f32_16x16x32_bf16(ah, wbl[kf], acc, 0, 0, 0);
                acc = __builtin_amdgcn_mfma_f32_16x16x32_bf16(al, wbh[kf], acc, 0, 0, 0);
            }
        }
        // ---- add Z, collect gates in-wave, update state, publish ----
        #pragma unroll
        for (int j = 0; j < 4; ++j) {
            const float zt = acc[j] + zlds[(rg * 4 + j) * 132 + gt * 32 + w * 4 + d];
            const float v4  = __shfl_xor(zt, 4);
            const float v8  = __shfl_xor(zt, 8);
            const float v12 = __shfl_xor(zt, 12);
            const float zi = (gt == 0) ? zt : (gt == 1) ? v4 : (gt == 2) ? v8 : v12;
            const float zf = (gt == 1) ? zt : (gt == 0) ? v4 : (gt == 3) ? v8 : v12;
            const float zg = (gt == 2) ? zt : (gt == 3) ? v4 : (gt == 0) ? v8 : v12;
            const float zo = (gt == 3) ? zt : (gt == 2) ? v4 : (gt == 1) ? v8 : v12;
            c_state[j] = sigf(zf) * c_state[j] + sigf(zi) * tanhf_fast(zg);
            const float h = sigf(zo) * tanhf_fast(c_state[j]);
            if (gt == 0) {
                const int bglob = qg * 16 + rg * 4 + j;
                const int dim = s * 32 + w * 4 + d;
                const int row = bt_layout ? (bglob * 64 + t) : (t * 128 + bglob);
                outbuf[(size_t)row * 512 + dir * 256 + dim] = h;
                __hip_bfloat16 bh = __float2bfloat16(h);
                __hip_bfloat16 bl = __float2bfloat16(h - __bfloat162float(bh));
                const unsigned int pk = ((unsigned int)(*(ushort*)&bh) << 16) | (*(ushort*)&bl);
                __hip_atomic_store(
                    &hx32[((size_t)((tt & 1) * 16 + gid)) * 4096 + (rg * 4 + j) * 256 + dim],
                    pk, __ATOMIC_RELAXED, __HIP_MEMORY_SCOPE_AGENT);
            }
        }
        __syncthreads();  // vmcnt(0) drain: publishes complete before flag add
        if (tid == 0)
            __hip_atomic_fetch_add(&flags[fbase + tt], 1, __ATOMIC_RELAXED,
                                   __HIP_MEMORY_SCOPE_AGENT);
    }
}

// ---------------- attention pooling (unchanged) ----------------------------
__global__ __launch_bounds__(256) void k_attnpool(
    const float* __restrict__ hbar, const float* __restrict__ outp,
    const float* __restrict__ ws2, float* __restrict__ sent)
{
    __shared__ float hb[64][132];
    __shared__ float w2[8][128];
    __shared__ float att[8][64];
    const int b = blockIdx.x, tid = threadIdx.x;
    for (int i = tid; i < 1024; i += 256) ((float*)w2)[i] = ws2[i];
    const float* hsrc = hbar + (size_t)b * 64 * 128;
    for (int i = tid; i < 2048; i += 256) {
        const int row = i >> 5, d4 = (i & 31) << 2;
        *(float4*)&hb[row][d4] = *(const float4*)(hsrc + row * 128 + d4);
    }
    __syncthreads();
    for (int p = tid; p < 512; p += 256) {
        const int r = p >> 6, t = p & 63;
        float s = 0.0f;
        #pragma unroll 8
        for (int d = 0; d < 128; d += 4) {
            const float4 x = *(const float4*)&hb[t][d];
            const float4 y = *(const float4*)&w2[r][d];
            s += x.x * y.x + x.y * y.y + x.z * y.z + x.w * y.w;
        }
        att[r][t] = s;
    }
    __syncthreads();
    const float* ob = outp + (size_t)b * 64 * 512;
    float s0[8] = {}, s1[8] = {};
    for (int t = 0; t < 64; ++t) {
        const float v0 = ob[t * 512 + tid];
        const float v1 = ob[t * 512 + 256 + tid];
        #pragma unroll
        for (int r = 0; r < 8; ++r) {
            const float a = att[r][t];
            s0[r] += a * v0; s1[r] += a * v1;
        }
    }
    #pragma unroll
    for (int r = 0; r < 8; ++r) {
        sent[((size_t)b * 8 + r) * 512 + tid]       = s0[r];
        sent[((size_t)b * 8 + r) * 512 + 256 + tid] = s1[r];
    }
}

// ---------------- dynamic routing (unchanged) ------------------------------
__global__ __launch_bounds__(512) void k_routing(
    const float* __restrict__ votes, float* __restrict__ out)
{
    __shared__ float v[8][32][16];
    __shared__ float logits[8][32];
    __shared__ float route[8][32];
    const int b = blockIdx.x, tid = threadIdx.x;
    const float* vb = votes + (size_t)b * 4096;
    for (int i = tid; i < 4096; i += 512) ((float*)v)[i] = vb[i];
    if (tid < 256) ((float*)logits)[tid] = 0.0f;
    __syncthreads();
    const int c = tid >> 4, a = tid & 15;
    float n2 = 0.0f;
    for (int it = 0; it < 3; ++it) {
        if (tid < 256) {
            const int r = tid >> 5, cc = tid & 31;
            const float l = logits[r][cc];
            float mx = l;
            #pragma unroll
            for (int m = 1; m < 32; m <<= 1) mx = fmaxf(mx, __shfl_xor(mx, m));
            const float e = __expf(l - mx);
            float sm = e;
            #pragma unroll
            for (int m = 1; m < 32; m <<= 1) sm += __shfl_xor(sm, m);
            route[r][cc] = e / sm;
        }
        __syncthreads();
        float pa = 0.0f;
        #pragma unroll
        for (int r = 0; r < 8; ++r) pa += route[r][c] * v[r][c][a];
        n2 = pa * pa;
        #pragma unroll
        for (int m = 1; m < 16; m <<= 1) n2 += __shfl_xor(n2, m);
        const float nrm = sqrtf(n2);
        const float av = pa * (nrm / (0.5f + n2));
        if (it < 2) {
            #pragma unroll
            for (int r = 0; r < 8; ++r) {
                float u = v[r][c][a] * av;
                #pragma unroll
                for (int m = 1; m < 16; m <<= 1) u += __shfl_xor(u, m);
                if (a == 0) logits[r][c] += u;
            }
        }
        __syncthreads();
    }
    if (a == 0) out[b * 32 + c] = n2 / (0.5f + n2);
}

// ---------------------------------------------------------------------------
static void launch_scan(const float* Z, const float* wf, const float* wb,
                        float* ob, int bt, unsigned int* hx32, int* fl,
                        hipStream_t stream)
{
    int base0 = 0;
    void* args[] = {(void*)&Z, (void*)&wf, (void*)&wb, (void*)&ob,
                    (void*)&bt, (void*)&hx32, (void*)&fl, (void*)&base0};
    if (hipLaunchCooperativeKernel((const void*)k_scan10, dim3(128), dim3(512),
                                   args, 0, stream) != hipSuccess) {
        k_scan10<<<dim3(128), 512, 0, stream>>>(Z, wf, wb, ob, bt, hx32, fl, 0);
    }
}

extern "C" void kernel_launch(void* const* d_in, const int* in_sizes, int n_in,
                              void* d_out, int out_size, void* d_ws, size_t ws_size,
                              hipStream_t stream) {
    (void)in_sizes; (void)n_in; (void)out_size; (void)ws_size;
    const int*   tokens  = (const int*)d_in[0];
    const float* emb     = (const float*)d_in[2];
    const float* w_ih_f0 = (const float*)d_in[3];
    const float* w_hh_f0 = (const float*)d_in[4];
    const float* b_f0    = (const float*)d_in[5];
    const float* w_ih_b0 = (const float*)d_in[6];
    const float* w_hh_b0 = (const float*)d_in[7];
    const float* b_b0    = (const float*)d_in[8];
    const float* w_ih_f1 = (const float*)d_in[9];
    const float* w_hh_f1 = (const float*)d_in[10];
    const float* b_f1    = (const float*)d_in[11];
    const float* w_ih_b1 = (const float*)d_in[12];
    const float* w_hh_b1 = (const float*)d_in[13];
    const float* b_b1    = (const float*)d_in[14];
    const float* ws1     = (const float*)d_in[15];
    const float* ws2     = (const float*)d_in[16];
    const float* caps    = (const float*)d_in[17];

    float* wsf  = (float*)d_ws;
    float* Wt   = wsf;                          //  4 * 262144
    float* Z    = Wt   + 4 * 262144;            //  8192*2048
    float* x1   = Z    + 16777216;              //  8192*512
    float* outp = x1   + 4194304;               //  8192*512
    float* hbar = outp + 4194304;               //  8192*128
    float* sent = hbar + 1048576;               //  128*8*512
    float* vote = sent + 524288;                //  128*8*512
    unsigned int* hx32 = (unsigned int*)(vote + 524288);  // 2*16*4096 u32
    int*   flags = (int*)(hx32 + 131072);       //  8192 ints
    float* out  = (float*)d_out;

    // 0. zero sync flags (every launch; replays don't re-poison)
    k_zero<<<dim3(32), 256, 0, stream>>>(flags, 8192);
    // 1. transpose recurrent weights
    k_transpose<<<dim3(32, 8, 4), dim3(32, 8), 0, stream>>>(w_hh_f0, w_hh_b0, w_hh_f1, w_hh_b1, Wt);
    // 2. layer-0 projection (bf16x3 MFMA, inline gather+split) -> Z
    k_mgemm<<<dim3(64, 16), 256, 0, stream>>>(
        emb, 300, tokens, w_ih_f0, w_ih_b0, 300, b_f0, b_b0, Z, 2048, 300, 320, 0);
    // 3. layer-0 scan -> x1 [t*128+b][512]
    launch_scan(Z, Wt, Wt + 262144, x1, 0, hx32, flags, stream);
    // 4. layer-1 projection (bf16x3 MFMA, inline split) -> Z
    k_mgemm<<<dim3(64, 16), 256, 0, stream>>>(
        x1, 512, (const int*)nullptr, w_ih_f1, w_ih_b1, 512, b_f1, b_b1, Z, 2048, 512, 512, 0);
    // 5. layer-1 scan -> outp [b*64+t][512]
    launch_scan(Z, Wt + 2 * 262144, Wt + 3 * 262144, outp, 1, hx32, flags + 4096, stream);
    // 6. hbar = tanh(outp @ ws1^T)  (MFMA + fused tanh)
    k_mgemm<<<dim3(64, 1), 256, 0, stream>>>(
        outp, 512, (const int*)nullptr, ws1, ws1, 512,
        (const float*)nullptr, (const float*)nullptr, hbar, 128, 512, 512, 1);
    // 7. attention + sent
    k_attnpool<<<dim3(128), 256, 0, stream>>>(hbar, outp, ws2, sent);
    // 8. votes
    k_gemm<<<dim3(1, 4, 8), 256, 0, stream>>>(
        sent, 4096, (const int*)nullptr, caps, (const float*)nullptr, 1 << 30, 512,
        (const float*)nullptr, (const float*)nullptr,
        vote, 4096, 512, 0, 0, 512LL, 262144LL, 512LL);
    // 9. routing
    k_routing<<<dim3(128), 512, 0, stream>>>(vote, out);
}

// Round 16
// 678.164 us; speedup vs baseline: 1.1172x; 1.1172x over previous
//
#include <hip/hip_runtime.h>
#include <hip/hip_bf16.h>

// ---------------------------------------------------------------------------
// CapsuleNetwork: embedding -> 2-layer BiLSTM -> attn pooling -> routing
// Round 15: revert scan to R13 k_scan9 (best, 154us) with ONE change:
// all-thread flag polling (drops tid0-poll + broadcast barrier; 3 bars/step).
// Everything else identical to R13 (total 579us).
// B=128 T=64 E=300 H=256 DA=128 R=8 SC=32 AT=16
// ---------------------------------------------------------------------------

typedef __attribute__((ext_vector_type(8))) short bf16x8;
typedef __attribute__((ext_vector_type(4))) float f32x4;

__device__ __forceinline__ float sigf(float x) { return 1.0f / (1.0f + __expf(-x)); }
__device__ __forceinline__ float tanhf_fast(float x) { return 1.0f - 2.0f / (__expf(2.0f * x) + 1.0f); }

// ---------------- transpose w_hh [1024][256] -> Wt [256][1024] -------------
__global__ void k_transpose(const float* __restrict__ w0, const float* __restrict__ w1,
                            const float* __restrict__ w2, const float* __restrict__ w3,
                            float* __restrict__ wt)
{
    __shared__ float tile[32][33];
    const float* W = (blockIdx.z == 0) ? w0 : (blockIdx.z == 1) ? w1 : (blockIdx.z == 2) ? w2 : w3;
    float* Wt = wt + (size_t)blockIdx.z * 256 * 1024;
    const int j0 = blockIdx.x * 32, k0 = blockIdx.y * 32;
    const int tx = threadIdx.x, ty = threadIdx.y;  // (32,8)
    #pragma unroll
    for (int i = 0; i < 32; i += 8)
        tile[ty + i][tx] = W[(size_t)(j0 + ty + i) * 256 + (k0 + tx)];
    __syncthreads();
    #pragma unroll
    for (int i = 0; i < 32; i += 8)
        Wt[(size_t)(k0 + ty + i) * 1024 + (j0 + tx)] = tile[tx][ty + i];
}

// ---------------- zero words -----------------------------------------------
__global__ void k_zero(int* __restrict__ p, int n)
{
    const int i = blockIdx.x * blockDim.x + threadIdx.x;
    if (i < n) p[i] = 0;
}

// ---------------- bf16x3 MFMA GEMM with INLINE fp32->hi/lo split -----------
__global__ __launch_bounds__(256) void k_mgemm(
    const float* __restrict__ A, int lda, const int* __restrict__ tokens,
    const float* __restrict__ W0, const float* __restrict__ W1, int ldw,
    const float* __restrict__ bias0, const float* __restrict__ bias1,
    float* __restrict__ C, int ldc, int Kin, int Kp, int act_tanh)
{
    __shared__ unsigned short lAh[128 * 40];
    __shared__ unsigned short lAl[128 * 40];
    __shared__ unsigned short lBh[128 * 40];
    __shared__ unsigned short lBl[128 * 40];

    const int tid = threadIdx.x;
    const int m0 = blockIdx.x * 128;
    const int n0 = blockIdx.y * 128;
    const int w  = tid >> 6, l = tid & 63;
    const int wm = (w >> 1) * 64, wn = (w & 1) * 64;
    const int lr = l & 15, lk = (l >> 4) * 8;

    int srow[2], sk8[2];
    const float* arow[2];
    const float* wrow[2];
    #pragma unroll
    for (int p = 0; p < 2; ++p) {
        const int chunk = tid + p * 256;
        srow[p] = chunk >> 2;
        sk8[p]  = (chunk & 3) * 8;
        const int am = m0 + srow[p];
        if (tokens) {
            const int t = am >> 7, b = am & 127;
            arow[p] = A + (size_t)tokens[b * 64 + t] * lda;
        } else {
            arow[p] = A + (size_t)am * lda;
        }
        const int wnr = n0 + srow[p];
        wrow[p] = (wnr < 1024) ? (W0 + (size_t)wnr * ldw)
                               : (W1 + (size_t)(wnr - 1024) * ldw);
    }

    f32x4 acc[4][4];
    #pragma unroll
    for (int i = 0; i < 4; ++i)
        #pragma unroll
        for (int j = 0; j < 4; ++j)
            acc[i][j] = (f32x4){0.f, 0.f, 0.f, 0.f};

    float fa[2][8], fw[2][8];
    #pragma unroll
    for (int p = 0; p < 2; ++p) {
        const int k0 = sk8[p];
        if (k0 + 7 < Kin) {
            const float4 a0 = *(const float4*)(arow[p] + k0);
            const float4 a1 = *(const float4*)(arow[p] + k0 + 4);
            fa[p][0]=a0.x; fa[p][1]=a0.y; fa[p][2]=a0.z; fa[p][3]=a0.w;
            fa[p][4]=a1.x; fa[p][5]=a1.y; fa[p][6]=a1.z; fa[p][7]=a1.w;
            const float4 b0 = *(const float4*)(wrow[p] + k0);
            const float4 b1 = *(const float4*)(wrow[p] + k0 + 4);
            fw[p][0]=b0.x; fw[p][1]=b0.y; fw[p][2]=b0.z; fw[p][3]=b0.w;
            fw[p][4]=b1.x; fw[p][5]=b1.y; fw[p][6]=b1.z; fw[p][7]=b1.w;
        } else {
            #pragma unroll
            for (int j = 0; j < 8; ++j) {
                fa[p][j] = (k0 + j < Kin) ? arow[p][k0 + j] : 0.0f;
                fw[p][j] = (k0 + j < Kin) ? wrow[p][k0 + j] : 0.0f;
            }
        }
    }

    for (int kt = 0; kt < Kp; kt += 32) {
        #pragma unroll
        for (int p = 0; p < 2; ++p) {
            const int la = srow[p] * 40 + sk8[p];
            ushort hA[8], lA[8], hW[8], lW[8];
            #pragma unroll
            for (int j = 0; j < 8; ++j) {
                __hip_bfloat16 bh = __float2bfloat16(fa[p][j]);
                const float fh = __bfloat162float(bh);
                __hip_bfloat16 bl = __float2bfloat16(fa[p][j] - fh);
                hA[j] = *(ushort*)&bh; lA[j] = *(ushort*)&bl;
                __hip_bfloat16 wh = __float2bfloat16(fw[p][j]);
                const float fwh = __bfloat162float(wh);
                __hip_bfloat16 wl = __float2bfloat16(fw[p][j] - fwh);
                hW[j] = *(ushort*)&wh; lW[j] = *(ushort*)&wl;
            }
            *(bf16x8*)&lAh[la] = *(bf16x8*)hA;
            *(bf16x8*)&lAl[la] = *(bf16x8*)lA;
            *(bf16x8*)&lBh[la] = *(bf16x8*)hW;
            *(bf16x8*)&lBl[la] = *(bf16x8*)lW;
        }
        __syncthreads();
        if (kt + 32 < Kp) {
            #pragma unroll
            for (int p = 0; p < 2; ++p) {
                const int k0 = kt + 32 + sk8[p];
                if (k0 + 7 < Kin) {
                    const float4 a0 = *(const float4*)(arow[p] + k0);
                    const float4 a1 = *(const float4*)(arow[p] + k0 + 4);
                    fa[p][0]=a0.x; fa[p][1]=a0.y; fa[p][2]=a0.z; fa[p][3]=a0.w;
                    fa[p][4]=a1.x; fa[p][5]=a1.y; fa[p][6]=a1.z; fa[p][7]=a1.w;
                    const float4 b0 = *(const float4*)(wrow[p] + k0);
                    const float4 b1 = *(const float4*)(wrow[p] + k0 + 4);
                    fw[p][0]=b0.x; fw[p][1]=b0.y; fw[p][2]=b0.z; fw[p][3]=b0.w;
                    fw[p][4]=b1.x; fw[p][5]=b1.y; fw[p][6]=b1.z; fw[p][7]=b1.w;
                } else {
                    #pragma unroll
                    for (int j = 0; j < 8; ++j) {
                        fa[p][j] = (k0 + j < Kin) ? arow[p][k0 + j] : 0.0f;
                        fw[p][j] = (k0 + j < Kin) ? wrow[p][k0 + j] : 0.0f;
                    }
                }
            }
        }
        bf16x8 ah[4], al[4], bh[4], bl[4];
        #pragma unroll
        for (int f = 0; f < 4; ++f) {
            const int ra = (wm + f * 16 + lr) * 40 + lk;
            const int rb = (wn + f * 16 + lr) * 40 + lk;
            ah[f] = *(const bf16x8*)&lAh[ra];
            al[f] = *(const bf16x8*)&lAl[ra];
            bh[f] = *(const bf16x8*)&lBh[rb];
            bl[f] = *(const bf16x8*)&lBl[rb];
        }
        #pragma unroll
        for (int fm = 0; fm < 4; ++fm)
            #pragma unroll
            for (int fn = 0; fn < 4; ++fn) {
                acc[fm][fn] = __builtin_amdgcn_mfma_f32_16x16x32_bf16(ah[fm], bh[fn], acc[fm][fn], 0, 0, 0);
                acc[fm][fn] = __builtin_amdgcn_mfma_f32_16x16x32_bf16(ah[fm], bl[fn], acc[fm][fn], 0, 0, 0);
                acc[fm][fn] = __builtin_amdgcn_mfma_f32_16x16x32_bf16(al[fm], bh[fn], acc[fm][fn], 0, 0, 0);
            }
        __syncthreads();
    }
    #pragma unroll
    for (int fm = 0; fm < 4; ++fm)
        #pragma unroll
        for (int fn = 0; fn < 4; ++fn) {
            const int col = n0 + wn + fn * 16 + lr;
            const float bv = (col < 1024) ? (bias0 ? bias0[col] : 0.f)
                                          : (bias1 ? bias1[col - 1024] : 0.f);
            #pragma unroll
            for (int j = 0; j < 4; ++j) {
                const int row = m0 + wm + fm * 16 + (l >> 4) * 4 + j;
                float x = acc[fm][fn][j] + bv;
                if (act_tanh) x = tanhf_fast(x);
                C[(size_t)row * ldc + col] = x;
            }
        }
}

// ---------------- fp32 GEMM (R6) — votes only ------------------------------
__global__ __launch_bounds__(256) void k_gemm(
    const float* __restrict__ A, int lda, const int* __restrict__ tokens,
    const float* __restrict__ W0, const float* __restrict__ W1, int nsplit, int ldw,
    const float* __restrict__ bias0, const float* __restrict__ bias1,
    float* __restrict__ C, int ldc, int K, int transb, int act_tanh,
    long long sA, long long sW, long long sC)
{
    __shared__ float As[32][128];
    __shared__ float Ws[32][128];
    A  += (size_t)blockIdx.z * (size_t)sA;
    W0 += (size_t)blockIdx.z * (size_t)sW;
    C  += (size_t)blockIdx.z * (size_t)sC;
    const int tid = threadIdx.x;
    const int m0 = blockIdx.x * 128;
    const int n0 = blockIdx.y * 128;

    const int srow = tid >> 1;
    const int kh   = (tid & 1) * 16;
    const int am = m0 + srow;
    const float* arow;
    if (tokens) {
        const int t = am >> 7, b = am & 127;
        arow = A + (size_t)tokens[b * 64 + t] * lda;
    } else {
        arow = A + (size_t)am * lda;
    }
    const int wn = n0 + srow;
    const float* wrow = (wn < nsplit) ? (W0 + (size_t)wn * ldw)
                                      : (W1 + (size_t)(wn - nsplit) * ldw);
    const int kw = tid >> 3;
    const int n8 = (tid & 7) * 16;

    const int tm4 = (tid & 15) * 4;
    const int tn4 = (tid >> 4) * 4;
    float acc[8][8] = {};
    float4 ra[4], rw[4];

    const int nt = (K + 31) / 32;

    #pragma unroll
    for (int j = 0; j < 4; ++j) {
        const int k = kh + j * 4;
        if (k + 3 < K) ra[j] = *(const float4*)(arow + k);
        else {
            float t0 = (k + 0 < K) ? arow[k + 0] : 0.f;
            float t1 = (k + 1 < K) ? arow[k + 1] : 0.f;
            float t2 = (k + 2 < K) ? arow[k + 2] : 0.f;
            float t3 = (k + 3 < K) ? arow[k + 3] : 0.f;
            ra[j] = make_float4(t0, t1, t2, t3);
        }
    }
    if (transb) {
        #pragma unroll
        for (int j = 0; j < 4; ++j) {
            const int k = kh + j * 4;
            if (k + 3 < K) rw[j] = *(const float4*)(wrow + k);
            else {
                float t0 = (k + 0 < K) ? wrow[k + 0] : 0.f;
                float t1 = (k + 1 < K) ? wrow[k + 1] : 0.f;
                float t2 = (k + 2 < K) ? wrow[k + 2] : 0.f;
                float t3 = (k + 3 < K) ? wrow[k + 3] : 0.f;
                rw[j] = make_float4(t0, t1, t2, t3);
            }
        }
    } else {
        const float* src = (kw < K) ? (W0 + (size_t)kw * ldw + n0 + n8) : W0;
        #pragma unroll
        for (int j = 0; j < 4; ++j)
            rw[j] = (kw < K) ? *(const float4*)(src + j * 4) : make_float4(0, 0, 0, 0);
    }

    for (int tile = 0; tile < nt; ++tile) {
        #pragma unroll
        for (int j = 0; j < 4; ++j) {
            As[kh + j * 4 + 0][srow] = ra[j].x;
            As[kh + j * 4 + 1][srow] = ra[j].y;
            As[kh + j * 4 + 2][srow] = ra[j].z;
            As[kh + j * 4 + 3][srow] = ra[j].w;
        }
        if (transb) {
            #pragma unroll
            for (int j = 0; j < 4; ++j) {
                Ws[kh + j * 4 + 0][srow] = rw[j].x;
                Ws[kh + j * 4 + 1][srow] = rw[j].y;
                Ws[kh + j * 4 + 2][srow] = rw[j].z;
                Ws[kh + j * 4 + 3][srow] = rw[j].w;
            }
        } else {
            #pragma unroll
            for (int j = 0; j < 4; ++j)
                *(float4*)&Ws[kw][n8 + j * 4] = rw[j];
        }
        __syncthreads();
        if (tile + 1 < nt) {
            const int kb = (tile + 1) * 32;
            #pragma unroll
            for (int j = 0; j < 4; ++j) {
                const int k = kb + kh + j * 4;
                if (k + 3 < K) ra[j] = *(const float4*)(arow + k);
                else {
                    float t0 = (k + 0 < K) ? arow[k + 0] : 0.f;
                    float t1 = (k + 1 < K) ? arow[k + 1] : 0.f;
                    float t2 = (k + 2 < K) ? arow[k + 2] : 0.f;
                    float t3 = (k + 3 < K) ? arow[k + 3] : 0.f;
                    ra[j] = make_float4(t0, t1, t2, t3);
                }
            }
            if (transb) {
                #pragma unroll
                for (int j = 0; j < 4; ++j) {
                    const int k = kb + kh + j * 4;
                    if (k + 3 < K) rw[j] = *(const float4*)(wrow + k);
                    else {
                        float t0 = (k + 0 < K) ? wrow[k + 0] : 0.f;
                        float t1 = (k + 1 < K) ? wrow[k + 1] : 0.f;
                        float t2 = (k + 2 < K) ? wrow[k + 2] : 0.f;
                        float t3 = (k + 3 < K) ? wrow[k + 3] : 0.f;
                        rw[j] = make_float4(t0, t1, t2, t3);
                    }
                }
            } else {
                const int k = kb + kw;
                const float* src = (k < K) ? (W0 + (size_t)k * ldw + n0 + n8) : W0;
                #pragma unroll
                for (int j = 0; j < 4; ++j)
                    rw[j] = (k < K) ? *(const float4*)(src + j * 4) : make_float4(0, 0, 0, 0);
            }
        }
        #pragma unroll 8
        for (int kk = 0; kk < 32; ++kk) {
            const float4 a0 = *(const float4*)&As[kk][tm4];
            const float4 a1 = *(const float4*)&As[kk][tm4 + 64];
            const float4 b0 = *(const float4*)&Ws[kk][tn4];
            const float4 b1 = *(const float4*)&Ws[kk][tn4 + 64];
            const float av[8] = {a0.x, a0.y, a0.z, a0.w, a1.x, a1.y, a1.z, a1.w};
            const float bv[8] = {b0.x, b0.y, b0.z, b0.w, b1.x, b1.y, b1.z, b1.w};
            #pragma unroll
            for (int i = 0; i < 8; ++i)
                #pragma unroll
                for (int j = 0; j < 8; ++j)
                    acc[i][j] += av[i] * bv[j];
        }
        __syncthreads();
    }
    const int half = (n0 >= nsplit) ? 1 : 0;
    const float* bp = half ? bias1 : bias0;
    const int nl = n0 - (half ? nsplit : 0);
    #pragma unroll
    for (int i = 0; i < 8; ++i) {
        const int row = m0 + tm4 + (i >> 2) * 64 + (i & 3);
        #pragma unroll
        for (int jh = 0; jh < 2; ++jh) {
            float v[4];
            #pragma unroll
            for (int j = 0; j < 4; ++j) {
                float x = acc[i][jh * 4 + j];
                if (bp) x += bp[nl + tn4 + jh * 64 + j];
                if (act_tanh) x = tanhf_fast(x);
                v[j] = x;
            }
            *(float4*)(C + (size_t)row * ldc + n0 + tn4 + jh * 64) =
                make_float4(v[0], v[1], v[2], v[3]);
        }
    }
}

// ---------------- BiLSTM scan: MFMA recurrence (R13 + all-thread poll) -----
// 128 blocks x 512 thr (8 waves). bx = s*16 + g: g = dir*8+qg (16 batch
// rows), s = 0..7 (32 h-dims). Per step: z[16b][128c] = h[16][256] @ W via
// bf16x3 MFMA. Wave w = col-fragment (gate w>>1, dim-half w&1); W resident
// as bf16 hi/lo frags. h exchanged as u32 (hi16|lo16) bf16 pairs; staged to
// LDS [16][264] u16. R8 flag protocol; ALL-THREAD poll (3 barriers/step).
__global__ __launch_bounds__(512, 2) void k_scan9(
    const float* __restrict__ Zin, const float* __restrict__ WtF,
    const float* __restrict__ WtB, float* __restrict__ outbuf,
    int bt_layout, unsigned int* __restrict__ hx32, int* __restrict__ flags,
    int bx_base)
{
    __shared__ __align__(16) unsigned short hbh[16 * 264];
    __shared__ __align__(16) unsigned short hbl[16 * 264];
    __shared__ float zbuf[8 * 16 * 17];          // [frag][bi][17]

    const int bx  = blockIdx.x + bx_base;
    const int g   = bx & 15;           // dir*8 + qg
    const int s   = bx >> 4;           // 0..7 dim slice
    const int dir = g >> 3;
    const int qg  = g & 7;
    const int tid = threadIdx.x;
    const int w   = tid >> 6;          // wave = fragment 0..7
    const int l   = tid & 63;
    const int lr  = l & 15;
    const int lk8 = (l >> 4) * 8;
    const float* __restrict__ Wt = dir ? WtB : WtF;

    // ---- W preload: fragment w -> gate = w>>1, dim-half = w&1 ----
    const int colg = (w >> 1) * 256 + s * 32 + (w & 1) * 16 + lr;
    bf16x8 wbh[8], wbl[8];
    #pragma unroll
    for (int kf = 0; kf < 8; ++kf) {
        ushort ph[8], pl[8];
        #pragma unroll
        for (int j = 0; j < 8; ++j) {
            const int k = kf * 32 + lk8 + j;
            const float v = Wt[(size_t)k * 1024 + colg];
            __hip_bfloat16 bh = __float2bfloat16(v);
            __hip_bfloat16 bl = __float2bfloat16(v - __bfloat162float(bh));
            ph[j] = *(ushort*)&bh; pl[j] = *(ushort*)&bl;
        }
        wbh[kf] = *(bf16x8*)ph;
        wbl[kf] = *(bf16x8*)pl;
    }

    // phase-2 / publish mapping: bi = tid>>5 (16 batch), di = tid&31 (32 dims)
    const int bi  = tid >> 5;
    const int di  = tid & 31;
    const int gb  = qg * 16 + bi;
    const int dim = s * 32 + di;
    float c_state = 0.0f;
    const int fbase = g * 64;
    // staging map: row = tid>>5, k8 = (tid&31)*8
    const int st_base = (tid >> 5) * 256 + (tid & 31) * 8;
    const int st_lds  = (tid >> 5) * 264 + (tid & 31) * 8;

    for (int tt = 0; tt < 64; ++tt) {
        const int t = dir ? (63 - tt) : tt;
        // Z prefetch (independent of h; overlaps poll)
        const float* zr = Zin + (size_t)(t * 128 + gb) * 2048 + dir * 1024 + dim;
        const float z0 = zr[0], z1 = zr[256], z2 = zr[512], z3 = zr[768];
        if (tt > 0) {
            // ---- all-thread poll (no broadcast barrier) ----
            while (__hip_atomic_load(&flags[fbase + tt - 1], __ATOMIC_RELAXED,
                                     __HIP_MEMORY_SCOPE_AGENT) < 8)
                __builtin_amdgcn_s_sleep(1);
            // ---- stage h: 8 u32 (4 u64 loads), unpack to bf16 hi/lo LDS ----
            {
                const unsigned long long* hs64 = (const unsigned long long*)
                    (hx32 + ((size_t)(((tt - 1) & 1) * 16 + g)) * 4096 + st_base);
                unsigned int hp[4], lp[4];
                #pragma unroll
                for (int j = 0; j < 4; ++j) {
                    const unsigned long long q = __hip_atomic_load(&hs64[j], __ATOMIC_RELAXED,
                                                                   __HIP_MEMORY_SCOPE_AGENT);
                    const unsigned int w0 = (unsigned int)q;
                    const unsigned int w1 = (unsigned int)(q >> 32);
                    hp[j] = (w0 >> 16) | (w1 & 0xFFFF0000u);
                    lp[j] = (w0 & 0xFFFFu) | (w1 << 16);
                }
                *(uint4*)&hbh[st_lds] = make_uint4(hp[0], hp[1], hp[2], hp[3]);
                *(uint4*)&hbl[st_lds] = make_uint4(lp[0], lp[1], lp[2], lp[3]);
            }
            __syncthreads();
            // ---- MFMA: 8 k-frags x 3 products ----
            f32x4 acc = (f32x4){0.f, 0.f, 0.f, 0.f};
            #pragma unroll
            for (int kf = 0; kf < 8; ++kf) {
                const int ao = lr * 264 + kf * 32 + lk8;
                const bf16x8 ah = *(const bf16x8*)&hbh[ao];
                const bf16x8 al = *(const bf16x8*)&hbl[ao];
                acc = __builtin_amdgcn_mfma_f32_16x16x32_bf16(ah, wbh[kf], acc, 0, 0, 0);
                acc = __builtin_amdgcn_mfma_f32_16x16x32_bf16(ah, wbl[kf], acc, 0, 0, 0);
                acc = __builtin_amdgcn_mfma_f32_16x16x32_bf16(al, wbh[kf], acc, 0, 0, 0);
            }
            // C layout: col = lr, row_b = (l>>4)*4 + j
            #pragma unroll
            for (int j = 0; j < 4; ++j)
                zbuf[(w * 16 + (l >> 4) * 4 + j) * 17 + lr] = acc[j];
            __syncthreads();
        } else {
            for (int i = tid; i < 2176; i += 512) zbuf[i] = 0.0f;
            __syncthreads();
        }
        // ---- phase 2: gates, state, publish (all 512 threads) ----
        {
            const int dh = di >> 4, dl = di & 15;
            const float zi = zbuf[((0 * 2 + dh) * 16 + bi) * 17 + dl] + z0;
            const float zf = zbuf[((1 * 2 + dh) * 16 + bi) * 17 + dl] + z1;
            const float zg = zbuf[((2 * 2 + dh) * 16 + bi) * 17 + dl] + z2;
            const float zo = zbuf[((3 * 2 + dh) * 16 + bi) * 17 + dl] + z3;
            c_state = sigf(zf) * c_state + sigf(zi) * tanhf_fast(zg);
            const float h = sigf(zo) * tanhf_fast(c_state);
            const int row = bt_layout ? (gb * 64 + t) : (t * 128 + gb);
            outbuf[(size_t)row * 512 + dir * 256 + dim] = h;
            __hip_bfloat16 bh = __float2bfloat16(h);
            __hip_bfloat16 bl = __float2bfloat16(h - __bfloat162float(bh));
            const unsigned int pk = ((unsigned int)(*(ushort*)&bh) << 16) | (*(ushort*)&bl);
            __hip_atomic_store(
                &hx32[((size_t)((tt & 1) * 16 + g)) * 4096 + bi * 256 + dim],
                pk, __ATOMIC_RELAXED, __HIP_MEMORY_SCOPE_AGENT);
        }
        __syncthreads();  // vmcnt(0) drain: publishes complete before flag add
        if (tid == 0)
            __hip_atomic_fetch_add(&flags[fbase + tt], 1, __ATOMIC_RELAXED,
                                   __HIP_MEMORY_SCOPE_AGENT);
    }
}

// ---------------- attention pooling (unchanged) ----------------------------
__global__ __launch_bounds__(256) void k_attnpool(
    const float* __restrict__ hbar, const float* __restrict__ outp,
    const float* __restrict__ ws2, float* __restrict__ sent)
{
    __shared__ float hb[64][132];
    __shared__ float w2[8][128];
    __shared__ float att[8][64];
    const int b = blockIdx.x, tid = threadIdx.x;
    for (int i = tid; i < 1024; i += 256) ((float*)w2)[i] = ws2[i];
    const float* hsrc = hbar + (size_t)b * 64 * 128;
    for (int i = tid; i < 2048; i += 256) {
        const int row = i >> 5, d4 = (i & 31) << 2;
        *(float4*)&hb[row][d4] = *(const float4*)(hsrc + row * 128 + d4);
    }
    __syncthreads();
    for (int p = tid; p < 512; p += 256) {
        const int r = p >> 6, t = p & 63;
        float s = 0.0f;
        #pragma unroll 8
        for (int d = 0; d < 128; d += 4) {
            const float4 x = *(const float4*)&hb[t][d];
            const float4 y = *(const float4*)&w2[r][d];
            s += x.x * y.x + x.y * y.y + x.z * y.z + x.w * y.w;
        }
        att[r][t] = s;
    }
    __syncthreads();
    const float* ob = outp + (size_t)b * 64 * 512;
    float s0[8] = {}, s1[8] = {};
    for (int t = 0; t < 64; ++t) {
        const float v0 = ob[t * 512 + tid];
        const float v1 = ob[t * 512 + 256 + tid];
        #pragma unroll
        for (int r = 0; r < 8; ++r) {
            const float a = att[r][t];
            s0[r] += a * v0; s1[r] += a * v1;
        }
    }
    #pragma unroll
    for (int r = 0; r < 8; ++r) {
        sent[((size_t)b * 8 + r) * 512 + tid]       = s0[r];
        sent[((size_t)b * 8 + r) * 512 + 256 + tid] = s1[r];
    }
}

// ---------------- dynamic routing (unchanged) ------------------------------
__global__ __launch_bounds__(512) void k_routing(
    const float* __restrict__ votes, float* __restrict__ out)
{
    __shared__ float v[8][32][16];
    __shared__ float logits[8][32];
    __shared__ float route[8][32];
    const int b = blockIdx.x, tid = threadIdx.x;
    const float* vb = votes + (size_t)b * 4096;
    for (int i = tid; i < 4096; i += 512) ((float*)v)[i] = vb[i];
    if (tid < 256) ((float*)logits)[tid] = 0.0f;
    __syncthreads();
    const int c = tid >> 4, a = tid & 15;
    float n2 = 0.0f;
    for (int it = 0; it < 3; ++it) {
        if (tid < 256) {
            const int r = tid >> 5, cc = tid & 31;
            const float l = logits[r][cc];
            float mx = l;
            #pragma unroll
            for (int m = 1; m < 32; m <<= 1) mx = fmaxf(mx, __shfl_xor(mx, m));
            const float e = __expf(l - mx);
            float sm = e;
            #pragma unroll
            for (int m = 1; m < 32; m <<= 1) sm += __shfl_xor(sm, m);
            route[r][cc] = e / sm;
        }
        __syncthreads();
        float pa = 0.0f;
        #pragma unroll
        for (int r = 0; r < 8; ++r) pa += route[r][c] * v[r][c][a];
        n2 = pa * pa;
        #pragma unroll
        for (int m = 1; m < 16; m <<= 1) n2 += __shfl_xor(n2, m);
        const float nrm = sqrtf(n2);
        const float av = pa * (nrm / (0.5f + n2));
        if (it < 2) {
            #pragma unroll
            for (int r = 0; r < 8; ++r) {
                float u = v[r][c][a] * av;
                #pragma unroll
                for (int m = 1; m < 16; m <<= 1) u += __shfl_xor(u, m);
                if (a == 0) logits[r][c] += u;
            }
        }
        __syncthreads();
    }
    if (a == 0) out[b * 32 + c] = n2 / (0.5f + n2);
}

// ---------------------------------------------------------------------------
static void launch_scan(const float* Z, const float* wf, const float* wb,
                        float* ob, int bt, unsigned int* hx32, int* fl,
                        hipStream_t stream)
{
    int base0 = 0;
    void* args[] = {(void*)&Z, (void*)&wf, (void*)&wb, (void*)&ob,
                    (void*)&bt, (void*)&hx32, (void*)&fl, (void*)&base0};
    if (hipLaunchCooperativeKernel((const void*)k_scan9, dim3(128), dim3(512),
                                   args, 0, stream) != hipSuccess) {
        // 128 blocks <= 256 CUs: all resident under plain launch too.
        k_scan9<<<dim3(128), 512, 0, stream>>>(Z, wf, wb, ob, bt, hx32, fl, 0);
    }
}

extern "C" void kernel_launch(void* const* d_in, const int* in_sizes, int n_in,
                              void* d_out, int out_size, void* d_ws, size_t ws_size,
                              hipStream_t stream) {
    (void)in_sizes; (void)n_in; (void)out_size; (void)ws_size;
    const int*   tokens  = (const int*)d_in[0];
    const float* emb     = (const float*)d_in[2];
    const float* w_ih_f0 = (const float*)d_in[3];
    const float* w_hh_f0 = (const float*)d_in[4];
    const float* b_f0    = (const float*)d_in[5];
    const float* w_ih_b0 = (const float*)d_in[6];
    const float* w_hh_b0 = (const float*)d_in[7];
    const float* b_b0    = (const float*)d_in[8];
    const float* w_ih_f1 = (const float*)d_in[9];
    const float* w_hh_f1 = (const float*)d_in[10];
    const float* b_f1    = (const float*)d_in[11];
    const float* w_ih_b1 = (const float*)d_in[12];
    const float* w_hh_b1 = (const float*)d_in[13];
    const float* b_b1    = (const float*)d_in[14];
    const float* ws1     = (const float*)d_in[15];
    const float* ws2     = (const float*)d_in[16];
    const float* caps    = (const float*)d_in[17];

    float* wsf  = (float*)d_ws;
    float* Wt   = wsf;                          //  4 * 262144
    float* Z    = Wt   + 4 * 262144;            //  8192*2048
    float* x1   = Z    + 16777216;               //  8192*512
    float* outp = x1   + 4194304;               //  8192*512
    float* hbar = outp + 4194304;               //  8192*128
    float* sent = hbar + 1048576;               //  128*8*512
    float* vote = sent + 524288;                //  128*8*512
    unsigned int* hx32 = (unsigned int*)(vote + 524288);  // 2*16*4096 u32
    int*   flags = (int*)(hx32 + 131072);       //  8192 ints
    float* out  = (float*)d_out;

    // 0. zero sync flags (every launch; replays don't re-poison)
    k_zero<<<dim3(32), 256, 0, stream>>>(flags, 8192);
    // 1. transpose recurrent weights
    k_transpose<<<dim3(32, 8, 4), dim3(32, 8), 0, stream>>>(w_hh_f0, w_hh_b0, w_hh_f1, w_hh_b1, Wt);
    // 2. layer-0 projection (bf16x3 MFMA, inline gather+split) -> Z
    k_mgemm<<<dim3(64, 16), 256, 0, stream>>>(
        emb, 300, tokens, w_ih_f0, w_ih_b0, 300, b_f0, b_b0, Z, 2048, 300, 320, 0);
    // 3. layer-0 scan -> x1 [t*128+b][512]
    launch_scan(Z, Wt, Wt + 262144, x1, 0, hx32, flags, stream);
    // 4. layer-1 projection (bf16x3 MFMA, inline split) -> Z
    k_mgemm<<<dim3(64, 16), 256, 0, stream>>>(
        x1, 512, (const int*)nullptr, w_ih_f1, w_ih_b1, 512, b_f1, b_b1, Z, 2048, 512, 512, 0);
    // 5. layer-1 scan -> outp [b*64+t][512]
    launch_scan(Z, Wt + 2 * 262144, Wt + 3 * 262144, outp, 1, hx32, flags + 4096, stream);
    // 6. hbar = tanh(outp @ ws1^T)  (MFMA + fused tanh)
    k_mgemm<<<dim3(64, 1), 256, 0, stream>>>(
        outp, 512, (const int*)nullptr, ws1, ws1, 512,
        (const float*)nullptr, (const float*)nullptr, hbar, 128, 512, 512, 1);
    // 7. attention + sent
    k_attnpool<<<dim3(128), 256, 0, stream>>>(hbar, outp, ws2, sent);
    // 8. votes
    k_gemm<<<dim3(1, 4, 8), 256, 0, stream>>>(
        sent, 4096, (const int*)nullptr, caps, (const float*)nullptr, 1 << 30, 512,
        (const float*)nullptr, (const float*)nullptr,
        vote, 4096, 512, 0, 0, 512LL, 262144LL, 512LL);
    // 9. routing
    k_routing<<<dim3(128), 512, 0, stream>>>(vote, out);
}

// Round 17
// 594.869 us; speedup vs baseline: 1.2737x; 1.1400x over previous
//
#include <hip/hip_runtime.h>
#include <hip/hip_bf16.h>

// ---------------------------------------------------------------------------
// CapsuleNetwork: embedding -> 2-layer BiLSTM -> attn pooling -> routing
// Round 16: revert to R13 tid0-poll (R15's all-thread poll = coherence-point
// contention, 154->208). Scan batch-split: 32 groups (2dir x 16 groups of 8
// batch rows) x 8 slice-blocks = 256 blocks -> 2/CU; co-resident blocks are
// in different sync groups so poll stalls overlap compute. MFMA unchanged
// (A rows 8-15 zeroed). Group stays 8 members (flag traffic unchanged).
// B=128 T=64 E=300 H=256 DA=128 R=8 SC=32 AT=16
// ---------------------------------------------------------------------------

typedef __attribute__((ext_vector_type(8))) short bf16x8;
typedef __attribute__((ext_vector_type(4))) float f32x4;

__device__ __forceinline__ float sigf(float x) { return 1.0f / (1.0f + __expf(-x)); }
__device__ __forceinline__ float tanhf_fast(float x) { return 1.0f - 2.0f / (__expf(2.0f * x) + 1.0f); }

// ---------------- transpose w_hh [1024][256] -> Wt [256][1024] -------------
__global__ void k_transpose(const float* __restrict__ w0, const float* __restrict__ w1,
                            const float* __restrict__ w2, const float* __restrict__ w3,
                            float* __restrict__ wt)
{
    __shared__ float tile[32][33];
    const float* W = (blockIdx.z == 0) ? w0 : (blockIdx.z == 1) ? w1 : (blockIdx.z == 2) ? w2 : w3;
    float* Wt = wt + (size_t)blockIdx.z * 256 * 1024;
    const int j0 = blockIdx.x * 32, k0 = blockIdx.y * 32;
    const int tx = threadIdx.x, ty = threadIdx.y;  // (32,8)
    #pragma unroll
    for (int i = 0; i < 32; i += 8)
        tile[ty + i][tx] = W[(size_t)(j0 + ty + i) * 256 + (k0 + tx)];
    __syncthreads();
    #pragma unroll
    for (int i = 0; i < 32; i += 8)
        Wt[(size_t)(k0 + ty + i) * 1024 + (j0 + tx)] = tile[tx][ty + i];
}

// ---------------- zero words -----------------------------------------------
__global__ void k_zero(int* __restrict__ p, int n)
{
    const int i = blockIdx.x * blockDim.x + threadIdx.x;
    if (i < n) p[i] = 0;
}

// ---------------- bf16x3 MFMA GEMM with INLINE fp32->hi/lo split -----------
__global__ __launch_bounds__(256) void k_mgemm(
    const float* __restrict__ A, int lda, const int* __restrict__ tokens,
    const float* __restrict__ W0, const float* __restrict__ W1, int ldw,
    const float* __restrict__ bias0, const float* __restrict__ bias1,
    float* __restrict__ C, int ldc, int Kin, int Kp, int act_tanh)
{
    __shared__ unsigned short lAh[128 * 40];
    __shared__ unsigned short lAl[128 * 40];
    __shared__ unsigned short lBh[128 * 40];
    __shared__ unsigned short lBl[128 * 40];

    const int tid = threadIdx.x;
    const int m0 = blockIdx.x * 128;
    const int n0 = blockIdx.y * 128;
    const int w  = tid >> 6, l = tid & 63;
    const int wm = (w >> 1) * 64, wn = (w & 1) * 64;
    const int lr = l & 15, lk = (l >> 4) * 8;

    int srow[2], sk8[2];
    const float* arow[2];
    const float* wrow[2];
    #pragma unroll
    for (int p = 0; p < 2; ++p) {
        const int chunk = tid + p * 256;
        srow[p] = chunk >> 2;
        sk8[p]  = (chunk & 3) * 8;
        const int am = m0 + srow[p];
        if (tokens) {
            const int t = am >> 7, b = am & 127;
            arow[p] = A + (size_t)tokens[b * 64 + t] * lda;
        } else {
            arow[p] = A + (size_t)am * lda;
        }
        const int wnr = n0 + srow[p];
        wrow[p] = (wnr < 1024) ? (W0 + (size_t)wnr * ldw)
                               : (W1 + (size_t)(wnr - 1024) * ldw);
    }

    f32x4 acc[4][4];
    #pragma unroll
    for (int i = 0; i < 4; ++i)
        #pragma unroll
        for (int j = 0; j < 4; ++j)
            acc[i][j] = (f32x4){0.f, 0.f, 0.f, 0.f};

    float fa[2][8], fw[2][8];
    #pragma unroll
    for (int p = 0; p < 2; ++p) {
        const int k0 = sk8[p];
        if (k0 + 7 < Kin) {
            const float4 a0 = *(const float4*)(arow[p] + k0);
            const float4 a1 = *(const float4*)(arow[p] + k0 + 4);
            fa[p][0]=a0.x; fa[p][1]=a0.y; fa[p][2]=a0.z; fa[p][3]=a0.w;
            fa[p][4]=a1.x; fa[p][5]=a1.y; fa[p][6]=a1.z; fa[p][7]=a1.w;
            const float4 b0 = *(const float4*)(wrow[p] + k0);
            const float4 b1 = *(const float4*)(wrow[p] + k0 + 4);
            fw[p][0]=b0.x; fw[p][1]=b0.y; fw[p][2]=b0.z; fw[p][3]=b0.w;
            fw[p][4]=b1.x; fw[p][5]=b1.y; fw[p][6]=b1.z; fw[p][7]=b1.w;
        } else {
            #pragma unroll
            for (int j = 0; j < 8; ++j) {
                fa[p][j] = (k0 + j < Kin) ? arow[p][k0 + j] : 0.0f;
                fw[p][j] = (k0 + j < Kin) ? wrow[p][k0 + j] : 0.0f;
            }
        }
    }

    for (int kt = 0; kt < Kp; kt += 32) {
        #pragma unroll
        for (int p = 0; p < 2; ++p) {
            const int la = srow[p] * 40 + sk8[p];
            ushort hA[8], lA[8], hW[8], lW[8];
            #pragma unroll
            for (int j = 0; j < 8; ++j) {
                __hip_bfloat16 bh = __float2bfloat16(fa[p][j]);
                const float fh = __bfloat162float(bh);
                __hip_bfloat16 bl = __float2bfloat16(fa[p][j] - fh);
                hA[j] = *(ushort*)&bh; lA[j] = *(ushort*)&bl;
                __hip_bfloat16 wh = __float2bfloat16(fw[p][j]);
                const float fwh = __bfloat162float(wh);
                __hip_bfloat16 wl = __float2bfloat16(fw[p][j] - fwh);
                hW[j] = *(ushort*)&wh; lW[j] = *(ushort*)&wl;
            }
            *(bf16x8*)&lAh[la] = *(bf16x8*)hA;
            *(bf16x8*)&lAl[la] = *(bf16x8*)lA;
            *(bf16x8*)&lBh[la] = *(bf16x8*)hW;
            *(bf16x8*)&lBl[la] = *(bf16x8*)lW;
        }
        __syncthreads();
        if (kt + 32 < Kp) {
            #pragma unroll
            for (int p = 0; p < 2; ++p) {
                const int k0 = kt + 32 + sk8[p];
                if (k0 + 7 < Kin) {
                    const float4 a0 = *(const float4*)(arow[p] + k0);
                    const float4 a1 = *(const float4*)(arow[p] + k0 + 4);
                    fa[p][0]=a0.x; fa[p][1]=a0.y; fa[p][2]=a0.z; fa[p][3]=a0.w;
                    fa[p][4]=a1.x; fa[p][5]=a1.y; fa[p][6]=a1.z; fa[p][7]=a1.w;
                    const float4 b0 = *(const float4*)(wrow[p] + k0);
                    const float4 b1 = *(const float4*)(wrow[p] + k0 + 4);
                    fw[p][0]=b0.x; fw[p][1]=b0.y; fw[p][2]=b0.z; fw[p][3]=b0.w;
                    fw[p][4]=b1.x; fw[p][5]=b1.y; fw[p][6]=b1.z; fw[p][7]=b1.w;
                } else {
                    #pragma unroll
                    for (int j = 0; j < 8; ++j) {
                        fa[p][j] = (k0 + j < Kin) ? arow[p][k0 + j] : 0.0f;
                        fw[p][j] = (k0 + j < Kin) ? wrow[p][k0 + j] : 0.0f;
                    }
                }
            }
        }
        bf16x8 ah[4], al[4], bh[4], bl[4];
        #pragma unroll
        for (int f = 0; f < 4; ++f) {
            const int ra = (wm + f * 16 + lr) * 40 + lk;
            const int rb = (wn + f * 16 + lr) * 40 + lk;
            ah[f] = *(const bf16x8*)&lAh[ra];
            al[f] = *(const bf16x8*)&lAl[ra];
            bh[f] = *(const bf16x8*)&lBh[rb];
            bl[f] = *(const bf16x8*)&lBl[rb];
        }
        #pragma unroll
        for (int fm = 0; fm < 4; ++fm)
            #pragma unroll
            for (int fn = 0; fn < 4; ++fn) {
                acc[fm][fn] = __builtin_amdgcn_mfma_f32_16x16x32_bf16(ah[fm], bh[fn], acc[fm][fn], 0, 0, 0);
                acc[fm][fn] = __builtin_amdgcn_mfma_f32_16x16x32_bf16(ah[fm], bl[fn], acc[fm][fn], 0, 0, 0);
                acc[fm][fn] = __builtin_amdgcn_mfma_f32_16x16x32_bf16(al[fm], bh[fn], acc[fm][fn], 0, 0, 0);
            }
        __syncthreads();
    }
    #pragma unroll
    for (int fm = 0; fm < 4; ++fm)
        #pragma unroll
        for (int fn = 0; fn < 4; ++fn) {
            const int col = n0 + wn + fn * 16 + lr;
            const float bv = (col < 1024) ? (bias0 ? bias0[col] : 0.f)
                                          : (bias1 ? bias1[col - 1024] : 0.f);
            #pragma unroll
            for (int j = 0; j < 4; ++j) {
                const int row = m0 + wm + fm * 16 + (l >> 4) * 4 + j;
                float x = acc[fm][fn][j] + bv;
                if (act_tanh) x = tanhf_fast(x);
                C[(size_t)row * ldc + col] = x;
            }
        }
}

// ---------------- fp32 GEMM (R6) — votes only ------------------------------
__global__ __launch_bounds__(256) void k_gemm(
    const float* __restrict__ A, int lda, const int* __restrict__ tokens,
    const float* __restrict__ W0, const float* __restrict__ W1, int nsplit, int ldw,
    const float* __restrict__ bias0, const float* __restrict__ bias1,
    float* __restrict__ C, int ldc, int K, int transb, int act_tanh,
    long long sA, long long sW, long long sC)
{
    __shared__ float As[32][128];
    __shared__ float Ws[32][128];
    A  += (size_t)blockIdx.z * (size_t)sA;
    W0 += (size_t)blockIdx.z * (size_t)sW;
    C  += (size_t)blockIdx.z * (size_t)sC;
    const int tid = threadIdx.x;
    const int m0 = blockIdx.x * 128;
    const int n0 = blockIdx.y * 128;

    const int srow = tid >> 1;
    const int kh   = (tid & 1) * 16;
    const int am = m0 + srow;
    const float* arow;
    if (tokens) {
        const int t = am >> 7, b = am & 127;
        arow = A + (size_t)tokens[b * 64 + t] * lda;
    } else {
        arow = A + (size_t)am * lda;
    }
    const int wn = n0 + srow;
    const float* wrow = (wn < nsplit) ? (W0 + (size_t)wn * ldw)
                                      : (W1 + (size_t)(wn - nsplit) * ldw);
    const int kw = tid >> 3;
    const int n8 = (tid & 7) * 16;

    const int tm4 = (tid & 15) * 4;
    const int tn4 = (tid >> 4) * 4;
    float acc[8][8] = {};
    float4 ra[4], rw[4];

    const int nt = (K + 31) / 32;

    #pragma unroll
    for (int j = 0; j < 4; ++j) {
        const int k = kh + j * 4;
        if (k + 3 < K) ra[j] = *(const float4*)(arow + k);
        else {
            float t0 = (k + 0 < K) ? arow[k + 0] : 0.f;
            float t1 = (k + 1 < K) ? arow[k + 1] : 0.f;
            float t2 = (k + 2 < K) ? arow[k + 2] : 0.f;
            float t3 = (k + 3 < K) ? arow[k + 3] : 0.f;
            ra[j] = make_float4(t0, t1, t2, t3);
        }
    }
    if (transb) {
        #pragma unroll
        for (int j = 0; j < 4; ++j) {
            const int k = kh + j * 4;
            if (k + 3 < K) rw[j] = *(const float4*)(wrow + k);
            else {
                float t0 = (k + 0 < K) ? wrow[k + 0] : 0.f;
                float t1 = (k + 1 < K) ? wrow[k + 1] : 0.f;
                float t2 = (k + 2 < K) ? wrow[k + 2] : 0.f;
                float t3 = (k + 3 < K) ? wrow[k + 3] : 0.f;
                rw[j] = make_float4(t0, t1, t2, t3);
            }
        }
    } else {
        const float* src = (kw < K) ? (W0 + (size_t)kw * ldw + n0 + n8) : W0;
        #pragma unroll
        for (int j = 0; j < 4; ++j)
            rw[j] = (kw < K) ? *(const float4*)(src + j * 4) : make_float4(0, 0, 0, 0);
    }

    for (int tile = 0; tile < nt; ++tile) {
        #pragma unroll
        for (int j = 0; j < 4; ++j) {
            As[kh + j * 4 + 0][srow] = ra[j].x;
            As[kh + j * 4 + 1][srow] = ra[j].y;
            As[kh + j * 4 + 2][srow] = ra[j].z;
            As[kh + j * 4 + 3][srow] = ra[j].w;
        }
        if (transb) {
            #pragma unroll
            for (int j = 0; j < 4; ++j) {
                Ws[kh + j * 4 + 0][srow] = rw[j].x;
                Ws[kh + j * 4 + 1][srow] = rw[j].y;
                Ws[kh + j * 4 + 2][srow] = rw[j].z;
                Ws[kh + j * 4 + 3][srow] = rw[j].w;
            }
        } else {
            #pragma unroll
            for (int j = 0; j < 4; ++j)
                *(float4*)&Ws[kw][n8 + j * 4] = rw[j];
        }
        __syncthreads();
        if (tile + 1 < nt) {
            const int kb = (tile + 1) * 32;
            #pragma unroll
            for (int j = 0; j < 4; ++j) {
                const int k = kb + kh + j * 4;
                if (k + 3 < K) ra[j] = *(const float4*)(arow + k);
                else {
                    float t0 = (k + 0 < K) ? arow[k + 0] : 0.f;
                    float t1 = (k + 1 < K) ? arow[k + 1] : 0.f;
                    float t2 = (k + 2 < K) ? arow[k + 2] : 0.f;
                    float t3 = (k + 3 < K) ? arow[k + 3] : 0.f;
                    ra[j] = make_float4(t0, t1, t2, t3);
                }
            }
            if (transb) {
                #pragma unroll
                for (int j = 0; j < 4; ++j) {
                    const int k = kb + kh + j * 4;
                    if (k + 3 < K) rw[j] = *(const float4*)(wrow + k);
                    else {
                        float t0 = (k + 0 < K) ? wrow[k + 0] : 0.f;
                        float t1 = (k + 1 < K) ? wrow[k + 1] : 0.f;
                        float t2 = (k + 2 < K) ? wrow[k + 2] : 0.f;
                        float t3 = (k + 3 < K) ? wrow[k + 3] : 0.f;
                        rw[j] = make_float4(t0, t1, t2, t3);
                    }
                }
            } else {
                const int k = kb + kw;
                const float* src = (k < K) ? (W0 + (size_t)k * ldw + n0 + n8) : W0;
                #pragma unroll
                for (int j = 0; j < 4; ++j)
                    rw[j] = (k < K) ? *(const float4*)(src + j * 4) : make_float4(0, 0, 0, 0);
            }
        }
        #pragma unroll 8
        for (int kk = 0; kk < 32; ++kk) {
            const float4 a0 = *(const float4*)&As[kk][tm4];
            const float4 a1 = *(const float4*)&As[kk][tm4 + 64];
            const float4 b0 = *(const float4*)&Ws[kk][tn4];
            const float4 b1 = *(const float4*)&Ws[kk][tn4 + 64];
            const float av[8] = {a0.x, a0.y, a0.z, a0.w, a1.x, a1.y, a1.z, a1.w};
            const float bv[8] = {b0.x, b0.y, b0.z, b0.w, b1.x, b1.y, b1.z, b1.w};
            #pragma unroll
            for (int i = 0; i < 8; ++i)
                #pragma unroll
                for (int j = 0; j < 8; ++j)
                    acc[i][j] += av[i] * bv[j];
        }
        __syncthreads();
    }
    const int half = (n0 >= nsplit) ? 1 : 0;
    const float* bp = half ? bias1 : bias0;
    const int nl = n0 - (half ? nsplit : 0);
    #pragma unroll
    for (int i = 0; i < 8; ++i) {
        const int row = m0 + tm4 + (i >> 2) * 64 + (i & 3);
        #pragma unroll
        for (int jh = 0; jh < 2; ++jh) {
            float v[4];
            #pragma unroll
            for (int j = 0; j < 4; ++j) {
                float x = acc[i][jh * 4 + j];
                if (bp) x += bp[nl + tn4 + jh * 64 + j];
                if (act_tanh) x = tanhf_fast(x);
                v[j] = x;
            }
            *(float4*)(C + (size_t)row * ldc + n0 + tn4 + jh * 64) =
                make_float4(v[0], v[1], v[2], v[3]);
        }
    }
}

// ---------------- BiLSTM scan: MFMA, batch-split (2 blocks/CU) -------------
// 256 blocks x 512 thr. bx = s*32 + g: g = dir*16 + qg (8 batch rows/group),
// s = 0..7 (32 h-dims). Group = 8 slice-blocks (same g). Per step:
// z[8b][128c] = h[8][256] @ W-slice via bf16x3 MFMA (A rows 8-15 zero).
// tid0 poll + broadcast barrier (R13 protocol; R15 showed all-thread poll
// regresses via coherence-point contention). h exchanged as packed u32.
__global__ __launch_bounds__(512, 2) void k_scan11(
    const float* __restrict__ Zin, const float* __restrict__ WtF,
    const float* __restrict__ WtB, float* __restrict__ outbuf,
    int bt_layout, unsigned int* __restrict__ hx32, int* __restrict__ flags,
    int bx_base)
{
    __shared__ __align__(16) unsigned short hbh[16 * 264];
    __shared__ __align__(16) unsigned short hbl[16 * 264];
    __shared__ float zbuf[8 * 16 * 17];          // [frag][bi][17]

    const int bx  = blockIdx.x + bx_base;
    const int g   = bx & 31;           // dir*16 + qg
    const int s   = bx >> 5;           // 0..7 dim slice
    const int dir = g >> 4;
    const int qg  = g & 15;
    const int tid = threadIdx.x;
    const int w   = tid >> 6;          // wave = col fragment 0..7
    const int l   = tid & 63;
    const int lr  = l & 15;
    const int lk8 = (l >> 4) * 8;
    const float* __restrict__ Wt = dir ? WtB : WtF;

    // ---- W preload: fragment w -> gate = w>>1, dim-half = w&1 ----
    const int colg = (w >> 1) * 256 + s * 32 + (w & 1) * 16 + lr;
    bf16x8 wbh[8], wbl[8];
    #pragma unroll
    for (int kf = 0; kf < 8; ++kf) {
        ushort ph[8], pl[8];
        #pragma unroll
        for (int j = 0; j < 8; ++j) {
            const int k = kf * 32 + lk8 + j;
            const float v = Wt[(size_t)k * 1024 + colg];
            __hip_bfloat16 bh = __float2bfloat16(v);
            __hip_bfloat16 bl = __float2bfloat16(v - __bfloat162float(bh));
            ph[j] = *(ushort*)&bh; pl[j] = *(ushort*)&bl;
        }
        wbh[kf] = *(bf16x8*)ph;
        wbl[kf] = *(bf16x8*)pl;
    }

    // ---- zero h LDS once (rows 8-15 stay zero forever) ----
    for (int i = tid; i < 16 * 264; i += 512) { hbh[i] = 0; hbl[i] = 0; }

    // phase-2 / publish mapping (tid<256): bi = tid>>5 (8 batch), di = tid&31
    const int bi  = tid >> 5;          // 0..7 valid when tid<256
    const int di  = tid & 31;
    const int gb  = qg * 8 + (bi & 7);
    const int dim = s * 32 + di;
    float c_state = 0.0f;
    const int fbase = g * 64;
    // staging map (tid<256): row = tid>>5 (0..7), 8 dims each
    const int st_base = (tid >> 5) * 256 + (tid & 31) * 8;
    const int st_lds  = (tid >> 5) * 264 + (tid & 31) * 8;

    __syncthreads();  // LDS zero visible

    for (int tt = 0; tt < 64; ++tt) {
        const int t = dir ? (63 - tt) : tt;
        // Z prefetch (independent of h; overlaps poll)
        float z0 = 0.f, z1 = 0.f, z2 = 0.f, z3 = 0.f;
        if (tid < 256) {
            const float* zr = Zin + (size_t)(t * 128 + gb) * 2048 + dir * 1024 + dim;
            z0 = zr[0]; z1 = zr[256]; z2 = zr[512]; z3 = zr[768];
        }
        if (tt > 0) {
            if (tid == 0) {
                while (__hip_atomic_load(&flags[fbase + tt - 1], __ATOMIC_RELAXED,
                                         __HIP_MEMORY_SCOPE_AGENT) < 8)
                    __builtin_amdgcn_s_sleep(1);
            }
            __syncthreads();
            // ---- stage h: 8 rows x 256 dims as packed u32 (4 u64/thread) ----
            if (tid < 256) {
                const unsigned long long* hs64 = (const unsigned long long*)
                    (hx32 + ((size_t)(((tt - 1) & 1) * 32 + g)) * 2048 + st_base);
                unsigned int hp[4], lp[4];
                #pragma unroll
                for (int j = 0; j < 4; ++j) {
                    const unsigned long long q = __hip_atomic_load(&hs64[j], __ATOMIC_RELAXED,
                                                                   __HIP_MEMORY_SCOPE_AGENT);
                    const unsigned int w0 = (unsigned int)q;
                    const unsigned int w1 = (unsigned int)(q >> 32);
                    hp[j] = (w0 >> 16) | (w1 & 0xFFFF0000u);
                    lp[j] = (w0 & 0xFFFFu) | (w1 << 16);
                }
                *(uint4*)&hbh[st_lds] = make_uint4(hp[0], hp[1], hp[2], hp[3]);
                *(uint4*)&hbl[st_lds] = make_uint4(lp[0], lp[1], lp[2], lp[3]);
            }
            __syncthreads();
            // ---- MFMA: 8 k-frags x 3 products (A rows 8-15 zero) ----
            f32x4 acc = (f32x4){0.f, 0.f, 0.f, 0.f};
            #pragma unroll
            for (int kf = 0; kf < 8; ++kf) {
                const int ao = lr * 264 + kf * 32 + lk8;
                const bf16x8 ah = *(const bf16x8*)&hbh[ao];
                const bf16x8 al = *(const bf16x8*)&hbl[ao];
                acc = __builtin_amdgcn_mfma_f32_16x16x32_bf16(ah, wbh[kf], acc, 0, 0, 0);
                acc = __builtin_amdgcn_mfma_f32_16x16x32_bf16(ah, wbl[kf], acc, 0, 0, 0);
                acc = __builtin_amdgcn_mfma_f32_16x16x32_bf16(al, wbh[kf], acc, 0, 0, 0);
            }
            // C layout: col = lr, row_b = (l>>4)*4 + j
            #pragma unroll
            for (int j = 0; j < 4; ++j)
                zbuf[(w * 16 + (l >> 4) * 4 + j) * 17 + lr] = acc[j];
            __syncthreads();
        } else {
            for (int i = tid; i < 2176; i += 512) zbuf[i] = 0.0f;
            __syncthreads();
        }
        // ---- phase 2: gates, state, publish (tid < 256) ----
        if (tid < 256) {
            const int dh = di >> 4, dl = di & 15;
            const float zi = zbuf[((0 * 2 + dh) * 16 + bi) * 17 + dl] + z0;
            const float zf = zbuf[((1 * 2 + dh) * 16 + bi) * 17 + dl] + z1;
            const float zg = zbuf[((2 * 2 + dh) * 16 + bi) * 17 + dl] + z2;
            const float zo = zbuf[((3 * 2 + dh) * 16 + bi) * 17 + dl] + z3;
            c_state = sigf(zf) * c_state + sigf(zi) * tanhf_fast(zg);
            const float h = sigf(zo) * tanhf_fast(c_state);
            const int row = bt_layout ? (gb * 64 + t) : (t * 128 + gb);
            outbuf[(size_t)row * 512 + dir * 256 + dim] = h;
            __hip_bfloat16 bh = __float2bfloat16(h);
            __hip_bfloat16 bl = __float2bfloat16(h - __bfloat162float(bh));
            const unsigned int pk = ((unsigned int)(*(ushort*)&bh) << 16) | (*(ushort*)&bl);
            __hip_atomic_store(
                &hx32[((size_t)((tt & 1) * 32 + g)) * 2048 + bi * 256 + dim],
                pk, __ATOMIC_RELAXED, __HIP_MEMORY_SCOPE_AGENT);
        }
        __syncthreads();  // vmcnt(0) drain: publishes complete before flag add
        if (tid == 0)
            __hip_atomic_fetch_add(&flags[fbase + tt], 1, __ATOMIC_RELAXED,
                                   __HIP_MEMORY_SCOPE_AGENT);
    }
}

// ---------------- attention pooling (unchanged) ----------------------------
__global__ __launch_bounds__(256) void k_attnpool(
    const float* __restrict__ hbar, const float* __restrict__ outp,
    const float* __restrict__ ws2, float* __restrict__ sent)
{
    __shared__ float hb[64][132];
    __shared__ float w2[8][128];
    __shared__ float att[8][64];
    const int b = blockIdx.x, tid = threadIdx.x;
    for (int i = tid; i < 1024; i += 256) ((float*)w2)[i] = ws2[i];
    const float* hsrc = hbar + (size_t)b * 64 * 128;
    for (int i = tid; i < 2048; i += 256) {
        const int row = i >> 5, d4 = (i & 31) << 2;
        *(float4*)&hb[row][d4] = *(const float4*)(hsrc + row * 128 + d4);
    }
    __syncthreads();
    for (int p = tid; p < 512; p += 256) {
        const int r = p >> 6, t = p & 63;
        float s = 0.0f;
        #pragma unroll 8
        for (int d = 0; d < 128; d += 4) {
            const float4 x = *(const float4*)&hb[t][d];
            const float4 y = *(const float4*)&w2[r][d];
            s += x.x * y.x + x.y * y.y + x.z * y.z + x.w * y.w;
        }
        att[r][t] = s;
    }
    __syncthreads();
    const float* ob = outp + (size_t)b * 64 * 512;
    float s0[8] = {}, s1[8] = {};
    for (int t = 0; t < 64; ++t) {
        const float v0 = ob[t * 512 + tid];
        const float v1 = ob[t * 512 + 256 + tid];
        #pragma unroll
        for (int r = 0; r < 8; ++r) {
            const float a = att[r][t];
            s0[r] += a * v0; s1[r] += a * v1;
        }
    }
    #pragma unroll
    for (int r = 0; r < 8; ++r) {
        sent[((size_t)b * 8 + r) * 512 + tid]       = s0[r];
        sent[((size_t)b * 8 + r) * 512 + 256 + tid] = s1[r];
    }
}

// ---------------- dynamic routing (unchanged) ------------------------------
__global__ __launch_bounds__(512) void k_routing(
    const float* __restrict__ votes, float* __restrict__ out)
{
    __shared__ float v[8][32][16];
    __shared__ float logits[8][32];
    __shared__ float route[8][32];
    const int b = blockIdx.x, tid = threadIdx.x;
    const float* vb = votes + (size_t)b * 4096;
    for (int i = tid; i < 4096; i += 512) ((float*)v)[i] = vb[i];
    if (tid < 256) ((float*)logits)[tid] = 0.0f;
    __syncthreads();
    const int c = tid >> 4, a = tid & 15;
    float n2 = 0.0f;
    for (int it = 0; it < 3; ++it) {
        if (tid < 256) {
            const int r = tid >> 5, cc = tid & 31;
            const float l = logits[r][cc];
            float mx = l;
            #pragma unroll
            for (int m = 1; m < 32; m <<= 1) mx = fmaxf(mx, __shfl_xor(mx, m));
            const float e = __expf(l - mx);
            float sm = e;
            #pragma unroll
            for (int m = 1; m < 32; m <<= 1) sm += __shfl_xor(sm, m);
            route[r][cc] = e / sm;
        }
        __syncthreads();
        float pa = 0.0f;
        #pragma unroll
        for (int r = 0; r < 8; ++r) pa += route[r][c] * v[r][c][a];
        n2 = pa * pa;
        #pragma unroll
        for (int m = 1; m < 16; m <<= 1) n2 += __shfl_xor(n2, m);
        const float nrm = sqrtf(n2);
        const float av = pa * (nrm / (0.5f + n2));
        if (it < 2) {
            #pragma unroll
            for (int r = 0; r < 8; ++r) {
                float u = v[r][c][a] * av;
                #pragma unroll
                for (int m = 1; m < 16; m <<= 1) u += __shfl_xor(u, m);
                if (a == 0) logits[r][c] += u;
            }
        }
        __syncthreads();
    }
    if (a == 0) out[b * 32 + c] = n2 / (0.5f + n2);
}

// ---------------------------------------------------------------------------
static void launch_scan(const float* Z, const float* wf, const float* wb,
                        float* ob, int bt, unsigned int* hx32, int* fl,
                        hipStream_t stream)
{
    int base0 = 0;
    void* args[] = {(void*)&Z, (void*)&wf, (void*)&wb, (void*)&ob,
                    (void*)&bt, (void*)&hx32, (void*)&fl, (void*)&base0};
    if (hipLaunchCooperativeKernel((const void*)k_scan11, dim3(256), dim3(512),
                                   args, 0, stream) != hipSuccess) {
        // 256 blocks x 2/CU: all resident under plain launch too.
        k_scan11<<<dim3(256), 512, 0, stream>>>(Z, wf, wb, ob, bt, hx32, fl, 0);
    }
}

extern "C" void kernel_launch(void* const* d_in, const int* in_sizes, int n_in,
                              void* d_out, int out_size, void* d_ws, size_t ws_size,
                              hipStream_t stream) {
    (void)in_sizes; (void)n_in; (void)out_size; (void)ws_size;
    const int*   tokens  = (const int*)d_in[0];
    const float* emb     = (const float*)d_in[2];
    const float* w_ih_f0 = (const float*)d_in[3];
    const float* w_hh_f0 = (const float*)d_in[4];
    const float* b_f0    = (const float*)d_in[5];
    const float* w_ih_b0 = (const float*)d_in[6];
    const float* w_hh_b0 = (const float*)d_in[7];
    const float* b_b0    = (const float*)d_in[8];
    const float* w_ih_f1 = (const float*)d_in[9];
    const float* w_hh_f1 = (const float*)d_in[10];
    const float* b_f1    = (const float*)d_in[11];
    const float* w_ih_b1 = (const float*)d_in[12];
    const float* w_hh_b1 = (const float*)d_in[13];
    const float* b_b1    = (const float*)d_in[14];
    const float* ws1     = (const float*)d_in[15];
    const float* ws2     = (const float*)d_in[16];
    const float* caps    = (const float*)d_in[17];

    float* wsf  = (float*)d_ws;
    float* Wt   = wsf;                          //  4 * 262144
    float* Z    = Wt   + 4 * 262144;            //  8192*2048
    float* x1   = Z    + 16777216;              //  8192*512
    float* outp = x1   + 4194304;               //  8192*512
    float* hbar = outp + 4194304;               //  8192*128
    float* sent = hbar + 1048576;               //  128*8*512
    float* vote = sent + 524288;                //  128*8*512
    unsigned int* hx32 = (unsigned int*)(vote + 524288);  // 2*32*2048 u32
    int*   flags = (int*)(hx32 + 131072);       //  8192 ints
    float* out  = (float*)d_out;

    // 0. zero sync flags (every launch; replays don't re-poison)
    k_zero<<<dim3(32), 256, 0, stream>>>(flags, 8192);
    // 1. transpose recurrent weights
    k_transpose<<<dim3(32, 8, 4), dim3(32, 8), 0, stream>>>(w_hh_f0, w_hh_b0, w_hh_f1, w_hh_b1, Wt);
    // 2. layer-0 projection (bf16x3 MFMA, inline gather+split) -> Z
    k_mgemm<<<dim3(64, 16), 256, 0, stream>>>(
        emb, 300, tokens, w_ih_f0, w_ih_b0, 300, b_f0, b_b0, Z, 2048, 300, 320, 0);
    // 3. layer-0 scan -> x1 [t*128+b][512]
    launch_scan(Z, Wt, Wt + 262144, x1, 0, hx32, flags, stream);
    // 4. layer-1 projection (bf16x3 MFMA, inline split) -> Z
    k_mgemm<<<dim3(64, 16), 256, 0, stream>>>(
        x1, 512, (const int*)nullptr, w_ih_f1, w_ih_b1, 512, b_f1, b_b1, Z, 2048, 512, 512, 0);
    // 5. layer-1 scan -> outp [b*64+t][512]
    launch_scan(Z, Wt + 2 * 262144, Wt + 3 * 262144, outp, 1, hx32, flags + 4096, stream);
    // 6. hbar = tanh(outp @ ws1^T)  (MFMA + fused tanh)
    k_mgemm<<<dim3(64, 1), 256, 0, stream>>>(
        outp, 512, (const int*)nullptr, ws1, ws1, 512,
        (const float*)nullptr, (const float*)nullptr, hbar, 128, 512, 512, 1);
    // 7. attention + sent
    k_attnpool<<<dim3(128), 256, 0, stream>>>(hbar, outp, ws2, sent);
    // 8. votes
    k_gemm<<<dim3(1, 4, 8), 256, 0, stream>>>(
        sent, 4096, (const int*)nullptr, caps, (const float*)nullptr, 1 << 30, 512,
        (const float*)nullptr, (const float*)nullptr,
        vote, 4096, 512, 0, 0, 512LL, 262144LL, 512LL);
    // 9. routing
    k_routing<<<dim3(128), 512, 0, stream>>>(vote, out);
}

// Round 18
// 573.617 us; speedup vs baseline: 1.3208x; 1.0370x over previous
//
#include <hip/hip_runtime.h>
#include <hip/hip_bf16.h>

// ---------------------------------------------------------------------------
// CapsuleNetwork: embedding -> 2-layer BiLSTM -> attn pooling -> routing
// Round 17: scan reverted to exact R13 k_scan9 (measured floor 154us; R14/15/
// 16 alternatives all regressed). W stacks pre-split once per launch
// (k_splitw) -> mgemm B-staging is pure bf16 copy (no per-tile W re-split;
// W was being re-split 64x). A-split stays inline.
// B=128 T=64 E=300 H=256 DA=128 R=8 SC=32 AT=16
// ---------------------------------------------------------------------------

typedef __attribute__((ext_vector_type(8))) short bf16x8;
typedef __attribute__((ext_vector_type(4))) float f32x4;

__device__ __forceinline__ float sigf(float x) { return 1.0f / (1.0f + __expf(-x)); }
__device__ __forceinline__ float tanhf_fast(float x) { return 1.0f - 2.0f / (__expf(2.0f * x) + 1.0f); }

// ---------------- transpose w_hh [1024][256] -> Wt [256][1024] -------------
__global__ void k_transpose(const float* __restrict__ w0, const float* __restrict__ w1,
                            const float* __restrict__ w2, const float* __restrict__ w3,
                            float* __restrict__ wt)
{
    __shared__ float tile[32][33];
    const float* W = (blockIdx.z == 0) ? w0 : (blockIdx.z == 1) ? w1 : (blockIdx.z == 2) ? w2 : w3;
    float* Wt = wt + (size_t)blockIdx.z * 256 * 1024;
    const int j0 = blockIdx.x * 32, k0 = blockIdx.y * 32;
    const int tx = threadIdx.x, ty = threadIdx.y;  // (32,8)
    #pragma unroll
    for (int i = 0; i < 32; i += 8)
        tile[ty + i][tx] = W[(size_t)(j0 + ty + i) * 256 + (k0 + tx)];
    __syncthreads();
    #pragma unroll
    for (int i = 0; i < 32; i += 8)
        Wt[(size_t)(k0 + ty + i) * 1024 + (j0 + tx)] = tile[tx][ty + i];
}

// ---------------- zero words -----------------------------------------------
__global__ void k_zero(int* __restrict__ p, int n)
{
    const int i = blockIdx.x * blockDim.x + threadIdx.x;
    if (i < n) p[i] = 0;
}

// ---------------- W stack fp32 -> (hi,lo) bf16, K-padded -------------------
// rows 0..1023 from W0, 1024.. from W1 (W1 may be null if rows < 1024).
__global__ void k_splitw(const float* __restrict__ W0, const float* __restrict__ W1,
                         int Kin, int Kp, unsigned short* __restrict__ hi,
                         unsigned short* __restrict__ lo)
{
    const int i4 = (blockIdx.x * 256 + threadIdx.x) * 4;
    const int r = i4 / Kp;
    const int k = i4 - r * Kp;
    const float* srow = (r < 1024) ? (W0 + (size_t)r * Kin)
                                   : (W1 + (size_t)(r - 1024) * Kin);
    float e[4];
    if (k + 4 <= Kin) {
        const float4 v = *(const float4*)(srow + k);
        e[0] = v.x; e[1] = v.y; e[2] = v.z; e[3] = v.w;
    } else {
        #pragma unroll
        for (int j = 0; j < 4; ++j) e[j] = (k + j < Kin) ? srow[k + j] : 0.0f;
    }
    ushort4 hv, lv;
    #pragma unroll
    for (int j = 0; j < 4; ++j) {
        __hip_bfloat16 bh = __float2bfloat16(e[j]);
        const float fh = __bfloat162float(bh);
        __hip_bfloat16 bl = __float2bfloat16(e[j] - fh);
        ((unsigned short*)&hv)[j] = *(unsigned short*)&bh;
        ((unsigned short*)&lv)[j] = *(unsigned short*)&bl;
    }
    *(ushort4*)&hi[(size_t)r * Kp + k] = hv;
    *(ushort4*)&lo[(size_t)r * Kp + k] = lv;
}

// ---------------- bf16x3 MFMA GEMM: inline A-split, pre-split W ------------
// C[m][n] = act( sum_k A[m,k]*W[n,k] + bias[n] ). A fp32 (opt. gathered),
// split in-register at staging; W read directly as (hi,lo) bf16.
// Tile 128x128, 4 waves (2x2 of 64x64), 4x4 frags of 16x16x32, LDS stride 40.
__global__ __launch_bounds__(256) void k_mgemm2(
    const float* __restrict__ A, int lda, const int* __restrict__ tokens,
    const unsigned short* __restrict__ Whi, const unsigned short* __restrict__ Wlo,
    const float* __restrict__ bias0, const float* __restrict__ bias1,
    float* __restrict__ C, int ldc, int Kin, int Kp, int act_tanh)
{
    __shared__ unsigned short lAh[128 * 40];
    __shared__ unsigned short lAl[128 * 40];
    __shared__ unsigned short lBh[128 * 40];
    __shared__ unsigned short lBl[128 * 40];

    const int tid = threadIdx.x;
    const int m0 = blockIdx.x * 128;
    const int n0 = blockIdx.y * 128;
    const int w  = tid >> 6, l = tid & 63;
    const int wm = (w >> 1) * 64, wn = (w & 1) * 64;
    const int lr = l & 15, lk = (l >> 4) * 8;

    int srow[2], sk8[2];
    const float* arow[2];
    size_t wbase[2];
    #pragma unroll
    for (int p = 0; p < 2; ++p) {
        const int chunk = tid + p * 256;
        srow[p] = chunk >> 2;
        sk8[p]  = (chunk & 3) * 8;
        const int am = m0 + srow[p];
        if (tokens) {
            const int t = am >> 7, b = am & 127;
            arow[p] = A + (size_t)tokens[b * 64 + t] * lda;
        } else {
            arow[p] = A + (size_t)am * lda;
        }
        wbase[p] = (size_t)(n0 + srow[p]) * Kp + sk8[p];
    }

    f32x4 acc[4][4];
    #pragma unroll
    for (int i = 0; i < 4; ++i)
        #pragma unroll
        for (int j = 0; j < 4; ++j)
            acc[i][j] = (f32x4){0.f, 0.f, 0.f, 0.f};

    float fa[2][8];
    bf16x8 rwh[2], rwl[2];
    #pragma unroll
    for (int p = 0; p < 2; ++p) {
        const int k0 = sk8[p];
        if (k0 + 7 < Kin) {
            const float4 a0 = *(const float4*)(arow[p] + k0);
            const float4 a1 = *(const float4*)(arow[p] + k0 + 4);
            fa[p][0]=a0.x; fa[p][1]=a0.y; fa[p][2]=a0.z; fa[p][3]=a0.w;
            fa[p][4]=a1.x; fa[p][5]=a1.y; fa[p][6]=a1.z; fa[p][7]=a1.w;
        } else {
            #pragma unroll
            for (int j = 0; j < 8; ++j)
                fa[p][j] = (k0 + j < Kin) ? arow[p][k0 + j] : 0.0f;
        }
        rwh[p] = *(const bf16x8*)&Whi[wbase[p]];
        rwl[p] = *(const bf16x8*)&Wlo[wbase[p]];
    }

    for (int kt = 0; kt < Kp; kt += 32) {
        // ---- stage: split A in-register; copy W ----
        #pragma unroll
        for (int p = 0; p < 2; ++p) {
            const int la = srow[p] * 40 + sk8[p];
            ushort hA[8], lA[8];
            #pragma unroll
            for (int j = 0; j < 8; ++j) {
                __hip_bfloat16 bh = __float2bfloat16(fa[p][j]);
                const float fh = __bfloat162float(bh);
                __hip_bfloat16 bl = __float2bfloat16(fa[p][j] - fh);
                hA[j] = *(ushort*)&bh; lA[j] = *(ushort*)&bl;
            }
            *(bf16x8*)&lAh[la] = *(bf16x8*)hA;
            *(bf16x8*)&lAl[la] = *(bf16x8*)lA;
            *(bf16x8*)&lBh[la] = rwh[p];
            *(bf16x8*)&lBl[la] = rwl[p];
        }
        __syncthreads();
        // ---- prefetch next tile (hidden under MFMAs) ----
        if (kt + 32 < Kp) {
            #pragma unroll
            for (int p = 0; p < 2; ++p) {
                const int k0 = kt + 32 + sk8[p];
                if (k0 + 7 < Kin) {
                    const float4 a0 = *(const float4*)(arow[p] + k0);
                    const float4 a1 = *(const float4*)(arow[p] + k0 + 4);
                    fa[p][0]=a0.x; fa[p][1]=a0.y; fa[p][2]=a0.z; fa[p][3]=a0.w;
                    fa[p][4]=a1.x; fa[p][5]=a1.y; fa[p][6]=a1.z; fa[p][7]=a1.w;
                } else {
                    #pragma unroll
                    for (int j = 0; j < 8; ++j)
                        fa[p][j] = (k0 + j < Kin) ? arow[p][k0 + j] : 0.0f;
                }
                rwh[p] = *(const bf16x8*)&Whi[wbase[p] + kt + 32];
                rwl[p] = *(const bf16x8*)&Wlo[wbase[p] + kt + 32];
            }
        }
        // ---- fragments + 48 MFMAs ----
        bf16x8 ah[4], al[4], bh[4], bl[4];
        #pragma unroll
        for (int f = 0; f < 4; ++f) {
            const int ra = (wm + f * 16 + lr) * 40 + lk;
            const int rb = (wn + f * 16 + lr) * 40 + lk;
            ah[f] = *(const bf16x8*)&lAh[ra];
            al[f] = *(const bf16x8*)&lAl[ra];
            bh[f] = *(const bf16x8*)&lBh[rb];
            bl[f] = *(const bf16x8*)&lBl[rb];
        }
        #pragma unroll
        for (int fm = 0; fm < 4; ++fm)
            #pragma unroll
            for (int fn = 0; fn < 4; ++fn) {
                acc[fm][fn] = __builtin_amdgcn_mfma_f32_16x16x32_bf16(ah[fm], bh[fn], acc[fm][fn], 0, 0, 0);
                acc[fm][fn] = __builtin_amdgcn_mfma_f32_16x16x32_bf16(ah[fm], bl[fn], acc[fm][fn], 0, 0, 0);
                acc[fm][fn] = __builtin_amdgcn_mfma_f32_16x16x32_bf16(al[fm], bh[fn], acc[fm][fn], 0, 0, 0);
            }
        __syncthreads();
    }
    #pragma unroll
    for (int fm = 0; fm < 4; ++fm)
        #pragma unroll
        for (int fn = 0; fn < 4; ++fn) {
            const int col = n0 + wn + fn * 16 + lr;
            const float bv = (col < 1024) ? (bias0 ? bias0[col] : 0.f)
                                          : (bias1 ? bias1[col - 1024] : 0.f);
            #pragma unroll
            for (int j = 0; j < 4; ++j) {
                const int row = m0 + wm + fm * 16 + (l >> 4) * 4 + j;
                float x = acc[fm][fn][j] + bv;
                if (act_tanh) x = tanhf_fast(x);
                C[(size_t)row * ldc + col] = x;
            }
        }
}

// ---------------- fp32 GEMM (R6) — votes only ------------------------------
__global__ __launch_bounds__(256) void k_gemm(
    const float* __restrict__ A, int lda, const int* __restrict__ tokens,
    const float* __restrict__ W0, const float* __restrict__ W1, int nsplit, int ldw,
    const float* __restrict__ bias0, const float* __restrict__ bias1,
    float* __restrict__ C, int ldc, int K, int transb, int act_tanh,
    long long sA, long long sW, long long sC)
{
    __shared__ float As[32][128];
    __shared__ float Ws[32][128];
    A  += (size_t)blockIdx.z * (size_t)sA;
    W0 += (size_t)blockIdx.z * (size_t)sW;
    C  += (size_t)blockIdx.z * (size_t)sC;
    const int tid = threadIdx.x;
    const int m0 = blockIdx.x * 128;
    const int n0 = blockIdx.y * 128;

    const int srow = tid >> 1;
    const int kh   = (tid & 1) * 16;
    const int am = m0 + srow;
    const float* arow;
    if (tokens) {
        const int t = am >> 7, b = am & 127;
        arow = A + (size_t)tokens[b * 64 + t] * lda;
    } else {
        arow = A + (size_t)am * lda;
    }
    const int wn = n0 + srow;
    const float* wrow = (wn < nsplit) ? (W0 + (size_t)wn * ldw)
                                      : (W1 + (size_t)(wn - nsplit) * ldw);
    const int kw = tid >> 3;
    const int n8 = (tid & 7) * 16;

    const int tm4 = (tid & 15) * 4;
    const int tn4 = (tid >> 4) * 4;
    float acc[8][8] = {};
    float4 ra[4], rw[4];

    const int nt = (K + 31) / 32;

    #pragma unroll
    for (int j = 0; j < 4; ++j) {
        const int k = kh + j * 4;
        if (k + 3 < K) ra[j] = *(const float4*)(arow + k);
        else {
            float t0 = (k + 0 < K) ? arow[k + 0] : 0.f;
            float t1 = (k + 1 < K) ? arow[k + 1] : 0.f;
            float t2 = (k + 2 < K) ? arow[k + 2] : 0.f;
            float t3 = (k + 3 < K) ? arow[k + 3] : 0.f;
            ra[j] = make_float4(t0, t1, t2, t3);
        }
    }
    if (transb) {
        #pragma unroll
        for (int j = 0; j < 4; ++j) {
            const int k = kh + j * 4;
            if (k + 3 < K) rw[j] = *(const float4*)(wrow + k);
            else {
                float t0 = (k + 0 < K) ? wrow[k + 0] : 0.f;
                float t1 = (k + 1 < K) ? wrow[k + 1] : 0.f;
                float t2 = (k + 2 < K) ? wrow[k + 2] : 0.f;
                float t3 = (k + 3 < K) ? wrow[k + 3] : 0.f;
                rw[j] = make_float4(t0, t1, t2, t3);
            }
        }
    } else {
        const float* src = (kw < K) ? (W0 + (size_t)kw * ldw + n0 + n8) : W0;
        #pragma unroll
        for (int j = 0; j < 4; ++j)
            rw[j] = (kw < K) ? *(const float4*)(src + j * 4) : make_float4(0, 0, 0, 0);
    }

    for (int tile = 0; tile < nt; ++tile) {
        #pragma unroll
        for (int j = 0; j < 4; ++j) {
            As[kh + j * 4 + 0][srow] = ra[j].x;
            As[kh + j * 4 + 1][srow] = ra[j].y;
            As[kh + j * 4 + 2][srow] = ra[j].z;
            As[kh + j * 4 + 3][srow] = ra[j].w;
        }
        if (transb) {
            #pragma unroll
            for (int j = 0; j < 4; ++j) {
                Ws[kh + j * 4 + 0][srow] = rw[j].x;
                Ws[kh + j * 4 + 1][srow] = rw[j].y;
                Ws[kh + j * 4 + 2][srow] = rw[j].z;
                Ws[kh + j * 4 + 3][srow] = rw[j].w;
            }
        } else {
            #pragma unroll
            for (int j = 0; j < 4; ++j)
                *(float4*)&Ws[kw][n8 + j * 4] = rw[j];
        }
        __syncthreads();
        if (tile + 1 < nt) {
            const int kb = (tile + 1) * 32;
            #pragma unroll
            for (int j = 0; j < 4; ++j) {
                const int k = kb + kh + j * 4;
                if (k + 3 < K) ra[j] = *(const float4*)(arow + k);
                else {
                    float t0 = (k + 0 < K) ? arow[k + 0] : 0.f;
                    float t1 = (k + 1 < K) ? arow[k + 1] : 0.f;
                    float t2 = (k + 2 < K) ? arow[k + 2] : 0.f;
                    float t3 = (k + 3 < K) ? arow[k + 3] : 0.f;
                    ra[j] = make_float4(t0, t1, t2, t3);
                }
            }
            if (transb) {
                #pragma unroll
                for (int j = 0; j < 4; ++j) {
                    const int k = kb + kh + j * 4;
                    if (k + 3 < K) rw[j] = *(const float4*)(wrow + k);
                    else {
                        float t0 = (k + 0 < K) ? wrow[k + 0] : 0.f;
                        float t1 = (k + 1 < K) ? wrow[k + 1] : 0.f;
                        float t2 = (k + 2 < K) ? wrow[k + 2] : 0.f;
                        float t3 = (k + 3 < K) ? wrow[k + 3] : 0.f;
                        rw[j] = make_float4(t0, t1, t2, t3);
                    }
                }
            } else {
                const int k = kb + kw;
                const float* src = (k < K) ? (W0 + (size_t)k * ldw + n0 + n8) : W0;
                #pragma unroll
                for (int j = 0; j < 4; ++j)
                    rw[j] = (k < K) ? *(const float4*)(src + j * 4) : make_float4(0, 0, 0, 0);
            }
        }
        #pragma unroll 8
        for (int kk = 0; kk < 32; ++kk) {
            const float4 a0 = *(const float4*)&As[kk][tm4];
            const float4 a1 = *(const float4*)&As[kk][tm4 + 64];
            const float4 b0 = *(const float4*)&Ws[kk][tn4];
            const float4 b1 = *(const float4*)&Ws[kk][tn4 + 64];
            const float av[8] = {a0.x, a0.y, a0.z, a0.w, a1.x, a1.y, a1.z, a1.w};
            const float bv[8] = {b0.x, b0.y, b0.z, b0.w, b1.x, b1.y, b1.z, b1.w};
            #pragma unroll
            for (int i = 0; i < 8; ++i)
                #pragma unroll
                for (int j = 0; j < 8; ++j)
                    acc[i][j] += av[i] * bv[j];
        }
        __syncthreads();
    }
    const int half = (n0 >= nsplit) ? 1 : 0;
    const float* bp = half ? bias1 : bias0;
    const int nl = n0 - (half ? nsplit : 0);
    #pragma unroll
    for (int i = 0; i < 8; ++i) {
        const int row = m0 + tm4 + (i >> 2) * 64 + (i & 3);
        #pragma unroll
        for (int jh = 0; jh < 2; ++jh) {
            float v[4];
            #pragma unroll
            for (int j = 0; j < 4; ++j) {
                float x = acc[i][jh * 4 + j];
                if (bp) x += bp[nl + tn4 + jh * 64 + j];
                if (act_tanh) x = tanhf_fast(x);
                v[j] = x;
            }
            *(float4*)(C + (size_t)row * ldc + n0 + tn4 + jh * 64) =
                make_float4(v[0], v[1], v[2], v[3]);
        }
    }
}

// ---------------- BiLSTM scan: MFMA recurrence (exact R13) -----------------
// 128 blocks x 512 thr (8 waves). bx = s*16 + g: g = dir*8+qg (16 batch
// rows), s = 0..7 (32 h-dims). Per step: z[16b][128c] = h[16][256] @ W via
// bf16x3 MFMA. Wave w = col-fragment (gate w>>1, dim-half w&1); W resident
// as bf16 hi/lo frags. h exchanged as u32 (hi16|lo16) bf16 pairs; staged to
// LDS [16][264] u16. tid0 poll + broadcast barrier (measured best).
__global__ __launch_bounds__(512, 2) void k_scan9(
    const float* __restrict__ Zin, const float* __restrict__ WtF,
    const float* __restrict__ WtB, float* __restrict__ outbuf,
    int bt_layout, unsigned int* __restrict__ hx32, int* __restrict__ flags,
    int bx_base)
{
    __shared__ __align__(16) unsigned short hbh[16 * 264];
    __shared__ __align__(16) unsigned short hbl[16 * 264];
    __shared__ float zbuf[8 * 16 * 17];          // [frag][bi][17]

    const int bx  = blockIdx.x + bx_base;
    const int g   = bx & 15;           // dir*8 + qg
    const int s   = bx >> 4;           // 0..7 dim slice
    const int dir = g >> 3;
    const int qg  = g & 7;
    const int tid = threadIdx.x;
    const int w   = tid >> 6;          // wave = fragment 0..7
    const int l   = tid & 63;
    const int lr  = l & 15;
    const int lk8 = (l >> 4) * 8;
    const float* __restrict__ Wt = dir ? WtB : WtF;

    // ---- W preload: fragment w -> gate = w>>1, dim-half = w&1 ----
    const int colg = (w >> 1) * 256 + s * 32 + (w & 1) * 16 + lr;
    bf16x8 wbh[8], wbl[8];
    #pragma unroll
    for (int kf = 0; kf < 8; ++kf) {
        ushort ph[8], pl[8];
        #pragma unroll
        for (int j = 0; j < 8; ++j) {
            const int k = kf * 32 + lk8 + j;
            const float v = Wt[(size_t)k * 1024 + colg];
            __hip_bfloat16 bh = __float2bfloat16(v);
            __hip_bfloat16 bl = __float2bfloat16(v - __bfloat162float(bh));
            ph[j] = *(ushort*)&bh; pl[j] = *(ushort*)&bl;
        }
        wbh[kf] = *(bf16x8*)ph;
        wbl[kf] = *(bf16x8*)pl;
    }

    // phase-2 / publish mapping: bi = tid>>5 (16 batch), di = tid&31 (32 dims)
    const int bi  = tid >> 5;
    const int di  = tid & 31;
    const int gb  = qg * 16 + bi;
    const int dim = s * 32 + di;
    float c_state = 0.0f;
    const int fbase = g * 64;
    // staging map: row = tid>>5, k8 = (tid&31)*8
    const int st_base = (tid >> 5) * 256 + (tid & 31) * 8;
    const int st_lds  = (tid >> 5) * 264 + (tid & 31) * 8;

    for (int tt = 0; tt < 64; ++tt) {
        const int t = dir ? (63 - tt) : tt;
        // Z prefetch (independent of h; overlaps poll)
        const float* zr = Zin + (size_t)(t * 128 + gb) * 2048 + dir * 1024 + dim;
        const float z0 = zr[0], z1 = zr[256], z2 = zr[512], z3 = zr[768];
        if (tt > 0) {
            if (tid == 0) {
                while (__hip_atomic_load(&flags[fbase + tt - 1], __ATOMIC_RELAXED,
                                         __HIP_MEMORY_SCOPE_AGENT) < 8)
                    __builtin_amdgcn_s_sleep(1);
            }
            __syncthreads();
            // ---- stage h: 8 u32 (4 u64 loads), unpack to bf16 hi/lo LDS ----
            {
                const unsigned long long* hs64 = (const unsigned long long*)
                    (hx32 + ((size_t)(((tt - 1) & 1) * 16 + g)) * 4096 + st_base);
                unsigned int hp[4], lp[4];
                #pragma unroll
                for (int j = 0; j < 4; ++j) {
                    const unsigned long long q = __hip_atomic_load(&hs64[j], __ATOMIC_RELAXED,
                                                                   __HIP_MEMORY_SCOPE_AGENT);
                    const unsigned int w0 = (unsigned int)q;
                    const unsigned int w1 = (unsigned int)(q >> 32);
                    hp[j] = (w0 >> 16) | (w1 & 0xFFFF0000u);
                    lp[j] = (w0 & 0xFFFFu) | (w1 << 16);
                }
                *(uint4*)&hbh[st_lds] = make_uint4(hp[0], hp[1], hp[2], hp[3]);
                *(uint4*)&hbl[st_lds] = make_uint4(lp[0], lp[1], lp[2], lp[3]);
            }
            __syncthreads();
            // ---- MFMA: 8 k-frags x 3 products ----
            f32x4 acc = (f32x4){0.f, 0.f, 0.f, 0.f};
            #pragma unroll
            for (int kf = 0; kf < 8; ++kf) {
                const int ao = lr * 264 + kf * 32 + lk8;
                const bf16x8 ah = *(const bf16x8*)&hbh[ao];
                const bf16x8 al = *(const bf16x8*)&hbl[ao];
                acc = __builtin_amdgcn_mfma_f32_16x16x32_bf16(ah, wbh[kf], acc, 0, 0, 0);
                acc = __builtin_amdgcn_mfma_f32_16x16x32_bf16(ah, wbl[kf], acc, 0, 0, 0);
                acc = __builtin_amdgcn_mfma_f32_16x16x32_bf16(al, wbh[kf], acc, 0, 0, 0);
            }
            // C layout: col = lr, row_b = (l>>4)*4 + j
            #pragma unroll
            for (int j = 0; j < 4; ++j)
                zbuf[(w * 16 + (l >> 4) * 4 + j) * 17 + lr] = acc[j];
            __syncthreads();
        } else {
            for (int i = tid; i < 2176; i += 512) zbuf[i] = 0.0f;
            __syncthreads();
        }
        // ---- phase 2: gates, state, publish (all 512 threads) ----
        {
            const int dh = di >> 4, dl = di & 15;
            const float zi = zbuf[((0 * 2 + dh) * 16 + bi) * 17 + dl] + z0;
            const float zf = zbuf[((1 * 2 + dh) * 16 + bi) * 17 + dl] + z1;
            const float zg = zbuf[((2 * 2 + dh) * 16 + bi) * 17 + dl] + z2;
            const float zo = zbuf[((3 * 2 + dh) * 16 + bi) * 17 + dl] + z3;
            c_state = sigf(zf) * c_state + sigf(zi) * tanhf_fast(zg);
            const float h = sigf(zo) * tanhf_fast(c_state);
            const int row = bt_layout ? (gb * 64 + t) : (t * 128 + gb);
            outbuf[(size_t)row * 512 + dir * 256 + dim] = h;
            __hip_bfloat16 bh = __float2bfloat16(h);
            __hip_bfloat16 bl = __float2bfloat16(h - __bfloat162float(bh));
            const unsigned int pk = ((unsigned int)(*(ushort*)&bh) << 16) | (*(ushort*)&bl);
            __hip_atomic_store(
                &hx32[((size_t)((tt & 1) * 16 + g)) * 4096 + bi * 256 + dim],
                pk, __ATOMIC_RELAXED, __HIP_MEMORY_SCOPE_AGENT);
        }
        __syncthreads();  // vmcnt(0) drain: publishes complete before flag add
        if (tid == 0)
            __hip_atomic_fetch_add(&flags[fbase + tt], 1, __ATOMIC_RELAXED,
                                   __HIP_MEMORY_SCOPE_AGENT);
    }
}

// ---------------- attention pooling (unchanged) ----------------------------
__global__ __launch_bounds__(256) void k_attnpool(
    const float* __restrict__ hbar, const float* __restrict__ outp,
    const float* __restrict__ ws2, float* __restrict__ sent)
{
    __shared__ float hb[64][132];
    __shared__ float w2[8][128];
    __shared__ float att[8][64];
    const int b = blockIdx.x, tid = threadIdx.x;
    for (int i = tid; i < 1024; i += 256) ((float*)w2)[i] = ws2[i];
    const float* hsrc = hbar + (size_t)b * 64 * 128;
    for (int i = tid; i < 2048; i += 256) {
        const int row = i >> 5, d4 = (i & 31) << 2;
        *(float4*)&hb[row][d4] = *(const float4*)(hsrc + row * 128 + d4);
    }
    __syncthreads();
    for (int p = tid; p < 512; p += 256) {
        const int r = p >> 6, t = p & 63;
        float s = 0.0f;
        #pragma unroll 8
        for (int d = 0; d < 128; d += 4) {
            const float4 x = *(const float4*)&hb[t][d];
            const float4 y = *(const float4*)&w2[r][d];
            s += x.x * y.x + x.y * y.y + x.z * y.z + x.w * y.w;
        }
        att[r][t] = s;
    }
    __syncthreads();
    const float* ob = outp + (size_t)b * 64 * 512;
    float s0[8] = {}, s1[8] = {};
    for (int t = 0; t < 64; ++t) {
        const float v0 = ob[t * 512 + tid];
        const float v1 = ob[t * 512 + 256 + tid];
        #pragma unroll
        for (int r = 0; r < 8; ++r) {
            const float a = att[r][t];
            s0[r] += a * v0; s1[r] += a * v1;
        }
    }
    #pragma unroll
    for (int r = 0; r < 8; ++r) {
        sent[((size_t)b * 8 + r) * 512 + tid]       = s0[r];
        sent[((size_t)b * 8 + r) * 512 + 256 + tid] = s1[r];
    }
}

// ---------------- dynamic routing (unchanged) ------------------------------
__global__ __launch_bounds__(512) void k_routing(
    const float* __restrict__ votes, float* __restrict__ out)
{
    __shared__ float v[8][32][16];
    __shared__ float logits[8][32];
    __shared__ float route[8][32];
    const int b = blockIdx.x, tid = threadIdx.x;
    const float* vb = votes + (size_t)b * 4096;
    for (int i = tid; i < 4096; i += 512) ((float*)v)[i] = vb[i];
    if (tid < 256) ((float*)logits)[tid] = 0.0f;
    __syncthreads();
    const int c = tid >> 4, a = tid & 15;
    float n2 = 0.0f;
    for (int it = 0; it < 3; ++it) {
        if (tid < 256) {
            const int r = tid >> 5, cc = tid & 31;
            const float l = logits[r][cc];
            float mx = l;
            #pragma unroll
            for (int m = 1; m < 32; m <<= 1) mx = fmaxf(mx, __shfl_xor(mx, m));
            const float e = __expf(l - mx);
            float sm = e;
            #pragma unroll
            for (int m = 1; m < 32; m <<= 1) sm += __shfl_xor(sm, m);
            route[r][cc] = e / sm;
        }
        __syncthreads();
        float pa = 0.0f;
        #pragma unroll
        for (int r = 0; r < 8; ++r) pa += route[r][c] * v[r][c][a];
        n2 = pa * pa;
        #pragma unroll
        for (int m = 1; m < 16; m <<= 1) n2 += __shfl_xor(n2, m);
        const float nrm = sqrtf(n2);
        const float av = pa * (nrm / (0.5f + n2));
        if (it < 2) {
            #pragma unroll
            for (int r = 0; r < 8; ++r) {
                float u = v[r][c][a] * av;
                #pragma unroll
                for (int m = 1; m < 16; m <<= 1) u += __shfl_xor(u, m);
                if (a == 0) logits[r][c] += u;
            }
        }
        __syncthreads();
    }
    if (a == 0) out[b * 32 + c] = n2 / (0.5f + n2);
}

// ---------------------------------------------------------------------------
static void launch_scan(const float* Z, const float* wf, const float* wb,
                        float* ob, int bt, unsigned int* hx32, int* fl,
                        hipStream_t stream)
{
    int base0 = 0;
    void* args[] = {(void*)&Z, (void*)&wf, (void*)&wb, (void*)&ob,
                    (void*)&bt, (void*)&hx32, (void*)&fl, (void*)&base0};
    if (hipLaunchCooperativeKernel((const void*)k_scan9, dim3(128), dim3(512),
                                   args, 0, stream) != hipSuccess) {
        k_scan9<<<dim3(128), 512, 0, stream>>>(Z, wf, wb, ob, bt, hx32, fl, 0);
    }
}

extern "C" void kernel_launch(void* const* d_in, const int* in_sizes, int n_in,
                              void* d_out, int out_size, void* d_ws, size_t ws_size,
                              hipStream_t stream) {
    (void)in_sizes; (void)n_in; (void)out_size; (void)ws_size;
    const int*   tokens  = (const int*)d_in[0];
    const float* emb     = (const float*)d_in[2];
    const float* w_ih_f0 = (const float*)d_in[3];
    const float* w_hh_f0 = (const float*)d_in[4];
    const float* b_f0    = (const float*)d_in[5];
    const float* w_ih_b0 = (const float*)d_in[6];
    const float* w_hh_b0 = (const float*)d_in[7];
    const float* b_b0    = (const float*)d_in[8];
    const float* w_ih_f1 = (const float*)d_in[9];
    const float* w_hh_f1 = (const float*)d_in[10];
    const float* b_f1    = (const float*)d_in[11];
    const float* w_ih_b1 = (const float*)d_in[12];
    const float* w_hh_b1 = (const float*)d_in[13];
    const float* b_b1    = (const float*)d_in[14];
    const float* ws1     = (const float*)d_in[15];
    const float* ws2     = (const float*)d_in[16];
    const float* caps    = (const float*)d_in[17];

    float* wsf  = (float*)d_ws;
    float* Wt   = wsf;                          //  4 * 262144
    float* Z    = Wt   + 4 * 262144;            //  8192*2048
    float* x1   = Z    + 16777216;              //  8192*512
    float* outp = x1   + 4194304;               //  8192*512
    float* hbar = outp + 4194304;               //  8192*128
    float* sent = hbar + 1048576;               //  128*8*512
    float* vote = sent + 524288;                //  128*8*512
    unsigned int* hx32 = (unsigned int*)(vote + 524288);  // 2*16*4096 u32
    int*   flags = (int*)(hx32 + 131072);       //  8192 ints
    unsigned short* Whi0 = (unsigned short*)(flags + 8192);  // 2048*320
    unsigned short* Wlo0 = Whi0 + 2048 * 320;
    unsigned short* Whi1 = Wlo0 + 2048 * 320;                // 2048*512
    unsigned short* Wlo1 = Whi1 + 2048 * 512;
    unsigned short* Whs1 = Wlo1 + 2048 * 512;                // 128*512 (ws1)
    unsigned short* Wls1 = Whs1 + 128 * 512;
    float* out  = (float*)d_out;

    // 0. zero sync flags (every launch; replays don't re-poison)
    k_zero<<<dim3(32), 256, 0, stream>>>(flags, 8192);
    // 1. pre-split W stacks to (hi,lo) bf16 (once per launch)
    k_splitw<<<dim3(640),  256, 0, stream>>>(w_ih_f0, w_ih_b0, 300, 320, Whi0, Wlo0);
    k_splitw<<<dim3(1024), 256, 0, stream>>>(w_ih_f1, w_ih_b1, 512, 512, Whi1, Wlo1);
    k_splitw<<<dim3(64),   256, 0, stream>>>(ws1, (const float*)nullptr, 512, 512, Whs1, Wls1);
    // 2. transpose recurrent weights
    k_transpose<<<dim3(32, 8, 4), dim3(32, 8), 0, stream>>>(w_hh_f0, w_hh_b0, w_hh_f1, w_hh_b1, Wt);
    // 3. layer-0 projection (bf16x3 MFMA, inline A-gather+split) -> Z
    k_mgemm2<<<dim3(64, 16), 256, 0, stream>>>(
        emb, 300, tokens, Whi0, Wlo0, b_f0, b_b0, Z, 2048, 300, 320, 0);
    // 4. layer-0 scan -> x1 [t*128+b][512]
    launch_scan(Z, Wt, Wt + 262144, x1, 0, hx32, flags, stream);
    // 5. layer-1 projection -> Z
    k_mgemm2<<<dim3(64, 16), 256, 0, stream>>>(
        x1, 512, (const int*)nullptr, Whi1, Wlo1, b_f1, b_b1, Z, 2048, 512, 512, 0);
    // 6. layer-1 scan -> outp [b*64+t][512]
    launch_scan(Z, Wt + 2 * 262144, Wt + 3 * 262144, outp, 1, hx32, flags + 4096, stream);
    // 7. hbar = tanh(outp @ ws1^T)
    k_mgemm2<<<dim3(64, 1), 256, 0, stream>>>(
        outp, 512, (const int*)nullptr, Whs1, Wls1,
        (const float*)nullptr, (const float*)nullptr, hbar, 128, 512, 512, 1);
    // 8. attention + sent
    k_attnpool<<<dim3(128), 256, 0, stream>>>(hbar, outp, ws2, sent);
    // 9. votes
    k_gemm<<<dim3(1, 4, 8), 256, 0, stream>>>(
        sent, 4096, (const int*)nullptr, caps, (const float*)nullptr, 1 << 30, 512,
        (const float*)nullptr, (const float*)nullptr,
        vote, 4096, 512, 0, 0, 512LL, 262144LL, 512LL);
    // 10. routing
    k_routing<<<dim3(128), 512, 0, stream>>>(vote, out);
}

// Round 19
// 536.656 us; speedup vs baseline: 1.4118x; 1.0689x over previous
//
#include <hip/hip_runtime.h>
#include <hip/hip_bf16.h>

// ---------------------------------------------------------------------------
// CapsuleNetwork: embedding -> 2-layer BiLSTM -> attn pooling -> routing
// Round 18: votes GEMM moved to MFMA (k_splitcaps pre-splits+transposes
// caps_w to bf16 hi/lo [r][o][u]; k_mvotes = mgemm2 structure per (n,r)).
// Dead fp32 k_gemm removed. Scan = R13 k_scan9 (floor 154us), W pre-split
// (R17). B=128 T=64 E=300 H=256 DA=128 R=8 SC=32 AT=16
// ---------------------------------------------------------------------------

typedef __attribute__((ext_vector_type(8))) short bf16x8;
typedef __attribute__((ext_vector_type(4))) float f32x4;

__device__ __forceinline__ float sigf(float x) { return 1.0f / (1.0f + __expf(-x)); }
__device__ __forceinline__ float tanhf_fast(float x) { return 1.0f - 2.0f / (__expf(2.0f * x) + 1.0f); }

// ---------------- transpose w_hh [1024][256] -> Wt [256][1024] -------------
__global__ void k_transpose(const float* __restrict__ w0, const float* __restrict__ w1,
                            const float* __restrict__ w2, const float* __restrict__ w3,
                            float* __restrict__ wt)
{
    __shared__ float tile[32][33];
    const float* W = (blockIdx.z == 0) ? w0 : (blockIdx.z == 1) ? w1 : (blockIdx.z == 2) ? w2 : w3;
    float* Wt = wt + (size_t)blockIdx.z * 256 * 1024;
    const int j0 = blockIdx.x * 32, k0 = blockIdx.y * 32;
    const int tx = threadIdx.x, ty = threadIdx.y;  // (32,8)
    #pragma unroll
    for (int i = 0; i < 32; i += 8)
        tile[ty + i][tx] = W[(size_t)(j0 + ty + i) * 256 + (k0 + tx)];
    __syncthreads();
    #pragma unroll
    for (int i = 0; i < 32; i += 8)
        Wt[(size_t)(k0 + ty + i) * 1024 + (j0 + tx)] = tile[tx][ty + i];
}

// ---------------- zero words -----------------------------------------------
__global__ void k_zero(int* __restrict__ p, int n)
{
    const int i = blockIdx.x * blockDim.x + threadIdx.x;
    if (i < n) p[i] = 0;
}

// ---------------- W stack fp32 -> (hi,lo) bf16, K-padded -------------------
__global__ void k_splitw(const float* __restrict__ W0, const float* __restrict__ W1,
                         int Kin, int Kp, unsigned short* __restrict__ hi,
                         unsigned short* __restrict__ lo)
{
    const int i4 = (blockIdx.x * 256 + threadIdx.x) * 4;
    const int r = i4 / Kp;
    const int k = i4 - r * Kp;
    const float* srow = (r < 1024) ? (W0 + (size_t)r * Kin)
                                   : (W1 + (size_t)(r - 1024) * Kin);
    float e[4];
    if (k + 4 <= Kin) {
        const float4 v = *(const float4*)(srow + k);
        e[0] = v.x; e[1] = v.y; e[2] = v.z; e[3] = v.w;
    } else {
        #pragma unroll
        for (int j = 0; j < 4; ++j) e[j] = (k + j < Kin) ? srow[k + j] : 0.0f;
    }
    ushort4 hv, lv;
    #pragma unroll
    for (int j = 0; j < 4; ++j) {
        __hip_bfloat16 bh = __float2bfloat16(e[j]);
        const float fh = __bfloat162float(bh);
        __hip_bfloat16 bl = __float2bfloat16(e[j] - fh);
        ((unsigned short*)&hv)[j] = *(unsigned short*)&bh;
        ((unsigned short*)&lv)[j] = *(unsigned short*)&bl;
    }
    *(ushort4*)&hi[(size_t)r * Kp + k] = hv;
    *(ushort4*)&lo[(size_t)r * Kp + k] = lv;
}

// ---------------- caps_w [r][u][o] -> bf16 hi/lo transposed [r][o][u] ------
__global__ void k_splitcaps(const float* __restrict__ caps,
                            unsigned short* __restrict__ hiT,
                            unsigned short* __restrict__ loT)
{
    __shared__ float tile[32][33];
    const float* src = caps + (size_t)blockIdx.z * 512 * 512;
    unsigned short* ho = hiT + (size_t)blockIdx.z * 512 * 512;
    unsigned short* lo = loT + (size_t)blockIdx.z * 512 * 512;
    const int u0 = blockIdx.x * 32, o0 = blockIdx.y * 32;
    const int tx = threadIdx.x, ty = threadIdx.y;  // (32,8)
    #pragma unroll
    for (int i = 0; i < 32; i += 8)
        tile[ty + i][tx] = src[(size_t)(u0 + ty + i) * 512 + (o0 + tx)];
    __syncthreads();
    #pragma unroll
    for (int i = 0; i < 32; i += 8) {
        const float v = tile[tx][ty + i];   // caps[u0+tx][o0+ty+i]
        __hip_bfloat16 bh = __float2bfloat16(v);
        __hip_bfloat16 bl = __float2bfloat16(v - __bfloat162float(bh));
        const size_t idx = (size_t)(o0 + ty + i) * 512 + (u0 + tx);
        ho[idx] = *(unsigned short*)&bh;
        lo[idx] = *(unsigned short*)&bl;
    }
}

// ---------------- bf16x3 MFMA GEMM: inline A-split, pre-split W ------------
// C[m][n] = act( sum_k A[m,k]*W[n,k] + bias[n] ). A fp32 (opt. gathered),
// split in-register at staging; W read directly as (hi,lo) bf16.
// Tile 128x128, 4 waves (2x2 of 64x64), 4x4 frags of 16x16x32, LDS stride 40.
__global__ __launch_bounds__(256) void k_mgemm2(
    const float* __restrict__ A, int lda, const int* __restrict__ tokens,
    const unsigned short* __restrict__ Whi, const unsigned short* __restrict__ Wlo,
    const float* __restrict__ bias0, const float* __restrict__ bias1,
    float* __restrict__ C, int ldc, int Kin, int Kp, int act_tanh)
{
    __shared__ unsigned short lAh[128 * 40];
    __shared__ unsigned short lAl[128 * 40];
    __shared__ unsigned short lBh[128 * 40];
    __shared__ unsigned short lBl[128 * 40];

    const int tid = threadIdx.x;
    const int m0 = blockIdx.x * 128;
    const int n0 = blockIdx.y * 128;
    const int w  = tid >> 6, l = tid & 63;
    const int wm = (w >> 1) * 64, wn = (w & 1) * 64;
    const int lr = l & 15, lk = (l >> 4) * 8;

    int srow[2], sk8[2];
    const float* arow[2];
    size_t wbase[2];
    #pragma unroll
    for (int p = 0; p < 2; ++p) {
        const int chunk = tid + p * 256;
        srow[p] = chunk >> 2;
        sk8[p]  = (chunk & 3) * 8;
        const int am = m0 + srow[p];
        if (tokens) {
            const int t = am >> 7, b = am & 127;
            arow[p] = A + (size_t)tokens[b * 64 + t] * lda;
        } else {
            arow[p] = A + (size_t)am * lda;
        }
        wbase[p] = (size_t)(n0 + srow[p]) * Kp + sk8[p];
    }

    f32x4 acc[4][4];
    #pragma unroll
    for (int i = 0; i < 4; ++i)
        #pragma unroll
        for (int j = 0; j < 4; ++j)
            acc[i][j] = (f32x4){0.f, 0.f, 0.f, 0.f};

    float fa[2][8];
    bf16x8 rwh[2], rwl[2];
    #pragma unroll
    for (int p = 0; p < 2; ++p) {
        const int k0 = sk8[p];
        if (k0 + 7 < Kin) {
            const float4 a0 = *(const float4*)(arow[p] + k0);
            const float4 a1 = *(const float4*)(arow[p] + k0 + 4);
            fa[p][0]=a0.x; fa[p][1]=a0.y; fa[p][2]=a0.z; fa[p][3]=a0.w;
            fa[p][4]=a1.x; fa[p][5]=a1.y; fa[p][6]=a1.z; fa[p][7]=a1.w;
        } else {
            #pragma unroll
            for (int j = 0; j < 8; ++j)
                fa[p][j] = (k0 + j < Kin) ? arow[p][k0 + j] : 0.0f;
        }
        rwh[p] = *(const bf16x8*)&Whi[wbase[p]];
        rwl[p] = *(const bf16x8*)&Wlo[wbase[p]];
    }

    for (int kt = 0; kt < Kp; kt += 32) {
        #pragma unroll
        for (int p = 0; p < 2; ++p) {
            const int la = srow[p] * 40 + sk8[p];
            ushort hA[8], lA[8];
            #pragma unroll
            for (int j = 0; j < 8; ++j) {
                __hip_bfloat16 bh = __float2bfloat16(fa[p][j]);
                const float fh = __bfloat162float(bh);
                __hip_bfloat16 bl = __float2bfloat16(fa[p][j] - fh);
                hA[j] = *(ushort*)&bh; lA[j] = *(ushort*)&bl;
            }
            *(bf16x8*)&lAh[la] = *(bf16x8*)hA;
            *(bf16x8*)&lAl[la] = *(bf16x8*)lA;
            *(bf16x8*)&lBh[la] = rwh[p];
            *(bf16x8*)&lBl[la] = rwl[p];
        }
        __syncthreads();
        if (kt + 32 < Kp) {
            #pragma unroll
            for (int p = 0; p < 2; ++p) {
                const int k0 = kt + 32 + sk8[p];
                if (k0 + 7 < Kin) {
                    const float4 a0 = *(const float4*)(arow[p] + k0);
                    const float4 a1 = *(const float4*)(arow[p] + k0 + 4);
                    fa[p][0]=a0.x; fa[p][1]=a0.y; fa[p][2]=a0.z; fa[p][3]=a0.w;
                    fa[p][4]=a1.x; fa[p][5]=a1.y; fa[p][6]=a1.z; fa[p][7]=a1.w;
                } else {
                    #pragma unroll
                    for (int j = 0; j < 8; ++j)
                        fa[p][j] = (k0 + j < Kin) ? arow[p][k0 + j] : 0.0f;
                }
                rwh[p] = *(const bf16x8*)&Whi[wbase[p] + kt + 32];
                rwl[p] = *(const bf16x8*)&Wlo[wbase[p] + kt + 32];
            }
        }
        bf16x8 ah[4], al[4], bh[4], bl[4];
        #pragma unroll
        for (int f = 0; f < 4; ++f) {
            const int ra = (wm + f * 16 + lr) * 40 + lk;
            const int rb = (wn + f * 16 + lr) * 40 + lk;
            ah[f] = *(const bf16x8*)&lAh[ra];
            al[f] = *(const bf16x8*)&lAl[ra];
            bh[f] = *(const bf16x8*)&lBh[rb];
            bl[f] = *(const bf16x8*)&lBl[rb];
        }
        #pragma unroll
        for (int fm = 0; fm < 4; ++fm)
            #pragma unroll
            for (int fn = 0; fn < 4; ++fn) {
                acc[fm][fn] = __builtin_amdgcn_mfma_f32_16x16x32_bf16(ah[fm], bh[fn], acc[fm][fn], 0, 0, 0);
                acc[fm][fn] = __builtin_amdgcn_mfma_f32_16x16x32_bf16(ah[fm], bl[fn], acc[fm][fn], 0, 0, 0);
                acc[fm][fn] = __builtin_amdgcn_mfma_f32_16x16x32_bf16(al[fm], bh[fn], acc[fm][fn], 0, 0, 0);
            }
        __syncthreads();
    }
    #pragma unroll
    for (int fm = 0; fm < 4; ++fm)
        #pragma unroll
        for (int fn = 0; fn < 4; ++fn) {
            const int col = n0 + wn + fn * 16 + lr;
            const float bv = (col < 1024) ? (bias0 ? bias0[col] : 0.f)
                                          : (bias1 ? bias1[col - 1024] : 0.f);
            #pragma unroll
            for (int j = 0; j < 4; ++j) {
                const int row = m0 + wm + fm * 16 + (l >> 4) * 4 + j;
                float x = acc[fm][fn][j] + bv;
                if (act_tanh) x = tanhf_fast(x);
                C[(size_t)row * ldc + col] = x;
            }
        }
}

// ---------------- votes MFMA GEMM ------------------------------------------
// votes[b,r,o] = sum_u sent[b,r,u] * capsT[r][o][u]. Grid (4 n-blocks, 8 r).
// A row b = sent + (b*8+r)*512 (fp32, inline split); W = capsT bf16 hi/lo.
// Same 128x128 / 4-wave / 4x4-frag structure as k_mgemm2, M=128, K=512.
__global__ __launch_bounds__(256) void k_mvotes(
    const float* __restrict__ sent, const unsigned short* __restrict__ Whi,
    const unsigned short* __restrict__ Wlo, float* __restrict__ votes)
{
    __shared__ unsigned short lAh[128 * 40];
    __shared__ unsigned short lAl[128 * 40];
    __shared__ unsigned short lBh[128 * 40];
    __shared__ unsigned short lBl[128 * 40];

    const int tid = threadIdx.x;
    const int n0 = blockIdx.x * 128;
    const int r  = blockIdx.y;
    const int w  = tid >> 6, l = tid & 63;
    const int wm = (w >> 1) * 64, wn = (w & 1) * 64;
    const int lr = l & 15, lk = (l >> 4) * 8;

    const unsigned short* WhiR = Whi + (size_t)r * 512 * 512;
    const unsigned short* WloR = Wlo + (size_t)r * 512 * 512;

    int srow[2], sk8[2];
    const float* arow[2];
    size_t wbase[2];
    #pragma unroll
    for (int p = 0; p < 2; ++p) {
        const int chunk = tid + p * 256;
        srow[p] = chunk >> 2;               // batch row 0..127
        sk8[p]  = (chunk & 3) * 8;
        arow[p] = sent + ((size_t)srow[p] * 8 + r) * 512;
        wbase[p] = (size_t)(n0 + srow[p]) * 512 + sk8[p];
    }

    f32x4 acc[4][4];
    #pragma unroll
    for (int i = 0; i < 4; ++i)
        #pragma unroll
        for (int j = 0; j < 4; ++j)
            acc[i][j] = (f32x4){0.f, 0.f, 0.f, 0.f};

    float fa[2][8];
    bf16x8 rwh[2], rwl[2];
    #pragma unroll
    for (int p = 0; p < 2; ++p) {
        const float4 a0 = *(const float4*)(arow[p] + sk8[p]);
        const float4 a1 = *(const float4*)(arow[p] + sk8[p] + 4);
        fa[p][0]=a0.x; fa[p][1]=a0.y; fa[p][2]=a0.z; fa[p][3]=a0.w;
        fa[p][4]=a1.x; fa[p][5]=a1.y; fa[p][6]=a1.z; fa[p][7]=a1.w;
        rwh[p] = *(const bf16x8*)&WhiR[wbase[p]];
        rwl[p] = *(const bf16x8*)&WloR[wbase[p]];
    }

    for (int kt = 0; kt < 512; kt += 32) {
        #pragma unroll
        for (int p = 0; p < 2; ++p) {
            const int la = srow[p] * 40 + sk8[p];
            ushort hA[8], lA[8];
            #pragma unroll
            for (int j = 0; j < 8; ++j) {
                __hip_bfloat16 bh = __float2bfloat16(fa[p][j]);
                const float fh = __bfloat162float(bh);
                __hip_bfloat16 bl = __float2bfloat16(fa[p][j] - fh);
                hA[j] = *(ushort*)&bh; lA[j] = *(ushort*)&bl;
            }
            *(bf16x8*)&lAh[la] = *(bf16x8*)hA;
            *(bf16x8*)&lAl[la] = *(bf16x8*)lA;
            *(bf16x8*)&lBh[la] = rwh[p];
            *(bf16x8*)&lBl[la] = rwl[p];
        }
        __syncthreads();
        if (kt + 32 < 512) {
            #pragma unroll
            for (int p = 0; p < 2; ++p) {
                const int k0 = kt + 32 + sk8[p];
                const float4 a0 = *(const float4*)(arow[p] + k0);
                const float4 a1 = *(const float4*)(arow[p] + k0 + 4);
                fa[p][0]=a0.x; fa[p][1]=a0.y; fa[p][2]=a0.z; fa[p][3]=a0.w;
                fa[p][4]=a1.x; fa[p][5]=a1.y; fa[p][6]=a1.z; fa[p][7]=a1.w;
                rwh[p] = *(const bf16x8*)&WhiR[wbase[p] + kt + 32];
                rwl[p] = *(const bf16x8*)&WloR[wbase[p] + kt + 32];
            }
        }
        bf16x8 ah[4], al[4], bh[4], bl[4];
        #pragma unroll
        for (int f = 0; f < 4; ++f) {
            const int ra = (wm + f * 16 + lr) * 40 + lk;
            const int rb = (wn + f * 16 + lr) * 40 + lk;
            ah[f] = *(const bf16x8*)&lAh[ra];
            al[f] = *(const bf16x8*)&lAl[ra];
            bh[f] = *(const bf16x8*)&lBh[rb];
            bl[f] = *(const bf16x8*)&lBl[rb];
        }
        #pragma unroll
        for (int fm = 0; fm < 4; ++fm)
            #pragma unroll
            for (int fn = 0; fn < 4; ++fn) {
                acc[fm][fn] = __builtin_amdgcn_mfma_f32_16x16x32_bf16(ah[fm], bh[fn], acc[fm][fn], 0, 0, 0);
                acc[fm][fn] = __builtin_amdgcn_mfma_f32_16x16x32_bf16(ah[fm], bl[fn], acc[fm][fn], 0, 0, 0);
                acc[fm][fn] = __builtin_amdgcn_mfma_f32_16x16x32_bf16(al[fm], bh[fn], acc[fm][fn], 0, 0, 0);
            }
        __syncthreads();
    }
    #pragma unroll
    for (int fm = 0; fm < 4; ++fm)
        #pragma unroll
        for (int fn = 0; fn < 4; ++fn) {
            const int col = n0 + wn + fn * 16 + lr;
            #pragma unroll
            for (int j = 0; j < 4; ++j) {
                const int row = wm + fm * 16 + (l >> 4) * 4 + j;  // batch b
                votes[((size_t)row * 8 + r) * 512 + col] = acc[fm][fn][j];
            }
        }
}

// ---------------- BiLSTM scan: MFMA recurrence (exact R13) -----------------
__global__ __launch_bounds__(512, 2) void k_scan9(
    const float* __restrict__ Zin, const float* __restrict__ WtF,
    const float* __restrict__ WtB, float* __restrict__ outbuf,
    int bt_layout, unsigned int* __restrict__ hx32, int* __restrict__ flags,
    int bx_base)
{
    __shared__ __align__(16) unsigned short hbh[16 * 264];
    __shared__ __align__(16) unsigned short hbl[16 * 264];
    __shared__ float zbuf[8 * 16 * 17];          // [frag][bi][17]

    const int bx  = blockIdx.x + bx_base;
    const int g   = bx & 15;           // dir*8 + qg
    const int s   = bx >> 4;           // 0..7 dim slice
    const int dir = g >> 3;
    const int qg  = g & 7;
    const int tid = threadIdx.x;
    const int w   = tid >> 6;          // wave = fragment 0..7
    const int l   = tid & 63;
    const int lr  = l & 15;
    const int lk8 = (l >> 4) * 8;
    const float* __restrict__ Wt = dir ? WtB : WtF;

    const int colg = (w >> 1) * 256 + s * 32 + (w & 1) * 16 + lr;
    bf16x8 wbh[8], wbl[8];
    #pragma unroll
    for (int kf = 0; kf < 8; ++kf) {
        ushort ph[8], pl[8];
        #pragma unroll
        for (int j = 0; j < 8; ++j) {
            const int k = kf * 32 + lk8 + j;
            const float v = Wt[(size_t)k * 1024 + colg];
            __hip_bfloat16 bh = __float2bfloat16(v);
            __hip_bfloat16 bl = __float2bfloat16(v - __bfloat162float(bh));
            ph[j] = *(ushort*)&bh; pl[j] = *(ushort*)&bl;
        }
        wbh[kf] = *(bf16x8*)ph;
        wbl[kf] = *(bf16x8*)pl;
    }

    const int bi  = tid >> 5;
    const int di  = tid & 31;
    const int gb  = qg * 16 + bi;
    const int dim = s * 32 + di;
    float c_state = 0.0f;
    const int fbase = g * 64;
    const int st_base = (tid >> 5) * 256 + (tid & 31) * 8;
    const int st_lds  = (tid >> 5) * 264 + (tid & 31) * 8;

    for (int tt = 0; tt < 64; ++tt) {
        const int t = dir ? (63 - tt) : tt;
        const float* zr = Zin + (size_t)(t * 128 + gb) * 2048 + dir * 1024 + dim;
        const float z0 = zr[0], z1 = zr[256], z2 = zr[512], z3 = zr[768];
        if (tt > 0) {
            if (tid == 0) {
                while (__hip_atomic_load(&flags[fbase + tt - 1], __ATOMIC_RELAXED,
                                         __HIP_MEMORY_SCOPE_AGENT) < 8)
                    __builtin_amdgcn_s_sleep(1);
            }
            __syncthreads();
            {
                const unsigned long long* hs64 = (const unsigned long long*)
                    (hx32 + ((size_t)(((tt - 1) & 1) * 16 + g)) * 4096 + st_base);
                unsigned int hp[4], lp[4];
                #pragma unroll
                for (int j = 0; j < 4; ++j) {
                    const unsigned long long q = __hip_atomic_load(&hs64[j], __ATOMIC_RELAXED,
                                                                   __HIP_MEMORY_SCOPE_AGENT);
                    const unsigned int w0 = (unsigned int)q;
                    const unsigned int w1 = (unsigned int)(q >> 32);
                    hp[j] = (w0 >> 16) | (w1 & 0xFFFF0000u);
                    lp[j] = (w0 & 0xFFFFu) | (w1 << 16);
                }
                *(uint4*)&hbh[st_lds] = make_uint4(hp[0], hp[1], hp[2], hp[3]);
                *(uint4*)&hbl[st_lds] = make_uint4(lp[0], lp[1], lp[2], lp[3]);
            }
            __syncthreads();
            f32x4 acc = (f32x4){0.f, 0.f, 0.f, 0.f};
            #pragma unroll
            for (int kf = 0; kf < 8; ++kf) {
                const int ao = lr * 264 + kf * 32 + lk8;
                const bf16x8 ah = *(const bf16x8*)&hbh[ao];
                const bf16x8 al = *(const bf16x8*)&hbl[ao];
                acc = __builtin_amdgcn_mfma_f32_16x16x32_bf16(ah, wbh[kf], acc, 0, 0, 0);
                acc = __builtin_amdgcn_mfma_f32_16x16x32_bf16(ah, wbl[kf], acc, 0, 0, 0);
                acc = __builtin_amdgcn_mfma_f32_16x16x32_bf16(al, wbh[kf], acc, 0, 0, 0);
            }
            #pragma unroll
            for (int j = 0; j < 4; ++j)
                zbuf[(w * 16 + (l >> 4) * 4 + j) * 17 + lr] = acc[j];
            __syncthreads();
        } else {
            for (int i = tid; i < 2176; i += 512) zbuf[i] = 0.0f;
            __syncthreads();
        }
        {
            const int dh = di >> 4, dl = di & 15;
            const float zi = zbuf[((0 * 2 + dh) * 16 + bi) * 17 + dl] + z0;
            const float zf = zbuf[((1 * 2 + dh) * 16 + bi) * 17 + dl] + z1;
            const float zg = zbuf[((2 * 2 + dh) * 16 + bi) * 17 + dl] + z2;
            const float zo = zbuf[((3 * 2 + dh) * 16 + bi) * 17 + dl] + z3;
            c_state = sigf(zf) * c_state + sigf(zi) * tanhf_fast(zg);
            const float h = sigf(zo) * tanhf_fast(c_state);
            const int row = bt_layout ? (gb * 64 + t) : (t * 128 + gb);
            outbuf[(size_t)row * 512 + dir * 256 + dim] = h;
            __hip_bfloat16 bh = __float2bfloat16(h);
            __hip_bfloat16 bl = __float2bfloat16(h - __bfloat162float(bh));
            const unsigned int pk = ((unsigned int)(*(ushort*)&bh) << 16) | (*(ushort*)&bl);
            __hip_atomic_store(
                &hx32[((size_t)((tt & 1) * 16 + g)) * 4096 + bi * 256 + dim],
                pk, __ATOMIC_RELAXED, __HIP_MEMORY_SCOPE_AGENT);
        }
        __syncthreads();
        if (tid == 0)
            __hip_atomic_fetch_add(&flags[fbase + tt], 1, __ATOMIC_RELAXED,
                                   __HIP_MEMORY_SCOPE_AGENT);
    }
}

// ---------------- attention pooling (unchanged) ----------------------------
__global__ __launch_bounds__(256) void k_attnpool(
    const float* __restrict__ hbar, const float* __restrict__ outp,
    const float* __restrict__ ws2, float* __restrict__ sent)
{
    __shared__ float hb[64][132];
    __shared__ float w2[8][128];
    __shared__ float att[8][64];
    const int b = blockIdx.x, tid = threadIdx.x;
    for (int i = tid; i < 1024; i += 256) ((float*)w2)[i] = ws2[i];
    const float* hsrc = hbar + (size_t)b * 64 * 128;
    for (int i = tid; i < 2048; i += 256) {
        const int row = i >> 5, d4 = (i & 31) << 2;
        *(float4*)&hb[row][d4] = *(const float4*)(hsrc + row * 128 + d4);
    }
    __syncthreads();
    for (int p = tid; p < 512; p += 256) {
        const int r = p >> 6, t = p & 63;
        float s = 0.0f;
        #pragma unroll 8
        for (int d = 0; d < 128; d += 4) {
            const float4 x = *(const float4*)&hb[t][d];
            const float4 y = *(const float4*)&w2[r][d];
            s += x.x * y.x + x.y * y.y + x.z * y.z + x.w * y.w;
        }
        att[r][t] = s;
    }
    __syncthreads();
    const float* ob = outp + (size_t)b * 64 * 512;
    float s0[8] = {}, s1[8] = {};
    for (int t = 0; t < 64; ++t) {
        const float v0 = ob[t * 512 + tid];
        const float v1 = ob[t * 512 + 256 + tid];
        #pragma unroll
        for (int r = 0; r < 8; ++r) {
            const float a = att[r][t];
            s0[r] += a * v0; s1[r] += a * v1;
        }
    }
    #pragma unroll
    for (int r = 0; r < 8; ++r) {
        sent[((size_t)b * 8 + r) * 512 + tid]       = s0[r];
        sent[((size_t)b * 8 + r) * 512 + 256 + tid] = s1[r];
    }
}

// ---------------- dynamic routing (unchanged) ------------------------------
__global__ __launch_bounds__(512) void k_routing(
    const float* __restrict__ votes, float* __restrict__ out)
{
    __shared__ float v[8][32][16];
    __shared__ float logits[8][32];
    __shared__ float route[8][32];
    const int b = blockIdx.x, tid = threadIdx.x;
    const float* vb = votes + (size_t)b * 4096;
    for (int i = tid; i < 4096; i += 512) ((float*)v)[i] = vb[i];
    if (tid < 256) ((float*)logits)[tid] = 0.0f;
    __syncthreads();
    const int c = tid >> 4, a = tid & 15;
    float n2 = 0.0f;
    for (int it = 0; it < 3; ++it) {
        if (tid < 256) {
            const int r = tid >> 5, cc = tid & 31;
            const float l = logits[r][cc];
            float mx = l;
            #pragma unroll
            for (int m = 1; m < 32; m <<= 1) mx = fmaxf(mx, __shfl_xor(mx, m));
            const float e = __expf(l - mx);
            float sm = e;
            #pragma unroll
            for (int m = 1; m < 32; m <<= 1) sm += __shfl_xor(sm, m);
            route[r][cc] = e / sm;
        }
        __syncthreads();
        float pa = 0.0f;
        #pragma unroll
        for (int r = 0; r < 8; ++r) pa += route[r][c] * v[r][c][a];
        n2 = pa * pa;
        #pragma unroll
        for (int m = 1; m < 16; m <<= 1) n2 += __shfl_xor(n2, m);
        const float nrm = sqrtf(n2);
        const float av = pa * (nrm / (0.5f + n2));
        if (it < 2) {
            #pragma unroll
            for (int r = 0; r < 8; ++r) {
                float u = v[r][c][a] * av;
                #pragma unroll
                for (int m = 1; m < 16; m <<= 1) u += __shfl_xor(u, m);
                if (a == 0) logits[r][c] += u;
            }
        }
        __syncthreads();
    }
    if (a == 0) out[b * 32 + c] = n2 / (0.5f + n2);
}

// ---------------------------------------------------------------------------
static void launch_scan(const float* Z, const float* wf, const float* wb,
                        float* ob, int bt, unsigned int* hx32, int* fl,
                        hipStream_t stream)
{
    int base0 = 0;
    void* args[] = {(void*)&Z, (void*)&wf, (void*)&wb, (void*)&ob,
                    (void*)&bt, (void*)&hx32, (void*)&fl, (void*)&base0};
    if (hipLaunchCooperativeKernel((const void*)k_scan9, dim3(128), dim3(512),
                                   args, 0, stream) != hipSuccess) {
        k_scan9<<<dim3(128), 512, 0, stream>>>(Z, wf, wb, ob, bt, hx32, fl, 0);
    }
}

extern "C" void kernel_launch(void* const* d_in, const int* in_sizes, int n_in,
                              void* d_out, int out_size, void* d_ws, size_t ws_size,
                              hipStream_t stream) {
    (void)in_sizes; (void)n_in; (void)out_size; (void)ws_size;
    const int*   tokens  = (const int*)d_in[0];
    const float* emb     = (const float*)d_in[2];
    const float* w_ih_f0 = (const float*)d_in[3];
    const float* w_hh_f0 = (const float*)d_in[4];
    const float* b_f0    = (const float*)d_in[5];
    const float* w_ih_b0 = (const float*)d_in[6];
    const float* w_hh_b0 = (const float*)d_in[7];
    const float* b_b0    = (const float*)d_in[8];
    const float* w_ih_f1 = (const float*)d_in[9];
    const float* w_hh_f1 = (const float*)d_in[10];
    const float* b_f1    = (const float*)d_in[11];
    const float* w_ih_b1 = (const float*)d_in[12];
    const float* w_hh_b1 = (const float*)d_in[13];
    const float* b_b1    = (const float*)d_in[14];
    const float* ws1     = (const float*)d_in[15];
    const float* ws2     = (const float*)d_in[16];
    const float* caps    = (const float*)d_in[17];

    float* wsf  = (float*)d_ws;
    float* Wt   = wsf;                          //  4 * 262144
    float* Z    = Wt   + 4 * 262144;            //  8192*2048
    float* x1   = Z    + 16777216;              //  8192*512
    float* outp = x1   + 4194304;               //  8192*512
    float* hbar = outp + 4194304;               //  8192*128
    float* sent = hbar + 1048576;               //  128*8*512
    float* vote = sent + 524288;                //  128*8*512
    unsigned int* hx32 = (unsigned int*)(vote + 524288);  // 2*16*4096 u32
    int*   flags = (int*)(hx32 + 131072);       //  8192 ints
    unsigned short* Whi0 = (unsigned short*)(flags + 8192);  // 2048*320
    unsigned short* Wlo0 = Whi0 + 2048 * 320;
    unsigned short* Whi1 = Wlo0 + 2048 * 320;                // 2048*512
    unsigned short* Wlo1 = Whi1 + 2048 * 512;
    unsigned short* Whs1 = Wlo1 + 2048 * 512;                // 128*512 (ws1)
    unsigned short* Wls1 = Whs1 + 128 * 512;
    unsigned short* Chi  = Wls1 + 128 * 512;                 // 8*512*512 capsT
    unsigned short* Clo  = Chi  + 8 * 512 * 512;
    float* out  = (float*)d_out;

    // 0. zero sync flags (every launch; replays don't re-poison)
    k_zero<<<dim3(32), 256, 0, stream>>>(flags, 8192);
    // 1. pre-split W stacks to (hi,lo) bf16 (once per launch)
    k_splitw<<<dim3(640),  256, 0, stream>>>(w_ih_f0, w_ih_b0, 300, 320, Whi0, Wlo0);
    k_splitw<<<dim3(1024), 256, 0, stream>>>(w_ih_f1, w_ih_b1, 512, 512, Whi1, Wlo1);
    k_splitw<<<dim3(64),   256, 0, stream>>>(ws1, (const float*)nullptr, 512, 512, Whs1, Wls1);
    k_splitcaps<<<dim3(16, 16, 8), dim3(32, 8), 0, stream>>>(caps, Chi, Clo);
    // 2. transpose recurrent weights
    k_transpose<<<dim3(32, 8, 4), dim3(32, 8), 0, stream>>>(w_hh_f0, w_hh_b0, w_hh_f1, w_hh_b1, Wt);
    // 3. layer-0 projection (bf16x3 MFMA, inline A-gather+split) -> Z
    k_mgemm2<<<dim3(64, 16), 256, 0, stream>>>(
        emb, 300, tokens, Whi0, Wlo0, b_f0, b_b0, Z, 2048, 300, 320, 0);
    // 4. layer-0 scan -> x1 [t*128+b][512]
    launch_scan(Z, Wt, Wt + 262144, x1, 0, hx32, flags, stream);
    // 5. layer-1 projection -> Z
    k_mgemm2<<<dim3(64, 16), 256, 0, stream>>>(
        x1, 512, (const int*)nullptr, Whi1, Wlo1, b_f1, b_b1, Z, 2048, 512, 512, 0);
    // 6. layer-1 scan -> outp [b*64+t][512]
    launch_scan(Z, Wt + 2 * 262144, Wt + 3 * 262144, outp, 1, hx32, flags + 4096, stream);
    // 7. hbar = tanh(outp @ ws1^T)
    k_mgemm2<<<dim3(64, 1), 256, 0, stream>>>(
        outp, 512, (const int*)nullptr, Whs1, Wls1,
        (const float*)nullptr, (const float*)nullptr, hbar, 128, 512, 512, 1);
    // 8. attention + sent
    k_attnpool<<<dim3(128), 256, 0, stream>>>(hbar, outp, ws2, sent);
    // 9. votes (MFMA)
    k_mvotes<<<dim3(4, 8), 256, 0, stream>>>(sent, Chi, Clo, vote);
    // 10. routing
    k_routing<<<dim3(128), 512, 0, stream>>>(vote, out);
}

// Round 20
// 528.594 us; speedup vs baseline: 1.4333x; 1.0153x over previous
//
#include <hip/hip_runtime.h>
#include <hip/hip_bf16.h>

// ---------------------------------------------------------------------------
// CapsuleNetwork: embedding -> 2-layer BiLSTM -> attn pooling -> routing
// Round 19: prep cleanup. k_transpose removed (scan W-preload reads w_hh
// [1024][256] rows directly — identical values, contiguous per-lane reads);
// 3x k_splitw merged into one batched k_splitw3 launch. All else = R18
// (best 536.7us): R13 scan (154 floor), bf16x3 MFMA GEMMs, MFMA votes.
// B=128 T=64 E=300 H=256 DA=128 R=8 SC=32 AT=16
// ---------------------------------------------------------------------------

typedef __attribute__((ext_vector_type(8))) short bf16x8;
typedef __attribute__((ext_vector_type(4))) float f32x4;

__device__ __forceinline__ float sigf(float x) { return 1.0f / (1.0f + __expf(-x)); }
__device__ __forceinline__ float tanhf_fast(float x) { return 1.0f - 2.0f / (__expf(2.0f * x) + 1.0f); }

// ---------------- zero words -----------------------------------------------
__global__ void k_zero(int* __restrict__ p, int n)
{
    const int i = blockIdx.x * blockDim.x + threadIdx.x;
    if (i < n) p[i] = 0;
}

// ---------------- batched W split: 3 stacks in one launch ------------------
// blockIdx.y selects target: 0 = L0 (Kin=300,Kp=320), 1 = L1 (512,512),
// 2 = ws1 (512,512, 128 rows). Rows 0..1023 from A, 1024.. from B.
__global__ void k_splitw3(
    const float* __restrict__ A0, const float* __restrict__ B0,
    unsigned short* __restrict__ h0, unsigned short* __restrict__ l0,
    const float* __restrict__ A1, const float* __restrict__ B1,
    unsigned short* __restrict__ h1, unsigned short* __restrict__ l1,
    const float* __restrict__ A2,
    unsigned short* __restrict__ h2, unsigned short* __restrict__ l2)
{
    const float *WA, *WB;
    unsigned short *hi, *lo;
    int Kin, Kp, nblk;
    if (blockIdx.y == 0)      { WA = A0; WB = B0; hi = h0; lo = l0; Kin = 300; Kp = 320; nblk = 640; }
    else if (blockIdx.y == 1) { WA = A1; WB = B1; hi = h1; lo = l1; Kin = 512; Kp = 512; nblk = 1024; }
    else                      { WA = A2; WB = A2; hi = h2; lo = l2; Kin = 512; Kp = 512; nblk = 64; }
    if ((int)blockIdx.x >= nblk) return;

    const int i4 = (blockIdx.x * 256 + threadIdx.x) * 4;
    const int r = i4 / Kp;
    const int k = i4 - r * Kp;
    const float* srow = (r < 1024) ? (WA + (size_t)r * Kin)
                                   : (WB + (size_t)(r - 1024) * Kin);
    float e[4];
    if (k + 4 <= Kin) {
        const float4 v = *(const float4*)(srow + k);
        e[0] = v.x; e[1] = v.y; e[2] = v.z; e[3] = v.w;
    } else {
        #pragma unroll
        for (int j = 0; j < 4; ++j) e[j] = (k + j < Kin) ? srow[k + j] : 0.0f;
    }
    ushort4 hv, lv;
    #pragma unroll
    for (int j = 0; j < 4; ++j) {
        __hip_bfloat16 bh = __float2bfloat16(e[j]);
        const float fh = __bfloat162float(bh);
        __hip_bfloat16 bl = __float2bfloat16(e[j] - fh);
        ((unsigned short*)&hv)[j] = *(unsigned short*)&bh;
        ((unsigned short*)&lv)[j] = *(unsigned short*)&bl;
    }
    *(ushort4*)&hi[(size_t)r * Kp + k] = hv;
    *(ushort4*)&lo[(size_t)r * Kp + k] = lv;
}

// ---------------- caps_w [r][u][o] -> bf16 hi/lo transposed [r][o][u] ------
__global__ void k_splitcaps(const float* __restrict__ caps,
                            unsigned short* __restrict__ hiT,
                            unsigned short* __restrict__ loT)
{
    __shared__ float tile[32][33];
    const float* src = caps + (size_t)blockIdx.z * 512 * 512;
    unsigned short* ho = hiT + (size_t)blockIdx.z * 512 * 512;
    unsigned short* lo = loT + (size_t)blockIdx.z * 512 * 512;
    const int u0 = blockIdx.x * 32, o0 = blockIdx.y * 32;
    const int tx = threadIdx.x, ty = threadIdx.y;  // (32,8)
    #pragma unroll
    for (int i = 0; i < 32; i += 8)
        tile[ty + i][tx] = src[(size_t)(u0 + ty + i) * 512 + (o0 + tx)];
    __syncthreads();
    #pragma unroll
    for (int i = 0; i < 32; i += 8) {
        const float v = tile[tx][ty + i];   // caps[u0+tx][o0+ty+i]
        __hip_bfloat16 bh = __float2bfloat16(v);
        __hip_bfloat16 bl = __float2bfloat16(v - __bfloat162float(bh));
        const size_t idx = (size_t)(o0 + ty + i) * 512 + (u0 + tx);
        ho[idx] = *(unsigned short*)&bh;
        lo[idx] = *(unsigned short*)&bl;
    }
}

// ---------------- bf16x3 MFMA GEMM: inline A-split, pre-split W ------------
// C[m][n] = act( sum_k A[m,k]*W[n,k] + bias[n] ). A fp32 (opt. gathered),
// split in-register at staging; W read directly as (hi,lo) bf16.
// Tile 128x128, 4 waves (2x2 of 64x64), 4x4 frags of 16x16x32, LDS stride 40.
__global__ __launch_bounds__(256) void k_mgemm2(
    const float* __restrict__ A, int lda, const int* __restrict__ tokens,
    const unsigned short* __restrict__ Whi, const unsigned short* __restrict__ Wlo,
    const float* __restrict__ bias0, const float* __restrict__ bias1,
    float* __restrict__ C, int ldc, int Kin, int Kp, int act_tanh)
{
    __shared__ unsigned short lAh[128 * 40];
    __shared__ unsigned short lAl[128 * 40];
    __shared__ unsigned short lBh[128 * 40];
    __shared__ unsigned short lBl[128 * 40];

    const int tid = threadIdx.x;
    const int m0 = blockIdx.x * 128;
    const int n0 = blockIdx.y * 128;
    const int w  = tid >> 6, l = tid & 63;
    const int wm = (w >> 1) * 64, wn = (w & 1) * 64;
    const int lr = l & 15, lk = (l >> 4) * 8;

    int srow[2], sk8[2];
    const float* arow[2];
    size_t wbase[2];
    #pragma unroll
    for (int p = 0; p < 2; ++p) {
        const int chunk = tid + p * 256;
        srow[p] = chunk >> 2;
        sk8[p]  = (chunk & 3) * 8;
        const int am = m0 + srow[p];
        if (tokens) {
            const int t = am >> 7, b = am & 127;
            arow[p] = A + (size_t)tokens[b * 64 + t] * lda;
        } else {
            arow[p] = A + (size_t)am * lda;
        }
        wbase[p] = (size_t)(n0 + srow[p]) * Kp + sk8[p];
    }

    f32x4 acc[4][4];
    #pragma unroll
    for (int i = 0; i < 4; ++i)
        #pragma unroll
        for (int j = 0; j < 4; ++j)
            acc[i][j] = (f32x4){0.f, 0.f, 0.f, 0.f};

    float fa[2][8];
    bf16x8 rwh[2], rwl[2];
    #pragma unroll
    for (int p = 0; p < 2; ++p) {
        const int k0 = sk8[p];
        if (k0 + 7 < Kin) {
            const float4 a0 = *(const float4*)(arow[p] + k0);
            const float4 a1 = *(const float4*)(arow[p] + k0 + 4);
            fa[p][0]=a0.x; fa[p][1]=a0.y; fa[p][2]=a0.z; fa[p][3]=a0.w;
            fa[p][4]=a1.x; fa[p][5]=a1.y; fa[p][6]=a1.z; fa[p][7]=a1.w;
        } else {
            #pragma unroll
            for (int j = 0; j < 8; ++j)
                fa[p][j] = (k0 + j < Kin) ? arow[p][k0 + j] : 0.0f;
        }
        rwh[p] = *(const bf16x8*)&Whi[wbase[p]];
        rwl[p] = *(const bf16x8*)&Wlo[wbase[p]];
    }

    for (int kt = 0; kt < Kp; kt += 32) {
        #pragma unroll
        for (int p = 0; p < 2; ++p) {
            const int la = srow[p] * 40 + sk8[p];
            ushort hA[8], lA[8];
            #pragma unroll
            for (int j = 0; j < 8; ++j) {
                __hip_bfloat16 bh = __float2bfloat16(fa[p][j]);
                const float fh = __bfloat162float(bh);
                __hip_bfloat16 bl = __float2bfloat16(fa[p][j] - fh);
                hA[j] = *(ushort*)&bh; lA[j] = *(ushort*)&bl;
            }
            *(bf16x8*)&lAh[la] = *(bf16x8*)hA;
            *(bf16x8*)&lAl[la] = *(bf16x8*)lA;
            *(bf16x8*)&lBh[la] = rwh[p];
            *(bf16x8*)&lBl[la] = rwl[p];
        }
        __syncthreads();
        if (kt + 32 < Kp) {
            #pragma unroll
            for (int p = 0; p < 2; ++p) {
                const int k0 = kt + 32 + sk8[p];
                if (k0 + 7 < Kin) {
                    const float4 a0 = *(const float4*)(arow[p] + k0);
                    const float4 a1 = *(const float4*)(arow[p] + k0 + 4);
                    fa[p][0]=a0.x; fa[p][1]=a0.y; fa[p][2]=a0.z; fa[p][3]=a0.w;
                    fa[p][4]=a1.x; fa[p][5]=a1.y; fa[p][6]=a1.z; fa[p][7]=a1.w;
                } else {
                    #pragma unroll
                    for (int j = 0; j < 8; ++j)
                        fa[p][j] = (k0 + j < Kin) ? arow[p][k0 + j] : 0.0f;
                }
                rwh[p] = *(const bf16x8*)&Whi[wbase[p] + kt + 32];
                rwl[p] = *(const bf16x8*)&Wlo[wbase[p] + kt + 32];
            }
        }
        bf16x8 ah[4], al[4], bh[4], bl[4];
        #pragma unroll
        for (int f = 0; f < 4; ++f) {
            const int ra = (wm + f * 16 + lr) * 40 + lk;
            const int rb = (wn + f * 16 + lr) * 40 + lk;
            ah[f] = *(const bf16x8*)&lAh[ra];
            al[f] = *(const bf16x8*)&lAl[ra];
            bh[f] = *(const bf16x8*)&lBh[rb];
            bl[f] = *(const bf16x8*)&lBl[rb];
        }
        #pragma unroll
        for (int fm = 0; fm < 4; ++fm)
            #pragma unroll
            for (int fn = 0; fn < 4; ++fn) {
                acc[fm][fn] = __builtin_amdgcn_mfma_f32_16x16x32_bf16(ah[fm], bh[fn], acc[fm][fn], 0, 0, 0);
                acc[fm][fn] = __builtin_amdgcn_mfma_f32_16x16x32_bf16(ah[fm], bl[fn], acc[fm][fn], 0, 0, 0);
                acc[fm][fn] = __builtin_amdgcn_mfma_f32_16x16x32_bf16(al[fm], bh[fn], acc[fm][fn], 0, 0, 0);
            }
        __syncthreads();
    }
    #pragma unroll
    for (int fm = 0; fm < 4; ++fm)
        #pragma unroll
        for (int fn = 0; fn < 4; ++fn) {
            const int col = n0 + wn + fn * 16 + lr;
            const float bv = (col < 1024) ? (bias0 ? bias0[col] : 0.f)
                                          : (bias1 ? bias1[col - 1024] : 0.f);
            #pragma unroll
            for (int j = 0; j < 4; ++j) {
                const int row = m0 + wm + fm * 16 + (l >> 4) * 4 + j;
                float x = acc[fm][fn][j] + bv;
                if (act_tanh) x = tanhf_fast(x);
                C[(size_t)row * ldc + col] = x;
            }
        }
}

// ---------------- votes MFMA GEMM ------------------------------------------
// votes[b,r,o] = sum_u sent[b,r,u] * capsT[r][o][u]. Grid (4 n-blocks, 8 r).
__global__ __launch_bounds__(256) void k_mvotes(
    const float* __restrict__ sent, const unsigned short* __restrict__ Whi,
    const unsigned short* __restrict__ Wlo, float* __restrict__ votes)
{
    __shared__ unsigned short lAh[128 * 40];
    __shared__ unsigned short lAl[128 * 40];
    __shared__ unsigned short lBh[128 * 40];
    __shared__ unsigned short lBl[128 * 40];

    const int tid = threadIdx.x;
    const int n0 = blockIdx.x * 128;
    const int r  = blockIdx.y;
    const int w  = tid >> 6, l = tid & 63;
    const int wm = (w >> 1) * 64, wn = (w & 1) * 64;
    const int lr = l & 15, lk = (l >> 4) * 8;

    const unsigned short* WhiR = Whi + (size_t)r * 512 * 512;
    const unsigned short* WloR = Wlo + (size_t)r * 512 * 512;

    int srow[2], sk8[2];
    const float* arow[2];
    size_t wbase[2];
    #pragma unroll
    for (int p = 0; p < 2; ++p) {
        const int chunk = tid + p * 256;
        srow[p] = chunk >> 2;               // batch row 0..127
        sk8[p]  = (chunk & 3) * 8;
        arow[p] = sent + ((size_t)srow[p] * 8 + r) * 512;
        wbase[p] = (size_t)(n0 + srow[p]) * 512 + sk8[p];
    }

    f32x4 acc[4][4];
    #pragma unroll
    for (int i = 0; i < 4; ++i)
        #pragma unroll
        for (int j = 0; j < 4; ++j)
            acc[i][j] = (f32x4){0.f, 0.f, 0.f, 0.f};

    float fa[2][8];
    bf16x8 rwh[2], rwl[2];
    #pragma unroll
    for (int p = 0; p < 2; ++p) {
        const float4 a0 = *(const float4*)(arow[p] + sk8[p]);
        const float4 a1 = *(const float4*)(arow[p] + sk8[p] + 4);
        fa[p][0]=a0.x; fa[p][1]=a0.y; fa[p][2]=a0.z; fa[p][3]=a0.w;
        fa[p][4]=a1.x; fa[p][5]=a1.y; fa[p][6]=a1.z; fa[p][7]=a1.w;
        rwh[p] = *(const bf16x8*)&WhiR[wbase[p]];
        rwl[p] = *(const bf16x8*)&WloR[wbase[p]];
    }

    for (int kt = 0; kt < 512; kt += 32) {
        #pragma unroll
        for (int p = 0; p < 2; ++p) {
            const int la = srow[p] * 40 + sk8[p];
            ushort hA[8], lA[8];
            #pragma unroll
            for (int j = 0; j < 8; ++j) {
                __hip_bfloat16 bh = __float2bfloat16(fa[p][j]);
                const float fh = __bfloat162float(bh);
                __hip_bfloat16 bl = __float2bfloat16(fa[p][j] - fh);
                hA[j] = *(ushort*)&bh; lA[j] = *(ushort*)&bl;
            }
            *(bf16x8*)&lAh[la] = *(bf16x8*)hA;
            *(bf16x8*)&lAl[la] = *(bf16x8*)lA;
            *(bf16x8*)&lBh[la] = rwh[p];
            *(bf16x8*)&lBl[la] = rwl[p];
        }
        __syncthreads();
        if (kt + 32 < 512) {
            #pragma unroll
            for (int p = 0; p < 2; ++p) {
                const int k0 = kt + 32 + sk8[p];
                const float4 a0 = *(const float4*)(arow[p] + k0);
                const float4 a1 = *(const float4*)(arow[p] + k0 + 4);
                fa[p][0]=a0.x; fa[p][1]=a0.y; fa[p][2]=a0.z; fa[p][3]=a0.w;
                fa[p][4]=a1.x; fa[p][5]=a1.y; fa[p][6]=a1.z; fa[p][7]=a1.w;
                rwh[p] = *(const bf16x8*)&WhiR[wbase[p] + kt + 32];
                rwl[p] = *(const bf16x8*)&WloR[wbase[p] + kt + 32];
            }
        }
        bf16x8 ah[4], al[4], bh[4], bl[4];
        #pragma unroll
        for (int f = 0; f < 4; ++f) {
            const int ra = (wm + f * 16 + lr) * 40 + lk;
            const int rb = (wn + f * 16 + lr) * 40 + lk;
            ah[f] = *(const bf16x8*)&lAh[ra];
            al[f] = *(const bf16x8*)&lAl[ra];
            bh[f] = *(const bf16x8*)&lBh[rb];
            bl[f] = *(const bf16x8*)&lBl[rb];
        }
        #pragma unroll
        for (int fm = 0; fm < 4; ++fm)
            #pragma unroll
            for (int fn = 0; fn < 4; ++fn) {
                acc[fm][fn] = __builtin_amdgcn_mfma_f32_16x16x32_bf16(ah[fm], bh[fn], acc[fm][fn], 0, 0, 0);
                acc[fm][fn] = __builtin_amdgcn_mfma_f32_16x16x32_bf16(ah[fm], bl[fn], acc[fm][fn], 0, 0, 0);
                acc[fm][fn] = __builtin_amdgcn_mfma_f32_16x16x32_bf16(al[fm], bh[fn], acc[fm][fn], 0, 0, 0);
            }
        __syncthreads();
    }
    #pragma unroll
    for (int fm = 0; fm < 4; ++fm)
        #pragma unroll
        for (int fn = 0; fn < 4; ++fn) {
            const int col = n0 + wn + fn * 16 + lr;
            #pragma unroll
            for (int j = 0; j < 4; ++j) {
                const int row = wm + fm * 16 + (l >> 4) * 4 + j;  // batch b
                votes[((size_t)row * 8 + r) * 512 + col] = acc[fm][fn][j];
            }
        }
}

// ---------------- BiLSTM scan: MFMA recurrence (R13; direct w_hh read) -----
// 128 blocks x 512 thr (8 waves). bx = s*16 + g: g = dir*8+qg (16 batch
// rows), s = 0..7 (32 h-dims). Whh layout [1024][256]: row = output col,
// col = k -> preload reads 8 contiguous floats per fragment (same values as
// the old transposed Wt read). All else identical to R13 (floor 154us).
__global__ __launch_bounds__(512, 2) void k_scan9(
    const float* __restrict__ Zin, const float* __restrict__ WhF,
    const float* __restrict__ WhB, float* __restrict__ outbuf,
    int bt_layout, unsigned int* __restrict__ hx32, int* __restrict__ flags,
    int bx_base)
{
    __shared__ __align__(16) unsigned short hbh[16 * 264];
    __shared__ __align__(16) unsigned short hbl[16 * 264];
    __shared__ float zbuf[8 * 16 * 17];          // [frag][bi][17]

    const int bx  = blockIdx.x + bx_base;
    const int g   = bx & 15;           // dir*8 + qg
    const int s   = bx >> 4;           // 0..7 dim slice
    const int dir = g >> 3;
    const int qg  = g & 7;
    const int tid = threadIdx.x;
    const int w   = tid >> 6;          // wave = fragment 0..7
    const int l   = tid & 63;
    const int lr  = l & 15;
    const int lk8 = (l >> 4) * 8;
    const float* __restrict__ Wh = dir ? WhB : WhF;

    // ---- W preload: fragment w -> gate = w>>1, dim-half = w&1 ----
    const int colg = (w >> 1) * 256 + s * 32 + (w & 1) * 16 + lr;
    const float* wrow = Wh + (size_t)colg * 256;
    bf16x8 wbh[8], wbl[8];
    #pragma unroll
    for (int kf = 0; kf < 8; ++kf) {
        const float4 va = *(const float4*)(wrow + kf * 32 + lk8);
        const float4 vb = *(const float4*)(wrow + kf * 32 + lk8 + 4);
        const float vv[8] = {va.x, va.y, va.z, va.w, vb.x, vb.y, vb.z, vb.w};
        ushort ph[8], pl[8];
        #pragma unroll
        for (int j = 0; j < 8; ++j) {
            __hip_bfloat16 bh = __float2bfloat16(vv[j]);
            __hip_bfloat16 bl = __float2bfloat16(vv[j] - __bfloat162float(bh));
            ph[j] = *(ushort*)&bh; pl[j] = *(ushort*)&bl;
        }
        wbh[kf] = *(bf16x8*)ph;
        wbl[kf] = *(bf16x8*)pl;
    }

    const int bi  = tid >> 5;
    const int di  = tid & 31;
    const int gb  = qg * 16 + bi;
    const int dim = s * 32 + di;
    float c_state = 0.0f;
    const int fbase = g * 64;
    const int st_base = (tid >> 5) * 256 + (tid & 31) * 8;
    const int st_lds  = (tid >> 5) * 264 + (tid & 31) * 8;

    for (int tt = 0; tt < 64; ++tt) {
        const int t = dir ? (63 - tt) : tt;
        const float* zr = Zin + (size_t)(t * 128 + gb) * 2048 + dir * 1024 + dim;
        const float z0 = zr[0], z1 = zr[256], z2 = zr[512], z3 = zr[768];
        if (tt > 0) {
            if (tid == 0) {
                while (__hip_atomic_load(&flags[fbase + tt - 1], __ATOMIC_RELAXED,
                                         __HIP_MEMORY_SCOPE_AGENT) < 8)
                    __builtin_amdgcn_s_sleep(1);
            }
            __syncthreads();
            {
                const unsigned long long* hs64 = (const unsigned long long*)
                    (hx32 + ((size_t)(((tt - 1) & 1) * 16 + g)) * 4096 + st_base);
                unsigned int hp[4], lp[4];
                #pragma unroll
                for (int j = 0; j < 4; ++j) {
                    const unsigned long long q = __hip_atomic_load(&hs64[j], __ATOMIC_RELAXED,
                                                                   __HIP_MEMORY_SCOPE_AGENT);
                    const unsigned int w0 = (unsigned int)q;
                    const unsigned int w1 = (unsigned int)(q >> 32);
                    hp[j] = (w0 >> 16) | (w1 & 0xFFFF0000u);
                    lp[j] = (w0 & 0xFFFFu) | (w1 << 16);
                }
                *(uint4*)&hbh[st_lds] = make_uint4(hp[0], hp[1], hp[2], hp[3]);
                *(uint4*)&hbl[st_lds] = make_uint4(lp[0], lp[1], lp[2], lp[3]);
            }
            __syncthreads();
            f32x4 acc = (f32x4){0.f, 0.f, 0.f, 0.f};
            #pragma unroll
            for (int kf = 0; kf < 8; ++kf) {
                const int ao = lr * 264 + kf * 32 + lk8;
                const bf16x8 ah = *(const bf16x8*)&hbh[ao];
                const bf16x8 al = *(const bf16x8*)&hbl[ao];
                acc = __builtin_amdgcn_mfma_f32_16x16x32_bf16(ah, wbh[kf], acc, 0, 0, 0);
                acc = __builtin_amdgcn_mfma_f32_16x16x32_bf16(ah, wbl[kf], acc, 0, 0, 0);
                acc = __builtin_amdgcn_mfma_f32_16x16x32_bf16(al, wbh[kf], acc, 0, 0, 0);
            }
            #pragma unroll
            for (int j = 0; j < 4; ++j)
                zbuf[(w * 16 + (l >> 4) * 4 + j) * 17 + lr] = acc[j];
            __syncthreads();
        } else {
            for (int i = tid; i < 2176; i += 512) zbuf[i] = 0.0f;
            __syncthreads();
        }
        {
            const int dh = di >> 4, dl = di & 15;
            const float zi = zbuf[((0 * 2 + dh) * 16 + bi) * 17 + dl] + z0;
            const float zf = zbuf[((1 * 2 + dh) * 16 + bi) * 17 + dl] + z1;
            const float zg = zbuf[((2 * 2 + dh) * 16 + bi) * 17 + dl] + z2;
            const float zo = zbuf[((3 * 2 + dh) * 16 + bi) * 17 + dl] + z3;
            c_state = sigf(zf) * c_state + sigf(zi) * tanhf_fast(zg);
            const float h = sigf(zo) * tanhf_fast(c_state);
            const int row = bt_layout ? (gb * 64 + t) : (t * 128 + gb);
            outbuf[(size_t)row * 512 + dir * 256 + dim] = h;
            __hip_bfloat16 bh = __float2bfloat16(h);
            __hip_bfloat16 bl = __float2bfloat16(h - __bfloat162float(bh));
            const unsigned int pk = ((unsigned int)(*(ushort*)&bh) << 16) | (*(ushort*)&bl);
            __hip_atomic_store(
                &hx32[((size_t)((tt & 1) * 16 + g)) * 4096 + bi * 256 + dim],
                pk, __ATOMIC_RELAXED, __HIP_MEMORY_SCOPE_AGENT);
        }
        __syncthreads();
        if (tid == 0)
            __hip_atomic_fetch_add(&flags[fbase + tt], 1, __ATOMIC_RELAXED,
                                   __HIP_MEMORY_SCOPE_AGENT);
    }
}

// ---------------- attention pooling (unchanged) ----------------------------
__global__ __launch_bounds__(256) void k_attnpool(
    const float* __restrict__ hbar, const float* __restrict__ outp,
    const float* __restrict__ ws2, float* __restrict__ sent)
{
    __shared__ float hb[64][132];
    __shared__ float w2[8][128];
    __shared__ float att[8][64];
    const int b = blockIdx.x, tid = threadIdx.x;
    for (int i = tid; i < 1024; i += 256) ((float*)w2)[i] = ws2[i];
    const float* hsrc = hbar + (size_t)b * 64 * 128;
    for (int i = tid; i < 2048; i += 256) {
        const int row = i >> 5, d4 = (i & 31) << 2;
        *(float4*)&hb[row][d4] = *(const float4*)(hsrc + row * 128 + d4);
    }
    __syncthreads();
    for (int p = tid; p < 512; p += 256) {
        const int r = p >> 6, t = p & 63;
        float s = 0.0f;
        #pragma unroll 8
        for (int d = 0; d < 128; d += 4) {
            const float4 x = *(const float4*)&hb[t][d];
            const float4 y = *(const float4*)&w2[r][d];
            s += x.x * y.x + x.y * y.y + x.z * y.z + x.w * y.w;
        }
        att[r][t] = s;
    }
    __syncthreads();
    const float* ob = outp + (size_t)b * 64 * 512;
    float s0[8] = {}, s1[8] = {};
    for (int t = 0; t < 64; ++t) {
        const float v0 = ob[t * 512 + tid];
        const float v1 = ob[t * 512 + 256 + tid];
        #pragma unroll
        for (int r = 0; r < 8; ++r) {
            const float a = att[r][t];
            s0[r] += a * v0; s1[r] += a * v1;
        }
    }
    #pragma unroll
    for (int r = 0; r < 8; ++r) {
        sent[((size_t)b * 8 + r) * 512 + tid]       = s0[r];
        sent[((size_t)b * 8 + r) * 512 + 256 + tid] = s1[r];
    }
}

// ---------------- dynamic routing (unchanged) ------------------------------
__global__ __launch_bounds__(512) void k_routing(
    const float* __restrict__ votes, float* __restrict__ out)
{
    __shared__ float v[8][32][16];
    __shared__ float logits[8][32];
    __shared__ float route[8][32];
    const int b = blockIdx.x, tid = threadIdx.x;
    const float* vb = votes + (size_t)b * 4096;
    for (int i = tid; i < 4096; i += 512) ((float*)v)[i] = vb[i];
    if (tid < 256) ((float*)logits)[tid] = 0.0f;
    __syncthreads();
    const int c = tid >> 4, a = tid & 15;
    float n2 = 0.0f;
    for (int it = 0; it < 3; ++it) {
        if (tid < 256) {
            const int r = tid >> 5, cc = tid & 31;
            const float l = logits[r][cc];
            float mx = l;
            #pragma unroll
            for (int m = 1; m < 32; m <<= 1) mx = fmaxf(mx, __shfl_xor(mx, m));
            const float e = __expf(l - mx);
            float sm = e;
            #pragma unroll
            for (int m = 1; m < 32; m <<= 1) sm += __shfl_xor(sm, m);
            route[r][cc] = e / sm;
        }
        __syncthreads();
        float pa = 0.0f;
        #pragma unroll
        for (int r = 0; r < 8; ++r) pa += route[r][c] * v[r][c][a];
        n2 = pa * pa;
        #pragma unroll
        for (int m = 1; m < 16; m <<= 1) n2 += __shfl_xor(n2, m);
        const float nrm = sqrtf(n2);
        const float av = pa * (nrm / (0.5f + n2));
        if (it < 2) {
            #pragma unroll
            for (int r = 0; r < 8; ++r) {
                float u = v[r][c][a] * av;
                #pragma unroll
                for (int m = 1; m < 16; m <<= 1) u += __shfl_xor(u, m);
                if (a == 0) logits[r][c] += u;
            }
        }
        __syncthreads();
    }
    if (a == 0) out[b * 32 + c] = n2 / (0.5f + n2);
}

// ---------------------------------------------------------------------------
static void launch_scan(const float* Z, const float* whF, const float* whB,
                        float* ob, int bt, unsigned int* hx32, int* fl,
                        hipStream_t stream)
{
    int base0 = 0;
    void* args[] = {(void*)&Z, (void*)&whF, (void*)&whB, (void*)&ob,
                    (void*)&bt, (void*)&hx32, (void*)&fl, (void*)&base0};
    if (hipLaunchCooperativeKernel((const void*)k_scan9, dim3(128), dim3(512),
                                   args, 0, stream) != hipSuccess) {
        k_scan9<<<dim3(128), 512, 0, stream>>>(Z, whF, whB, ob, bt, hx32, fl, 0);
    }
}

extern "C" void kernel_launch(void* const* d_in, const int* in_sizes, int n_in,
                              void* d_out, int out_size, void* d_ws, size_t ws_size,
                              hipStream_t stream) {
    (void)in_sizes; (void)n_in; (void)out_size; (void)ws_size;
    const int*   tokens  = (const int*)d_in[0];
    const float* emb     = (const float*)d_in[2];
    const float* w_ih_f0 = (const float*)d_in[3];
    const float* w_hh_f0 = (const float*)d_in[4];
    const float* b_f0    = (const float*)d_in[5];
    const float* w_ih_b0 = (const float*)d_in[6];
    const float* w_hh_b0 = (const float*)d_in[7];
    const float* b_b0    = (const float*)d_in[8];
    const float* w_ih_f1 = (const float*)d_in[9];
    const float* w_hh_f1 = (const float*)d_in[10];
    const float* b_f1    = (const float*)d_in[11];
    const float* w_ih_b1 = (const float*)d_in[12];
    const float* w_hh_b1 = (const float*)d_in[13];
    const float* b_b1    = (const float*)d_in[14];
    const float* ws1     = (const float*)d_in[15];
    const float* ws2     = (const float*)d_in[16];
    const float* caps    = (const float*)d_in[17];

    float* wsf  = (float*)d_ws;
    float* Z    = wsf  + 4 * 262144;            //  8192*2048 (Wt slot unused)
    float* x1   = Z    + 16777216;              //  8192*512
    float* outp = x1   + 4194304;               //  8192*512
    float* hbar = outp + 4194304;               //  8192*128
    float* sent = hbar + 1048576;               //  128*8*512
    float* vote = sent + 524288;                //  128*8*512
    unsigned int* hx32 = (unsigned int*)(vote + 524288);  // 2*16*4096 u32
    int*   flags = (int*)(hx32 + 131072);       //  8192 ints
    unsigned short* Whi0 = (unsigned short*)(flags + 8192);  // 2048*320
    unsigned short* Wlo0 = Whi0 + 2048 * 320;
    unsigned short* Whi1 = Wlo0 + 2048 * 320;                // 2048*512
    unsigned short* Wlo1 = Whi1 + 2048 * 512;
    unsigned short* Whs1 = Wlo1 + 2048 * 512;                // 128*512 (ws1)
    unsigned short* Wls1 = Whs1 + 128 * 512;
    unsigned short* Chi  = Wls1 + 128 * 512;                 // 8*512*512 capsT
    unsigned short* Clo  = Chi  + 8 * 512 * 512;
    float* out  = (float*)d_out;

    // 0. zero sync flags (every launch; replays don't re-poison)
    k_zero<<<dim3(32), 256, 0, stream>>>(flags, 8192);
    // 1. pre-split all W stacks (one batched launch) + caps transpose-split
    k_splitw3<<<dim3(1024, 3), 256, 0, stream>>>(
        w_ih_f0, w_ih_b0, Whi0, Wlo0,
        w_ih_f1, w_ih_b1, Whi1, Wlo1,
        ws1, Whs1, Wls1);
    k_splitcaps<<<dim3(16, 16, 8), dim3(32, 8), 0, stream>>>(caps, Chi, Clo);
    // 2. layer-0 projection (bf16x3 MFMA, inline A-gather+split) -> Z
    k_mgemm2<<<dim3(64, 16), 256, 0, stream>>>(
        emb, 300, tokens, Whi0, Wlo0, b_f0, b_b0, Z, 2048, 300, 320, 0);
    // 3. layer-0 scan -> x1 [t*128+b][512]  (reads w_hh directly)
    launch_scan(Z, w_hh_f0, w_hh_b0, x1, 0, hx32, flags, stream);
    // 4. layer-1 projection -> Z
    k_mgemm2<<<dim3(64, 16), 256, 0, stream>>>(
        x1, 512, (const int*)nullptr, Whi1, Wlo1, b_f1, b_b1, Z, 2048, 512, 512, 0);
    // 5. layer-1 scan -> outp [b*64+t][512]
    launch_scan(Z, w_hh_f1, w_hh_b1, outp, 1, hx32, flags + 4096, stream);
    // 6. hbar = tanh(outp @ ws1^T)
    k_mgemm2<<<dim3(64, 1), 256, 0, stream>>>(
        outp, 512, (const int*)nullptr, Whs1, Wls1,
        (const float*)nullptr, (const float*)nullptr, hbar, 128, 512, 512, 1);
    // 7. attention + sent
    k_attnpool<<<dim3(128), 256, 0, stream>>>(hbar, outp, ws2, sent);
    // 8. votes (MFMA)
    k_mvotes<<<dim3(4, 8), 256, 0, stream>>>(sent, Chi, Clo, vote);
    // 9. routing
    k_routing<<<dim3(128), 512, 0, stream>>>(vote, out);
}